// Round 3
// baseline (418.053 us; speedup 1.0000x reference)
//
#include <hip/hip_runtime.h>
#include <hip/hip_bf16.h>

// NTM cell on MI355X. B=2048, IN=64, CTRL=512, M=1024, V=64, OUT=64.
// Single NON-cooperative kernel, 512 blocks x 256 threads, 4 phases separated
// by a hand-rolled device-scope grid barrier (monotonic ticket counters in
// __device__ globals; no reset needed across graph-replay iterations):
//   phase0: blocks 0..127 split-K read_prev GEMM; blocks 128..511 grid-stride
//           fp32->bf16 converts to tile-major layouts
//   phase1: gates GEMM + fused LSTM (512 tiles, 1/block), 2-phase dbuf pipeline
//   phase2: heads GEMM (560 tiles, strided over 512 blocks)
//   phase3: tail softmax + read_new + out-GEMM (256 tiles)
// Coherence (G16): release = __syncthreads (vmcnt drain) + __threadfence
// (buffer_wbl2) before agent-scope fetch_add; acquire = agent-scope spin +
// __threadfence by ALL threads after the barrier (buffer_inv).
// Co-residency: 52KB LDS -> 3 blocks/CU; __launch_bounds__(256,2) -> 2/CU
// guaranteed; grid 512 = 2 x 256 CUs, so all blocks resident (no deadlock).

typedef unsigned short u16;
typedef __attribute__((ext_vector_type(8))) short bf16x8;
typedef __attribute__((ext_vector_type(4))) float f32x4;

#define MFMA_BF16(a, b, c) __builtin_amdgcn_mfma_f32_16x16x32_bf16((a), (b), (c), 0, 0, 0)
#define LDW 136
#define SLDW 520
#define SMEM_BYTES 53248

__device__ unsigned g_bar[3];

__device__ __forceinline__ void grid_barrier(int idx) {
    __syncthreads();                      // all block stores drained (vmcnt 0)
    if (threadIdx.x == 0) {
        __threadfence();                  // release: L2 writeback, device scope
        unsigned ticket = __hip_atomic_fetch_add(&g_bar[idx], 1u,
                              __ATOMIC_ACQ_REL, __HIP_MEMORY_SCOPE_AGENT);
        unsigned target = (ticket & ~511u) + 512u;   // end of this round
        while (__hip_atomic_load(&g_bar[idx], __ATOMIC_RELAXED,
                                 __HIP_MEMORY_SCOPE_AGENT) < target)
            __builtin_amdgcn_s_sleep(8);
    }
    __syncthreads();
    __threadfence();                      // acquire: invalidate L1/L2
}

__device__ __forceinline__ void dma16(const void* g, void* l) {
    __builtin_amdgcn_global_load_lds(
        (const __attribute__((address_space(1))) unsigned int*)g,
        (__attribute__((address_space(3))) unsigned int*)l, 16, 0, 0);
}

__device__ __forceinline__ u16 f2bf(float f) {
    union { float f; unsigned int u; } a; a.f = f;
    return (u16)((a.u + 0x7FFFu + ((a.u >> 16) & 1u)) >> 16);
}

__device__ __forceinline__ void pack_store4(float a0, float a1, float a2, float a3, u16* d) {
    union { __hip_bfloat162 h[2]; uint2 u; } cv;
    cv.h[0] = __float22bfloat162_rn(make_float2(a0, a1));
    cv.h[1] = __float22bfloat162_rn(make_float2(a2, a3));
    *(uint2*)d = cv.u;
}

__device__ __forceinline__ void cvt4(const float* __restrict__ s, u16* __restrict__ d) {
    float4 v = *(const float4*)s;
    pack_store4(v.x, v.y, v.z, v.w, d);
}

__device__ __forceinline__ uint4 cvt8u(const float* __restrict__ s) {
    float4 v0 = *(const float4*)(s);
    float4 v1 = *(const float4*)(s + 4);
    union { __hip_bfloat162 h[4]; uint4 u; } r;
    r.h[0] = __float22bfloat162_rn(make_float2(v0.x, v0.y));
    r.h[1] = __float22bfloat162_rn(make_float2(v0.z, v0.w));
    r.h[2] = __float22bfloat162_rn(make_float2(v1.x, v1.y));
    r.h[3] = __float22bfloat162_rn(make_float2(v1.z, v1.w));
    return r.u;
}

__device__ __forceinline__ uint4 cvt8u_sum4(const float* __restrict__ p, int off) {
    float4 a0 = *(const float4*)(p + off);
    float4 a1 = *(const float4*)(p + 131072 + off);
    float4 a2 = *(const float4*)(p + 262144 + off);
    float4 a3 = *(const float4*)(p + 393216 + off);
    float4 b0 = *(const float4*)(p + off + 4);
    float4 b1 = *(const float4*)(p + 131072 + off + 4);
    float4 b2 = *(const float4*)(p + 262144 + off + 4);
    float4 b3 = *(const float4*)(p + 393216 + off + 4);
    float4 s0{a0.x + a1.x + a2.x + a3.x, a0.y + a1.y + a2.y + a3.y,
              a0.z + a1.z + a2.z + a3.z, a0.w + a1.w + a2.w + a3.w};
    float4 s1{b0.x + b1.x + b2.x + b3.x, b0.y + b1.y + b2.y + b3.y,
              b0.z + b1.z + b2.z + b3.z, b0.w + b1.w + b2.w + b3.w};
    union { __hip_bfloat162 h[4]; uint4 u; } r;
    r.h[0] = __float22bfloat162_rn(make_float2(s0.x, s0.y));
    r.h[1] = __float22bfloat162_rn(make_float2(s0.z, s0.w));
    r.h[2] = __float22bfloat162_rn(make_float2(s1.x, s1.y));
    r.h[3] = __float22bfloat162_rn(make_float2(s1.z, s1.w));
    return r.u;
}

__device__ __forceinline__ void bfu4_to_f8(uint4 u, float* f) {
    f[0] = __uint_as_float(u.x << 16); f[1] = __uint_as_float(u.x & 0xffff0000u);
    f[2] = __uint_as_float(u.y << 16); f[3] = __uint_as_float(u.y & 0xffff0000u);
    f[4] = __uint_as_float(u.z << 16); f[5] = __uint_as_float(u.z & 0xffff0000u);
    f[6] = __uint_as_float(u.w << 16); f[7] = __uint_as_float(u.w & 0xffff0000u);
}

__device__ __forceinline__ uint4 pack8(const float* v) {
    union { __hip_bfloat162 h[4]; uint4 u; } r;
#pragma unroll
    for (int j = 0; j < 4; ++j) r.h[j] = __float22bfloat162_rn(make_float2(v[2 * j], v[2 * j + 1]));
    return r.u;
}

__device__ __forceinline__ float sigf(float x) { return 1.f / (1.f + __expf(-x)); }
__device__ __forceinline__ float fast_tanh(float x) { return 1.f - 2.f / (__expf(2.f * x) + 1.f); }

#define PIPE_BAR_PRE_CNT()  do {                                              \
    asm volatile("s_waitcnt vmcnt(6) lgkmcnt(0)" ::: "memory");               \
    __builtin_amdgcn_s_barrier();                                             \
    __builtin_amdgcn_sched_barrier(0);                                        \
} while (0)
#define PIPE_BAR_PRE_ZERO() do {                                              \
    asm volatile("s_waitcnt vmcnt(0) lgkmcnt(0)" ::: "memory");               \
    __builtin_amdgcn_s_barrier();                                             \
    __builtin_amdgcn_sched_barrier(0);                                        \
} while (0)
#define PIPE_BAR_POST() do {                                                  \
    __builtin_amdgcn_sched_barrier(0);                                        \
    asm volatile("s_waitcnt lgkmcnt(0)" ::: "memory");                        \
    __builtin_amdgcn_s_barrier();                                             \
    __builtin_amdgcn_sched_barrier(0);                                        \
} while (0)

// One fp32->bf16 tile-major convert unit, t in [0, 926720).
__device__ __forceinline__ void convert_unit(int t,
    const float* __restrict__ x, const float* __restrict__ h_prev,
    const float* __restrict__ W_ih, const float* __restrict__ W_hh,
    const float* __restrict__ W_read, const float* __restrict__ W_write,
    const float* __restrict__ W_erase, const float* __restrict__ W_add,
    const float* __restrict__ W_out, const float* __restrict__ memory,
    u16* x_t, u16* ht_t, u16* wcat_t, u16* Wcat2_t, u16* Wo_rn, u16* memt)
{
    if (t < 32768) {  // x -> x_t[mt][oct8][row128]
        int r = t >> 4, c = (t & 15) * 4;
        cvt4(x + r * 64 + c, x_t + ((r >> 7) * 8 + (c >> 3)) * 1024 + (r & 127) * 8 + (c & 7));
        return;
    }
    t -= 32768;
    if (t < 262144) {  // h_prev -> ht_t[mt][oct64][row128]
        int r = t >> 7, c = (t & 127) * 4;
        cvt4(h_prev + r * 512 + c, ht_t + ((r >> 7) * 64 + (c >> 3)) * 1024 + (r & 127) * 8 + (c & 7));
        return;
    }
    t -= 262144;
    if (t < 65536) {  // W_ih (gate-interleave rows, col swap rp|x) -> wcat_t[bn][kt0][oct][row64]
        int r = t >> 5, c = (t & 31) * 4;
        int g = r >> 9, j = r & 511;
        int bn = j >> 4, row64 = (g << 4) + (j & 15);
        int cd = (c < 64) ? c + 64 : c - 64;
        cvt4(W_ih + r * 128 + c, wcat_t + (bn * 5) * 8192 + (cd >> 3) * 512 + row64 * 8 + (cd & 7));
        return;
    }
    t -= 65536;
    if (t < 262144) {  // W_hh -> wcat_t[bn][kt1..4][oct][row64]
        int r = t >> 7, c = (t & 127) * 4;
        int g = r >> 9, j = r & 511;
        int bn = j >> 4, row64 = (g << 4) + (j & 15);
        int cd = 128 + c;
        cvt4(W_hh + r * 512 + c, wcat_t + (bn * 5 + (cd >> 7)) * 8192 + ((cd >> 3) & 15) * 512 + row64 * 8 + (cd & 7));
        return;
    }
    t -= 262144;
    if (t < 131072) {  // W_read -> Wcat2_t bn 0..15
        int r = t >> 7, c = (t & 127) * 4;
        cvt4(W_read + t * 4, Wcat2_t + ((r >> 6) * 4 + (c >> 7)) * 8192 + ((c >> 3) & 15) * 512 + (r & 63) * 8 + (c & 7));
        return;
    }
    t -= 131072;
    if (t < 131072) {  // W_write -> bn 16..31
        int r = t >> 7, c = (t & 127) * 4;
        cvt4(W_write + t * 4, Wcat2_t + ((16 + (r >> 6)) * 4 + (c >> 7)) * 8192 + ((c >> 3) & 15) * 512 + (r & 63) * 8 + (c & 7));
        return;
    }
    t -= 131072;
    if (t < 8192) {  // W_erase -> bn 32
        int r = t >> 7, c = (t & 127) * 4;
        cvt4(W_erase + t * 4, Wcat2_t + (32 * 4 + (c >> 7)) * 8192 + ((c >> 3) & 15) * 512 + r * 8 + (c & 7));
        return;
    }
    t -= 8192;
    if (t < 8192) {  // W_add -> bn 33
        int r = t >> 7, c = (t & 127) * 4;
        cvt4(W_add + t * 4, Wcat2_t + (33 * 4 + (c >> 7)) * 8192 + ((c >> 3) & 15) * 512 + r * 8 + (c & 7));
        return;
    }
    t -= 8192;
    if (t < 9216) {  // W_out: h-part -> bn 34; rn-part -> Wo_rn
        int r = t / 144, c = (t % 144) * 4;
        if (c < 512)
            cvt4(W_out + r * 576 + c, Wcat2_t + (34 * 4 + (c >> 7)) * 8192 + ((c >> 3) & 15) * 512 + r * 8 + (c & 7));
        else
            cvt4(W_out + r * 576 + c, Wo_rn + r * 64 + (c - 512));
        return;
    }
    t -= 9216;
    {  // memory^T -> memt (64 x 1024)
        int v = t >> 8, m = (t & 255) * 4;
        pack_store4(memory[m * 64 + v], memory[(m + 1) * 64 + v],
                    memory[(m + 2) * 64 + v], memory[(m + 3) * 64 + v], memt + v * 1024 + m);
    }
}

__global__ __launch_bounds__(256, 2) void k_fused(
    const float* __restrict__ x, const float* __restrict__ h_prev, const float* __restrict__ c_prev,
    const float* __restrict__ rwp, const float* __restrict__ memory,
    const float* __restrict__ W_ih, const float* __restrict__ b_ih,
    const float* __restrict__ W_hh, const float* __restrict__ b_hh,
    const float* __restrict__ W_read, const float* __restrict__ b_read,
    const float* __restrict__ W_write, const float* __restrict__ b_write,
    const float* __restrict__ W_erase, const float* __restrict__ b_erase,
    const float* __restrict__ W_add, const float* __restrict__ b_add,
    const float* __restrict__ W_out, const float* __restrict__ b_out,
    float* __restrict__ out, char* __restrict__ wsp)
{
    __shared__ __align__(16) char smem[SMEM_BYTES];

    u16*   x_t     = (u16*)(wsp + 0);           // 16 x 8oct x 128row x 8  (256 KB)
    u16*   ht_t    = (u16*)(wsp + 262144);      // 16 x 64oct x 128row x 8 (2 MB)
    u16*   wcat_t  = (u16*)(wsp + 2359296);     // 32bn x 5kt x 16oct x 64row x 8
    u16*   memt    = (u16*)(wsp + 4980736);     // 64 x 1024 bf16 memory^T
    u16*   Wcat2_t = (u16*)(wsp + 5111808);     // 35bn x 4kt x 16oct x 64row x 8
    u16*   Wo_rn   = (u16*)(wsp + 7405568);     // 64x64 bf16
    float* rp      = (float*)(wsp + 7413760);   // 4 x 2048x64 fp32 split-K partials
    u16*   hrn_t   = (u16*)(wsp + 9510912);     // 16 x 64oct x 128row x 8 (2 MB)
    u16*   pre_r   = (u16*)(wsp + 11608064);    // 2048x1024 bf16
    u16*   pre_w   = (u16*)(wsp + 15802368);    // 2048x1024 bf16
    float* erase   = (float*)(wsp + 19996672);  // 2048x64 fp32
    float* add     = (float*)(wsp + 20520960);  // 2048x64 fp32

    const int bid = blockIdx.x;
    const int tid = threadIdx.x, w = tid >> 6, lane = tid & 63;
    const int lrow = lane & 15, lq = lane >> 4;

    // ======================= phase 0: pre =======================
    if (bid < 128) {
        u16* As = (u16*)smem;                 // 64 x LDW
        u16* Bs = (u16*)(smem + 64 * LDW * 2);
        const int mb = bid & 31, ks = bid >> 5;
        const int m0 = mb * 64, k0 = ks * 256;
        const int m_loc = tid >> 1, v0 = (tid & 1) * 32;
        f32x4 acc[4] = {};
        for (int kt = 0; kt < 2; ++kt) {
#pragma unroll
            for (int i = 0; i < 4; ++i) {
                int idx = i * 256 + tid, r = idx >> 4, c = (idx & 15) * 8;
                *(uint4*)(&As[r * LDW + c]) = cvt8u(rwp + (m0 + r) * 1024 + k0 + kt * 128 + c);
            }
#pragma unroll
            for (int j = 0; j < 8; ++j) {
                float4 q = *(const float4*)(memory + (k0 + kt * 128 + m_loc) * 64 + v0 + 4 * j);
                Bs[(v0 + 4 * j + 0) * LDW + m_loc] = f2bf(q.x);
                Bs[(v0 + 4 * j + 1) * LDW + m_loc] = f2bf(q.y);
                Bs[(v0 + 4 * j + 2) * LDW + m_loc] = f2bf(q.z);
                Bs[(v0 + 4 * j + 3) * LDW + m_loc] = f2bf(q.w);
            }
            __syncthreads();
#pragma unroll
            for (int kk = 0; kk < 128; kk += 32) {
                bf16x8 a  = *(const bf16x8*)(&As[(16 * w + lrow) * LDW + kk + 8 * lq]);
                bf16x8 b0 = *(const bf16x8*)(&Bs[(lrow) * LDW + kk + 8 * lq]);
                bf16x8 b1 = *(const bf16x8*)(&Bs[(16 + lrow) * LDW + kk + 8 * lq]);
                bf16x8 b2 = *(const bf16x8*)(&Bs[(32 + lrow) * LDW + kk + 8 * lq]);
                bf16x8 b3 = *(const bf16x8*)(&Bs[(48 + lrow) * LDW + kk + 8 * lq]);
                acc[0] = MFMA_BF16(a, b0, acc[0]);
                acc[1] = MFMA_BF16(a, b1, acc[1]);
                acc[2] = MFMA_BF16(a, b2, acc[2]);
                acc[3] = MFMA_BF16(a, b3, acc[3]);
            }
            __syncthreads();
        }
        float* rps = rp + ks * 131072;
#pragma unroll
        for (int nj = 0; nj < 4; ++nj)
#pragma unroll
            for (int r = 0; r < 4; ++r) {
                int row = m0 + 16 * w + 4 * lq + r, col = 16 * nj + lrow;
                rps[row * 64 + col] = acc[nj][r];
            }
    } else {
        for (int t = (bid - 128) * 256 + tid; t < 926720; t += 384 * 256)
            convert_unit(t, x, h_prev, W_ih, W_hh, W_read, W_write, W_erase, W_add,
                         W_out, memory, x_t, ht_t, wcat_t, Wcat2_t, Wo_rn, memt);
    }
    grid_barrier(0);

    // ======================= phase 1: gates =======================
    {
        u16* AsG = (u16*)smem;                 // 2 x 8192 u16
        u16* BsG = (u16*)(smem + 32768);       // 2 x 4096 u16
        const int mt = bid & 15, bn = bid >> 4;
        const int m0 = mt * 128;
        f32x4 acc[2][4] = {};

        // prologue: tile 0 = rp strip (K 0..63). A via VGPR sum4-cvt, B via DMA.
#pragma unroll
        for (int i = 0; i < 4; ++i) {
            int cp = i * 256 + tid;
            *(uint4*)(&AsG[cp * 8]) = cvt8u_sum4(rp, (m0 + (cp & 127)) * 64 + (cp >> 7) * 8);
        }
#pragma unroll
        for (int i = 0; i < 2; ++i) {
            dma16(wcat_t + (bn * 5) * 8192 + (i * 256 + tid) * 8, &BsG[(i * 256 + w * 64) * 8]);
        }

#pragma unroll
        for (int t = 0; t < 10; ++t) {
            if (t < 9) {
                const int tn = t + 1, b = tn & 1;
                const u16* asrc = (tn == 1) ? (x_t + mt * 8192)
                                            : (ht_t + mt * 65536 + (tn - 2) * 8192);
#pragma unroll
                for (int i = 0; i < 4; ++i)
                    dma16(asrc + (i * 256 + tid) * 8, &AsG[b * 8192 + (i * 256 + w * 64) * 8]);
#pragma unroll
                for (int i = 0; i < 2; ++i)
                    dma16(wcat_t + (bn * 5 + (tn >> 1)) * 8192 + (tn & 1) * 4096 + (i * 256 + tid) * 8,
                          &BsG[b * 4096 + (i * 256 + w * 64) * 8]);
                PIPE_BAR_PRE_CNT();
            } else {
                PIPE_BAR_PRE_ZERO();
            }
            const int b = t & 1;
#pragma unroll
            for (int kk = 0; kk < 64; kk += 32) {
                const int ob = (kk >> 3) + lq;
                bf16x8 a0 = *(const bf16x8*)(&AsG[b * 8192 + ob * 1024 + (32 * w + lrow) * 8]);
                bf16x8 a1 = *(const bf16x8*)(&AsG[b * 8192 + ob * 1024 + (32 * w + 16 + lrow) * 8]);
                bf16x8 b0 = *(const bf16x8*)(&BsG[b * 4096 + ob * 512 + (lrow) * 8]);
                bf16x8 b1 = *(const bf16x8*)(&BsG[b * 4096 + ob * 512 + (16 + lrow) * 8]);
                bf16x8 b2 = *(const bf16x8*)(&BsG[b * 4096 + ob * 512 + (32 + lrow) * 8]);
                bf16x8 b3 = *(const bf16x8*)(&BsG[b * 4096 + ob * 512 + (48 + lrow) * 8]);
                acc[0][0] = MFMA_BF16(a0, b0, acc[0][0]);
                acc[0][1] = MFMA_BF16(a0, b1, acc[0][1]);
                acc[0][2] = MFMA_BF16(a0, b2, acc[0][2]);
                acc[0][3] = MFMA_BF16(a0, b3, acc[0][3]);
                acc[1][0] = MFMA_BF16(a1, b0, acc[1][0]);
                acc[1][1] = MFMA_BF16(a1, b1, acc[1][1]);
                acc[1][2] = MFMA_BF16(a1, b2, acc[1][2]);
                acc[1][3] = MFMA_BF16(a1, b3, acc[1][3]);
            }
            PIPE_BAR_POST();
        }

        const int j = bn * 16 + lrow;
        const float bI = b_ih[j] + b_hh[j];
        const float bF = b_ih[512 + j] + b_hh[512 + j];
        const float bG = b_ih[1024 + j] + b_hh[1024 + j];
        const float bO = b_ih[1536 + j] + b_hh[1536 + j];
#pragma unroll
        for (int mi = 0; mi < 2; ++mi)
#pragma unroll
            for (int r = 0; r < 4; ++r) {
                int row = m0 + 32 * w + 16 * mi + 4 * lq + r;
                float ig = sigf(acc[mi][0][r] + bI);
                float fg = sigf(acc[mi][1][r] + bF);
                float gg = fast_tanh(acc[mi][2][r] + bG);
                float og = sigf(acc[mi][3][r] + bO);
                float c = fg * c_prev[row * 512 + j] + ig * gg;
                hrn_t[(row >> 7) * 65536 + (j >> 3) * 1024 + (row & 127) * 8 + (j & 7)] =
                    f2bf(og * fast_tanh(c));
            }
    }
    grid_barrier(1);

    // ======================= phase 2: heads =======================
    for (int tile = bid; tile < 560; tile += 512) {
        u16* AsG = (u16*)smem;
        u16* BsG = (u16*)(smem + 32768);
        const int mt = tile & 15, bn = tile >> 4;
        const int m0 = mt * 128;
        f32x4 acc[2][4] = {};

#pragma unroll
        for (int i = 0; i < 4; ++i)
            dma16(hrn_t + mt * 65536 + (i * 256 + tid) * 8, &AsG[(i * 256 + w * 64) * 8]);
#pragma unroll
        for (int i = 0; i < 2; ++i)
            dma16(Wcat2_t + (bn * 4) * 8192 + (i * 256 + tid) * 8, &BsG[(i * 256 + w * 64) * 8]);

#pragma unroll
        for (int t = 0; t < 8; ++t) {
            if (t < 7) {
                const int tn = t + 1, b = tn & 1;
#pragma unroll
                for (int i = 0; i < 4; ++i)
                    dma16(hrn_t + mt * 65536 + tn * 8192 + (i * 256 + tid) * 8,
                          &AsG[b * 8192 + (i * 256 + w * 64) * 8]);
#pragma unroll
                for (int i = 0; i < 2; ++i)
                    dma16(Wcat2_t + (bn * 4 + (tn >> 1)) * 8192 + (tn & 1) * 4096 + (i * 256 + tid) * 8,
                          &BsG[b * 4096 + (i * 256 + w * 64) * 8]);
                PIPE_BAR_PRE_CNT();
            } else {
                PIPE_BAR_PRE_ZERO();
            }
            const int b = t & 1;
#pragma unroll
            for (int kk = 0; kk < 64; kk += 32) {
                const int ob = (kk >> 3) + lq;
                bf16x8 a0 = *(const bf16x8*)(&AsG[b * 8192 + ob * 1024 + (32 * w + lrow) * 8]);
                bf16x8 a1 = *(const bf16x8*)(&AsG[b * 8192 + ob * 1024 + (32 * w + 16 + lrow) * 8]);
                bf16x8 b0 = *(const bf16x8*)(&BsG[b * 4096 + ob * 512 + (lrow) * 8]);
                bf16x8 b1 = *(const bf16x8*)(&BsG[b * 4096 + ob * 512 + (16 + lrow) * 8]);
                bf16x8 b2 = *(const bf16x8*)(&BsG[b * 4096 + ob * 512 + (32 + lrow) * 8]);
                bf16x8 b3 = *(const bf16x8*)(&BsG[b * 4096 + ob * 512 + (48 + lrow) * 8]);
                acc[0][0] = MFMA_BF16(a0, b0, acc[0][0]);
                acc[0][1] = MFMA_BF16(a0, b1, acc[0][1]);
                acc[0][2] = MFMA_BF16(a0, b2, acc[0][2]);
                acc[0][3] = MFMA_BF16(a0, b3, acc[0][3]);
                acc[1][0] = MFMA_BF16(a1, b0, acc[1][0]);
                acc[1][1] = MFMA_BF16(a1, b1, acc[1][1]);
                acc[1][2] = MFMA_BF16(a1, b2, acc[1][2]);
                acc[1][3] = MFMA_BF16(a1, b3, acc[1][3]);
            }
            PIPE_BAR_POST();
        }

#pragma unroll
        for (int mi = 0; mi < 2; ++mi)
#pragma unroll
            for (int nj = 0; nj < 4; ++nj)
#pragma unroll
                for (int r = 0; r < 4; ++r) {
                    int row = m0 + 32 * w + 16 * mi + 4 * lq + r;
                    int col = bn * 64 + 16 * nj + lrow;
                    float v = acc[mi][nj][r];
                    if (bn < 16)       pre_r[row * 1024 + col] = f2bf(v + b_read[col]);
                    else if (bn < 32)  pre_w[row * 1024 + (col - 1024)] = f2bf(v + b_write[col - 1024]);
                    else if (bn == 32) erase[row * 64 + (col - 2048)] = sigf(v + b_erase[col - 2048]);
                    else if (bn == 33) add[row * 64 + (col - 2112)] = fast_tanh(v + b_add[col - 2112]);
                    else               out[row * 64 + (col - 2176)] = v + b_out[col - 2176];
                }
    }
    grid_barrier(2);

    // ======================= phase 3: tail =======================
    if (bid < 256) {
        u16*   rwS  = (u16*)smem;                    // 16 x SLDW
        u16*   rw2S = (u16*)(smem + 16640);          // 16 x SLDW
        u16*   BsP  = (u16*)(smem + 33280);          // 64 x LDW
        u16*   Ps   = (u16*)(smem + 50688);          // 16 x 72
        float* s_sh = (float*)(smem + 52992);        // 16
        const int mb = bid >> 1, kh = bid & 1;
        const int m0 = mb * 16, k0 = kh * 512;

        {
            const int row = tid >> 4, c16 = tid & 15;
            const int row_g = m0 + row;
            const u16* prp = pre_r + row_g * 1024;
            const u16* pwp = pre_w + row_g * 1024;
            float vr[64], vw[64];
#pragma unroll
            for (int q = 0; q < 8; ++q) {
                bfu4_to_f8(*(const uint4*)(prp + q * 128 + c16 * 8), vr + 8 * q);
                bfu4_to_f8(*(const uint4*)(pwp + q * 128 + c16 * 8), vw + 8 * q);
            }
            float mr = vr[0], mw = vw[0];
#pragma unroll
            for (int i = 1; i < 64; ++i) { mr = fmaxf(mr, vr[i]); mw = fmaxf(mw, vw[i]); }
#pragma unroll
            for (int o = 1; o < 16; o <<= 1) {
                mr = fmaxf(mr, __shfl_xor(mr, o, 64));
                mw = fmaxf(mw, __shfl_xor(mw, o, 64));
            }
            float sr = 0.f, sw = 0.f;
#pragma unroll
            for (int i = 0; i < 64; ++i) {
                vr[i] = __expf(vr[i] - mr); sr += vr[i];
                vw[i] = __expf(vw[i] - mw); sw += vw[i];
            }
#pragma unroll
            for (int o = 1; o < 16; o <<= 1) {
                sr += __shfl_xor(sr, o, 64);
                sw += __shfl_xor(sw, o, 64);
            }
            const float isr = 1.f / sr, isw = 1.f / sw;
            float ss = 0.f;
#pragma unroll
            for (int q = 0; q < 8; ++q) {
                float a8[8], r8[8];
#pragma unroll
                for (int i = 0; i < 8; ++i) {
                    float a = vr[8 * q + i] * isr;
                    float r2 = a * (vw[8 * q + i] * isw);
                    a8[i] = a; r8[i] = r2;
                    ss += r2;
                }
                if ((q >> 2) == kh) {
                    int cb = (q - 4 * kh) * 128 + c16 * 8;
                    *(uint4*)(&rwS[row * SLDW + cb])  = pack8(a8);
                    *(uint4*)(&rw2S[row * SLDW + cb]) = pack8(r8);
                }
            }
#pragma unroll
            for (int o = 1; o < 16; o <<= 1) ss += __shfl_xor(ss, o, 64);
            if (c16 == 0) s_sh[row] = ss;
        }
        __syncthreads();

        f32x4 acc1 = {}, acc2 = {};
        for (int kt = 0; kt < 4; ++kt) {
#pragma unroll
            for (int i = 0; i < 4; ++i) {
                int idx = i * 256 + tid, r = idx >> 4, c = (idx & 15) * 8;
                *(uint4*)(&BsP[r * LDW + c]) = *(const uint4*)(memt + r * 1024 + k0 + kt * 128 + c);
            }
            __syncthreads();
#pragma unroll
            for (int kk = 0; kk < 128; kk += 32) {
                bf16x8 a1 = *(const bf16x8*)(&rwS[lrow * SLDW + kt * 128 + kk + 8 * lq]);
                bf16x8 a2 = *(const bf16x8*)(&rw2S[lrow * SLDW + kt * 128 + kk + 8 * lq]);
                bf16x8 b  = *(const bf16x8*)(&BsP[(16 * w + lrow) * LDW + kk + 8 * lq]);
                acc1 = MFMA_BF16(a1, b, acc1);
                acc2 = MFMA_BF16(a2, b, acc2);
            }
            __syncthreads();
        }

#pragma unroll
        for (int r = 0; r < 4; ++r) {
            int row_l = 4 * lq + r, col = 16 * w + lrow;
            int row_g = m0 + row_l;
            float p = acc1[r] - erase[row_g * 64 + col] * acc2[r];
            if (kh == 0) p += add[row_g * 64 + col] * s_sh[row_l];
            Ps[row_l * 72 + col] = f2bf(p);
        }
#pragma unroll
        for (int i = 0; i < 2; ++i) {
            int idx = i * 256 + tid, r = idx >> 3, c = (idx & 7) * 8;
            *(uint4*)(&BsP[r * LDW + c]) = *(const uint4*)(Wo_rn + r * 64 + c);
        }
        __syncthreads();

        f32x4 acc3 = {};
#pragma unroll
        for (int kk = 0; kk < 64; kk += 32) {
            bf16x8 a = *(const bf16x8*)(&Ps[lrow * 72 + kk + 8 * lq]);
            bf16x8 b = *(const bf16x8*)(&BsP[(16 * w + lrow) * LDW + kk + 8 * lq]);
            acc3 = MFMA_BF16(a, b, acc3);
        }
#pragma unroll
        for (int r = 0; r < 4; ++r) {
            int row_g = m0 + 4 * lq + r, col = 16 * w + lrow;
            atomicAdd(&out[row_g * 64 + col], acc3[r]);
        }
    }
}

extern "C" void kernel_launch(void* const* d_in, const int* in_sizes, int n_in,
                              void* d_out, int out_size, void* d_ws, size_t ws_size,
                              hipStream_t stream)
{
    const float* x        = (const float*)d_in[0];
    const float* h_prev   = (const float*)d_in[1];
    const float* c_prev   = (const float*)d_in[2];
    const float* rwp      = (const float*)d_in[3];
    const float* memory   = (const float*)d_in[4];
    const float* W_ih     = (const float*)d_in[5];
    const float* b_ih     = (const float*)d_in[6];
    const float* W_hh     = (const float*)d_in[7];
    const float* b_hh     = (const float*)d_in[8];
    const float* W_read   = (const float*)d_in[9];
    const float* b_read   = (const float*)d_in[10];
    const float* W_write  = (const float*)d_in[11];
    const float* b_write  = (const float*)d_in[12];
    const float* W_erase  = (const float*)d_in[13];
    const float* b_erase  = (const float*)d_in[14];
    const float* W_add    = (const float*)d_in[15];
    const float* b_add    = (const float*)d_in[16];
    const float* W_out    = (const float*)d_in[17];
    const float* b_out    = (const float*)d_in[18];
    float* out = (float*)d_out;
    char* wsp = (char*)d_ws;

    k_fused<<<dim3(512), dim3(256), 0, stream>>>(
        x, h_prev, c_prev, rwp, memory, W_ih, b_ih, W_hh, b_hh,
        W_read, b_read, W_write, b_write, W_erase, b_erase, W_add, b_add,
        W_out, b_out, out, wsp);
}

// Round 4
// 212.898 us; speedup vs baseline: 1.9636x; 1.9636x over previous
//
#include <hip/hip_runtime.h>
#include <hip/hip_bf16.h>

// NTM cell on MI355X. B=2048, IN=64, CTRL=512, M=1024, V=64, OUT=64.
// Single kernel, 512 blocks x 256 threads, 4 phases separated by a
// HIERARCHICAL device-scope grid barrier (round-3 post-mortem: the flat
// single-counter barrier + all-thread fences cost ~90us/barrier; counters
// showed 95% idle). New barrier: 16 group counters (32 blocks each, 256B
// apart) -> 1 root; RELEASE on adds (one wbl2 per block), RELAXED polls,
// one ACQUIRE load per block (one buffer_inv, covers CU-shared L1).
// Monotonic tickets -> no reset across graph replays.
//   phase0: blocks 0..127 split-K read_prev GEMM; blocks 128..511 grid-stride
//           fp32->bf16 converts to tile-major layouts
//   phase1: gates GEMM + fused LSTM (512 tiles, 1/block), 2-phase dbuf pipeline
//   phase2: heads GEMM (560 tiles, strided over 512 blocks)
//   phase3: tail softmax + read_new + out-GEMM (256 tiles)
// Co-residency: 52KB LDS -> 3 blocks/CU; __launch_bounds__(256,2) -> 2/CU
// guaranteed; grid 512 = 2 x 256 CUs, so all blocks resident (no deadlock).

typedef unsigned short u16;
typedef __attribute__((ext_vector_type(8))) short bf16x8;
typedef __attribute__((ext_vector_type(4))) float f32x4;

#define MFMA_BF16(a, b, c) __builtin_amdgcn_mfma_f32_16x16x32_bf16((a), (b), (c), 0, 0, 0)
#define LDW 136
#define SLDW 520
#define SMEM_BYTES 53248

// Barrier state: 3 barriers x 16 group counters (64-uint = 256B stride) + root.
__device__ unsigned g_grp[3 * 16 * 64];
__device__ unsigned g_root[3 * 64];

__device__ __forceinline__ void grid_barrier(int idx) {
    __syncthreads();                      // all block stores drained (vmcnt 0)
    if (threadIdx.x == 0) {
        const int grp = blockIdx.x >> 5;  // 16 groups of 32 blocks
        unsigned t = __hip_atomic_fetch_add(&g_grp[(idx * 16 + grp) * 64], 1u,
                          __ATOMIC_RELEASE, __HIP_MEMORY_SCOPE_AGENT);
        unsigned r = t >> 5;              // round number (monotonic per launch)
        if ((t & 31u) == 31u)             // last of this group this round
            __hip_atomic_fetch_add(&g_root[idx * 64], 1u,
                                   __ATOMIC_RELEASE, __HIP_MEMORY_SCOPE_AGENT);
        const unsigned target = r * 16u + 16u;
        while (__hip_atomic_load(&g_root[idx * 64], __ATOMIC_RELAXED,
                                 __HIP_MEMORY_SCOPE_AGENT) < target)
            __builtin_amdgcn_s_sleep(8);
        unsigned v = __hip_atomic_load(&g_root[idx * 64], __ATOMIC_ACQUIRE,
                                       __HIP_MEMORY_SCOPE_AGENT);
        asm volatile("" :: "v"(v));       // keep acquire load live
    }
    __syncthreads();
}

__device__ __forceinline__ void dma16(const void* g, void* l) {
    __builtin_amdgcn_global_load_lds(
        (const __attribute__((address_space(1))) unsigned int*)g,
        (__attribute__((address_space(3))) unsigned int*)l, 16, 0, 0);
}

__device__ __forceinline__ u16 f2bf(float f) {
    union { float f; unsigned int u; } a; a.f = f;
    return (u16)((a.u + 0x7FFFu + ((a.u >> 16) & 1u)) >> 16);
}

__device__ __forceinline__ void pack_store4(float a0, float a1, float a2, float a3, u16* d) {
    union { __hip_bfloat162 h[2]; uint2 u; } cv;
    cv.h[0] = __float22bfloat162_rn(make_float2(a0, a1));
    cv.h[1] = __float22bfloat162_rn(make_float2(a2, a3));
    *(uint2*)d = cv.u;
}

__device__ __forceinline__ void cvt4(const float* __restrict__ s, u16* __restrict__ d) {
    float4 v = *(const float4*)s;
    pack_store4(v.x, v.y, v.z, v.w, d);
}

__device__ __forceinline__ uint4 cvt8u(const float* __restrict__ s) {
    float4 v0 = *(const float4*)(s);
    float4 v1 = *(const float4*)(s + 4);
    union { __hip_bfloat162 h[4]; uint4 u; } r;
    r.h[0] = __float22bfloat162_rn(make_float2(v0.x, v0.y));
    r.h[1] = __float22bfloat162_rn(make_float2(v0.z, v0.w));
    r.h[2] = __float22bfloat162_rn(make_float2(v1.x, v1.y));
    r.h[3] = __float22bfloat162_rn(make_float2(v1.z, v1.w));
    return r.u;
}

__device__ __forceinline__ uint4 cvt8u_sum4(const float* __restrict__ p, int off) {
    float4 a0 = *(const float4*)(p + off);
    float4 a1 = *(const float4*)(p + 131072 + off);
    float4 a2 = *(const float4*)(p + 262144 + off);
    float4 a3 = *(const float4*)(p + 393216 + off);
    float4 b0 = *(const float4*)(p + off + 4);
    float4 b1 = *(const float4*)(p + 131072 + off + 4);
    float4 b2 = *(const float4*)(p + 262144 + off + 4);
    float4 b3 = *(const float4*)(p + 393216 + off + 4);
    float4 s0{a0.x + a1.x + a2.x + a3.x, a0.y + a1.y + a2.y + a3.y,
              a0.z + a1.z + a2.z + a3.z, a0.w + a1.w + a2.w + a3.w};
    float4 s1{b0.x + b1.x + b2.x + b3.x, b0.y + b1.y + b2.y + b3.y,
              b0.z + b1.z + b2.z + b3.z, b0.w + b1.w + b2.w + b3.w};
    union { __hip_bfloat162 h[4]; uint4 u; } r;
    r.h[0] = __float22bfloat162_rn(make_float2(s0.x, s0.y));
    r.h[1] = __float22bfloat162_rn(make_float2(s0.z, s0.w));
    r.h[2] = __float22bfloat162_rn(make_float2(s1.x, s1.y));
    r.h[3] = __float22bfloat162_rn(make_float2(s1.z, s1.w));
    return r.u;
}

__device__ __forceinline__ void bfu4_to_f8(uint4 u, float* f) {
    f[0] = __uint_as_float(u.x << 16); f[1] = __uint_as_float(u.x & 0xffff0000u);
    f[2] = __uint_as_float(u.y << 16); f[3] = __uint_as_float(u.y & 0xffff0000u);
    f[4] = __uint_as_float(u.z << 16); f[5] = __uint_as_float(u.z & 0xffff0000u);
    f[6] = __uint_as_float(u.w << 16); f[7] = __uint_as_float(u.w & 0xffff0000u);
}

__device__ __forceinline__ uint4 pack8(const float* v) {
    union { __hip_bfloat162 h[4]; uint4 u; } r;
#pragma unroll
    for (int j = 0; j < 4; ++j) r.h[j] = __float22bfloat162_rn(make_float2(v[2 * j], v[2 * j + 1]));
    return r.u;
}

__device__ __forceinline__ float sigf(float x) { return 1.f / (1.f + __expf(-x)); }
__device__ __forceinline__ float fast_tanh(float x) { return 1.f - 2.f / (__expf(2.f * x) + 1.f); }

#define PIPE_BAR_PRE_CNT()  do {                                              \
    asm volatile("s_waitcnt vmcnt(6) lgkmcnt(0)" ::: "memory");               \
    __builtin_amdgcn_s_barrier();                                             \
    __builtin_amdgcn_sched_barrier(0);                                        \
} while (0)
#define PIPE_BAR_PRE_ZERO() do {                                              \
    asm volatile("s_waitcnt vmcnt(0) lgkmcnt(0)" ::: "memory");               \
    __builtin_amdgcn_s_barrier();                                             \
    __builtin_amdgcn_sched_barrier(0);                                        \
} while (0)
#define PIPE_BAR_POST() do {                                                  \
    __builtin_amdgcn_sched_barrier(0);                                        \
    asm volatile("s_waitcnt lgkmcnt(0)" ::: "memory");                        \
    __builtin_amdgcn_s_barrier();                                             \
    __builtin_amdgcn_sched_barrier(0);                                        \
} while (0)

// One fp32->bf16 tile-major convert unit, t in [0, 926720).
__device__ __forceinline__ void convert_unit(int t,
    const float* __restrict__ x, const float* __restrict__ h_prev,
    const float* __restrict__ W_ih, const float* __restrict__ W_hh,
    const float* __restrict__ W_read, const float* __restrict__ W_write,
    const float* __restrict__ W_erase, const float* __restrict__ W_add,
    const float* __restrict__ W_out, const float* __restrict__ memory,
    u16* x_t, u16* ht_t, u16* wcat_t, u16* Wcat2_t, u16* Wo_rn, u16* memt)
{
    if (t < 32768) {  // x -> x_t[mt][oct8][row128]
        int r = t >> 4, c = (t & 15) * 4;
        cvt4(x + r * 64 + c, x_t + ((r >> 7) * 8 + (c >> 3)) * 1024 + (r & 127) * 8 + (c & 7));
        return;
    }
    t -= 32768;
    if (t < 262144) {  // h_prev -> ht_t[mt][oct64][row128]
        int r = t >> 7, c = (t & 127) * 4;
        cvt4(h_prev + r * 512 + c, ht_t + ((r >> 7) * 64 + (c >> 3)) * 1024 + (r & 127) * 8 + (c & 7));
        return;
    }
    t -= 262144;
    if (t < 65536) {  // W_ih (gate-interleave rows, col swap rp|x) -> wcat_t[bn][kt0][oct][row64]
        int r = t >> 5, c = (t & 31) * 4;
        int g = r >> 9, j = r & 511;
        int bn = j >> 4, row64 = (g << 4) + (j & 15);
        int cd = (c < 64) ? c + 64 : c - 64;
        cvt4(W_ih + r * 128 + c, wcat_t + (bn * 5) * 8192 + (cd >> 3) * 512 + row64 * 8 + (cd & 7));
        return;
    }
    t -= 65536;
    if (t < 262144) {  // W_hh -> wcat_t[bn][kt1..4][oct][row64]
        int r = t >> 7, c = (t & 127) * 4;
        int g = r >> 9, j = r & 511;
        int bn = j >> 4, row64 = (g << 4) + (j & 15);
        int cd = 128 + c;
        cvt4(W_hh + r * 512 + c, wcat_t + (bn * 5 + (cd >> 7)) * 8192 + ((cd >> 3) & 15) * 512 + row64 * 8 + (cd & 7));
        return;
    }
    t -= 262144;
    if (t < 131072) {  // W_read -> Wcat2_t bn 0..15
        int r = t >> 7, c = (t & 127) * 4;
        cvt4(W_read + t * 4, Wcat2_t + ((r >> 6) * 4 + (c >> 7)) * 8192 + ((c >> 3) & 15) * 512 + (r & 63) * 8 + (c & 7));
        return;
    }
    t -= 131072;
    if (t < 131072) {  // W_write -> bn 16..31
        int r = t >> 7, c = (t & 127) * 4;
        cvt4(W_write + t * 4, Wcat2_t + ((16 + (r >> 6)) * 4 + (c >> 7)) * 8192 + ((c >> 3) & 15) * 512 + (r & 63) * 8 + (c & 7));
        return;
    }
    t -= 131072;
    if (t < 8192) {  // W_erase -> bn 32
        int r = t >> 7, c = (t & 127) * 4;
        cvt4(W_erase + t * 4, Wcat2_t + (32 * 4 + (c >> 7)) * 8192 + ((c >> 3) & 15) * 512 + r * 8 + (c & 7));
        return;
    }
    t -= 8192;
    if (t < 8192) {  // W_add -> bn 33
        int r = t >> 7, c = (t & 127) * 4;
        cvt4(W_add + t * 4, Wcat2_t + (33 * 4 + (c >> 7)) * 8192 + ((c >> 3) & 15) * 512 + r * 8 + (c & 7));
        return;
    }
    t -= 8192;
    if (t < 9216) {  // W_out: h-part -> bn 34; rn-part -> Wo_rn
        int r = t / 144, c = (t % 144) * 4;
        if (c < 512)
            cvt4(W_out + r * 576 + c, Wcat2_t + (34 * 4 + (c >> 7)) * 8192 + ((c >> 3) & 15) * 512 + r * 8 + (c & 7));
        else
            cvt4(W_out + r * 576 + c, Wo_rn + r * 64 + (c - 512));
        return;
    }
    t -= 9216;
    {  // memory^T -> memt (64 x 1024)
        int v = t >> 8, m = (t & 255) * 4;
        pack_store4(memory[m * 64 + v], memory[(m + 1) * 64 + v],
                    memory[(m + 2) * 64 + v], memory[(m + 3) * 64 + v], memt + v * 1024 + m);
    }
}

__global__ __launch_bounds__(256, 2) void k_fused(
    const float* __restrict__ x, const float* __restrict__ h_prev, const float* __restrict__ c_prev,
    const float* __restrict__ rwp, const float* __restrict__ memory,
    const float* __restrict__ W_ih, const float* __restrict__ b_ih,
    const float* __restrict__ W_hh, const float* __restrict__ b_hh,
    const float* __restrict__ W_read, const float* __restrict__ b_read,
    const float* __restrict__ W_write, const float* __restrict__ b_write,
    const float* __restrict__ W_erase, const float* __restrict__ b_erase,
    const float* __restrict__ W_add, const float* __restrict__ b_add,
    const float* __restrict__ W_out, const float* __restrict__ b_out,
    float* __restrict__ out, char* __restrict__ wsp)
{
    __shared__ __align__(16) char smem[SMEM_BYTES];

    u16*   x_t     = (u16*)(wsp + 0);           // 16 x 8oct x 128row x 8  (256 KB)
    u16*   ht_t    = (u16*)(wsp + 262144);      // 16 x 64oct x 128row x 8 (2 MB)
    u16*   wcat_t  = (u16*)(wsp + 2359296);     // 32bn x 5kt x 16oct x 64row x 8
    u16*   memt    = (u16*)(wsp + 4980736);     // 64 x 1024 bf16 memory^T
    u16*   Wcat2_t = (u16*)(wsp + 5111808);     // 35bn x 4kt x 16oct x 64row x 8
    u16*   Wo_rn   = (u16*)(wsp + 7405568);     // 64x64 bf16
    float* rp      = (float*)(wsp + 7413760);   // 4 x 2048x64 fp32 split-K partials
    u16*   hrn_t   = (u16*)(wsp + 9510912);     // 16 x 64oct x 128row x 8 (2 MB)
    u16*   pre_r   = (u16*)(wsp + 11608064);    // 2048x1024 bf16
    u16*   pre_w   = (u16*)(wsp + 15802368);    // 2048x1024 bf16
    float* erase   = (float*)(wsp + 19996672);  // 2048x64 fp32
    float* add     = (float*)(wsp + 20520960);  // 2048x64 fp32

    const int bid = blockIdx.x;
    const int tid = threadIdx.x, w = tid >> 6, lane = tid & 63;
    const int lrow = lane & 15, lq = lane >> 4;

    // ======================= phase 0: pre =======================
    if (bid < 128) {
        u16* As = (u16*)smem;                 // 64 x LDW
        u16* Bs = (u16*)(smem + 64 * LDW * 2);
        const int mb = bid & 31, ks = bid >> 5;
        const int m0 = mb * 64, k0 = ks * 256;
        const int m_loc = tid >> 1, v0 = (tid & 1) * 32;
        f32x4 acc[4] = {};
        for (int kt = 0; kt < 2; ++kt) {
#pragma unroll
            for (int i = 0; i < 4; ++i) {
                int idx = i * 256 + tid, r = idx >> 4, c = (idx & 15) * 8;
                *(uint4*)(&As[r * LDW + c]) = cvt8u(rwp + (m0 + r) * 1024 + k0 + kt * 128 + c);
            }
#pragma unroll
            for (int j = 0; j < 8; ++j) {
                float4 q = *(const float4*)(memory + (k0 + kt * 128 + m_loc) * 64 + v0 + 4 * j);
                Bs[(v0 + 4 * j + 0) * LDW + m_loc] = f2bf(q.x);
                Bs[(v0 + 4 * j + 1) * LDW + m_loc] = f2bf(q.y);
                Bs[(v0 + 4 * j + 2) * LDW + m_loc] = f2bf(q.z);
                Bs[(v0 + 4 * j + 3) * LDW + m_loc] = f2bf(q.w);
            }
            __syncthreads();
#pragma unroll
            for (int kk = 0; kk < 128; kk += 32) {
                bf16x8 a  = *(const bf16x8*)(&As[(16 * w + lrow) * LDW + kk + 8 * lq]);
                bf16x8 b0 = *(const bf16x8*)(&Bs[(lrow) * LDW + kk + 8 * lq]);
                bf16x8 b1 = *(const bf16x8*)(&Bs[(16 + lrow) * LDW + kk + 8 * lq]);
                bf16x8 b2 = *(const bf16x8*)(&Bs[(32 + lrow) * LDW + kk + 8 * lq]);
                bf16x8 b3 = *(const bf16x8*)(&Bs[(48 + lrow) * LDW + kk + 8 * lq]);
                acc[0] = MFMA_BF16(a, b0, acc[0]);
                acc[1] = MFMA_BF16(a, b1, acc[1]);
                acc[2] = MFMA_BF16(a, b2, acc[2]);
                acc[3] = MFMA_BF16(a, b3, acc[3]);
            }
            __syncthreads();
        }
        float* rps = rp + ks * 131072;
#pragma unroll
        for (int nj = 0; nj < 4; ++nj)
#pragma unroll
            for (int r = 0; r < 4; ++r) {
                int row = m0 + 16 * w + 4 * lq + r, col = 16 * nj + lrow;
                rps[row * 64 + col] = acc[nj][r];
            }
    } else {
        for (int t = (bid - 128) * 256 + tid; t < 926720; t += 384 * 256)
            convert_unit(t, x, h_prev, W_ih, W_hh, W_read, W_write, W_erase, W_add,
                         W_out, memory, x_t, ht_t, wcat_t, Wcat2_t, Wo_rn, memt);
    }
    grid_barrier(0);

    // ======================= phase 1: gates =======================
    {
        u16* AsG = (u16*)smem;                 // 2 x 8192 u16
        u16* BsG = (u16*)(smem + 32768);       // 2 x 4096 u16
        const int mt = bid & 15, bn = bid >> 4;
        const int m0 = mt * 128;
        f32x4 acc[2][4] = {};

        // prologue: tile 0 = rp strip (K 0..63). A via VGPR sum4-cvt, B via DMA.
#pragma unroll
        for (int i = 0; i < 4; ++i) {
            int cp = i * 256 + tid;
            *(uint4*)(&AsG[cp * 8]) = cvt8u_sum4(rp, (m0 + (cp & 127)) * 64 + (cp >> 7) * 8);
        }
#pragma unroll
        for (int i = 0; i < 2; ++i) {
            dma16(wcat_t + (bn * 5) * 8192 + (i * 256 + tid) * 8, &BsG[(i * 256 + w * 64) * 8]);
        }

#pragma unroll
        for (int t = 0; t < 10; ++t) {
            if (t < 9) {
                const int tn = t + 1, b = tn & 1;
                const u16* asrc = (tn == 1) ? (x_t + mt * 8192)
                                            : (ht_t + mt * 65536 + (tn - 2) * 8192);
#pragma unroll
                for (int i = 0; i < 4; ++i)
                    dma16(asrc + (i * 256 + tid) * 8, &AsG[b * 8192 + (i * 256 + w * 64) * 8]);
#pragma unroll
                for (int i = 0; i < 2; ++i)
                    dma16(wcat_t + (bn * 5 + (tn >> 1)) * 8192 + (tn & 1) * 4096 + (i * 256 + tid) * 8,
                          &BsG[b * 4096 + (i * 256 + w * 64) * 8]);
                PIPE_BAR_PRE_CNT();
            } else {
                PIPE_BAR_PRE_ZERO();
            }
            const int b = t & 1;
#pragma unroll
            for (int kk = 0; kk < 64; kk += 32) {
                const int ob = (kk >> 3) + lq;
                bf16x8 a0 = *(const bf16x8*)(&AsG[b * 8192 + ob * 1024 + (32 * w + lrow) * 8]);
                bf16x8 a1 = *(const bf16x8*)(&AsG[b * 8192 + ob * 1024 + (32 * w + 16 + lrow) * 8]);
                bf16x8 b0 = *(const bf16x8*)(&BsG[b * 4096 + ob * 512 + (lrow) * 8]);
                bf16x8 b1 = *(const bf16x8*)(&BsG[b * 4096 + ob * 512 + (16 + lrow) * 8]);
                bf16x8 b2 = *(const bf16x8*)(&BsG[b * 4096 + ob * 512 + (32 + lrow) * 8]);
                bf16x8 b3 = *(const bf16x8*)(&BsG[b * 4096 + ob * 512 + (48 + lrow) * 8]);
                acc[0][0] = MFMA_BF16(a0, b0, acc[0][0]);
                acc[0][1] = MFMA_BF16(a0, b1, acc[0][1]);
                acc[0][2] = MFMA_BF16(a0, b2, acc[0][2]);
                acc[0][3] = MFMA_BF16(a0, b3, acc[0][3]);
                acc[1][0] = MFMA_BF16(a1, b0, acc[1][0]);
                acc[1][1] = MFMA_BF16(a1, b1, acc[1][1]);
                acc[1][2] = MFMA_BF16(a1, b2, acc[1][2]);
                acc[1][3] = MFMA_BF16(a1, b3, acc[1][3]);
            }
            PIPE_BAR_POST();
        }

        const int j = bn * 16 + lrow;
        const float bI = b_ih[j] + b_hh[j];
        const float bF = b_ih[512 + j] + b_hh[512 + j];
        const float bG = b_ih[1024 + j] + b_hh[1024 + j];
        const float bO = b_ih[1536 + j] + b_hh[1536 + j];
#pragma unroll
        for (int mi = 0; mi < 2; ++mi)
#pragma unroll
            for (int r = 0; r < 4; ++r) {
                int row = m0 + 32 * w + 16 * mi + 4 * lq + r;
                float ig = sigf(acc[mi][0][r] + bI);
                float fg = sigf(acc[mi][1][r] + bF);
                float gg = fast_tanh(acc[mi][2][r] + bG);
                float og = sigf(acc[mi][3][r] + bO);
                float c = fg * c_prev[row * 512 + j] + ig * gg;
                hrn_t[(row >> 7) * 65536 + (j >> 3) * 1024 + (row & 127) * 8 + (j & 7)] =
                    f2bf(og * fast_tanh(c));
            }
    }
    grid_barrier(1);

    // ======================= phase 2: heads =======================
    for (int tile = bid; tile < 560; tile += 512) {
        u16* AsG = (u16*)smem;
        u16* BsG = (u16*)(smem + 32768);
        const int mt = tile & 15, bn = tile >> 4;
        const int m0 = mt * 128;
        f32x4 acc[2][4] = {};

#pragma unroll
        for (int i = 0; i < 4; ++i)
            dma16(hrn_t + mt * 65536 + (i * 256 + tid) * 8, &AsG[(i * 256 + w * 64) * 8]);
#pragma unroll
        for (int i = 0; i < 2; ++i)
            dma16(Wcat2_t + (bn * 4) * 8192 + (i * 256 + tid) * 8, &BsG[(i * 256 + w * 64) * 8]);

#pragma unroll
        for (int t = 0; t < 8; ++t) {
            if (t < 7) {
                const int tn = t + 1, b = tn & 1;
#pragma unroll
                for (int i = 0; i < 4; ++i)
                    dma16(hrn_t + mt * 65536 + tn * 8192 + (i * 256 + tid) * 8,
                          &AsG[b * 8192 + (i * 256 + w * 64) * 8]);
#pragma unroll
                for (int i = 0; i < 2; ++i)
                    dma16(Wcat2_t + (bn * 4 + (tn >> 1)) * 8192 + (tn & 1) * 4096 + (i * 256 + tid) * 8,
                          &BsG[b * 4096 + (i * 256 + w * 64) * 8]);
                PIPE_BAR_PRE_CNT();
            } else {
                PIPE_BAR_PRE_ZERO();
            }
            const int b = t & 1;
#pragma unroll
            for (int kk = 0; kk < 64; kk += 32) {
                const int ob = (kk >> 3) + lq;
                bf16x8 a0 = *(const bf16x8*)(&AsG[b * 8192 + ob * 1024 + (32 * w + lrow) * 8]);
                bf16x8 a1 = *(const bf16x8*)(&AsG[b * 8192 + ob * 1024 + (32 * w + 16 + lrow) * 8]);
                bf16x8 b0 = *(const bf16x8*)(&BsG[b * 4096 + ob * 512 + (lrow) * 8]);
                bf16x8 b1 = *(const bf16x8*)(&BsG[b * 4096 + ob * 512 + (16 + lrow) * 8]);
                bf16x8 b2 = *(const bf16x8*)(&BsG[b * 4096 + ob * 512 + (32 + lrow) * 8]);
                bf16x8 b3 = *(const bf16x8*)(&BsG[b * 4096 + ob * 512 + (48 + lrow) * 8]);
                acc[0][0] = MFMA_BF16(a0, b0, acc[0][0]);
                acc[0][1] = MFMA_BF16(a0, b1, acc[0][1]);
                acc[0][2] = MFMA_BF16(a0, b2, acc[0][2]);
                acc[0][3] = MFMA_BF16(a0, b3, acc[0][3]);
                acc[1][0] = MFMA_BF16(a1, b0, acc[1][0]);
                acc[1][1] = MFMA_BF16(a1, b1, acc[1][1]);
                acc[1][2] = MFMA_BF16(a1, b2, acc[1][2]);
                acc[1][3] = MFMA_BF16(a1, b3, acc[1][3]);
            }
            PIPE_BAR_POST();
        }

#pragma unroll
        for (int mi = 0; mi < 2; ++mi)
#pragma unroll
            for (int nj = 0; nj < 4; ++nj)
#pragma unroll
                for (int r = 0; r < 4; ++r) {
                    int row = m0 + 32 * w + 16 * mi + 4 * lq + r;
                    int col = bn * 64 + 16 * nj + lrow;
                    float v = acc[mi][nj][r];
                    if (bn < 16)       pre_r[row * 1024 + col] = f2bf(v + b_read[col]);
                    else if (bn < 32)  pre_w[row * 1024 + (col - 1024)] = f2bf(v + b_write[col - 1024]);
                    else if (bn == 32) erase[row * 64 + (col - 2048)] = sigf(v + b_erase[col - 2048]);
                    else if (bn == 33) add[row * 64 + (col - 2112)] = fast_tanh(v + b_add[col - 2112]);
                    else               out[row * 64 + (col - 2176)] = v + b_out[col - 2176];
                }
    }
    grid_barrier(2);

    // ======================= phase 3: tail =======================
    if (bid < 256) {
        u16*   rwS  = (u16*)smem;                    // 16 x SLDW
        u16*   rw2S = (u16*)(smem + 16640);          // 16 x SLDW
        u16*   BsP  = (u16*)(smem + 33280);          // 64 x LDW
        u16*   Ps   = (u16*)(smem + 50688);          // 16 x 72
        float* s_sh = (float*)(smem + 52992);        // 16
        const int mb = bid >> 1, kh = bid & 1;
        const int m0 = mb * 16, k0 = kh * 512;

        {
            const int row = tid >> 4, c16 = tid & 15;
            const int row_g = m0 + row;
            const u16* prp = pre_r + row_g * 1024;
            const u16* pwp = pre_w + row_g * 1024;
            float vr[64], vw[64];
#pragma unroll
            for (int q = 0; q < 8; ++q) {
                bfu4_to_f8(*(const uint4*)(prp + q * 128 + c16 * 8), vr + 8 * q);
                bfu4_to_f8(*(const uint4*)(pwp + q * 128 + c16 * 8), vw + 8 * q);
            }
            float mr = vr[0], mw = vw[0];
#pragma unroll
            for (int i = 1; i < 64; ++i) { mr = fmaxf(mr, vr[i]); mw = fmaxf(mw, vw[i]); }
#pragma unroll
            for (int o = 1; o < 16; o <<= 1) {
                mr = fmaxf(mr, __shfl_xor(mr, o, 64));
                mw = fmaxf(mw, __shfl_xor(mw, o, 64));
            }
            float sr = 0.f, sw = 0.f;
#pragma unroll
            for (int i = 0; i < 64; ++i) {
                vr[i] = __expf(vr[i] - mr); sr += vr[i];
                vw[i] = __expf(vw[i] - mw); sw += vw[i];
            }
#pragma unroll
            for (int o = 1; o < 16; o <<= 1) {
                sr += __shfl_xor(sr, o, 64);
                sw += __shfl_xor(sw, o, 64);
            }
            const float isr = 1.f / sr, isw = 1.f / sw;
            float ss = 0.f;
#pragma unroll
            for (int q = 0; q < 8; ++q) {
                float a8[8], r8[8];
#pragma unroll
                for (int i = 0; i < 8; ++i) {
                    float a = vr[8 * q + i] * isr;
                    float r2 = a * (vw[8 * q + i] * isw);
                    a8[i] = a; r8[i] = r2;
                    ss += r2;
                }
                if ((q >> 2) == kh) {
                    int cb = (q - 4 * kh) * 128 + c16 * 8;
                    *(uint4*)(&rwS[row * SLDW + cb])  = pack8(a8);
                    *(uint4*)(&rw2S[row * SLDW + cb]) = pack8(r8);
                }
            }
#pragma unroll
            for (int o = 1; o < 16; o <<= 1) ss += __shfl_xor(ss, o, 64);
            if (c16 == 0) s_sh[row] = ss;
        }
        __syncthreads();

        f32x4 acc1 = {}, acc2 = {};
        for (int kt = 0; kt < 4; ++kt) {
#pragma unroll
            for (int i = 0; i < 4; ++i) {
                int idx = i * 256 + tid, r = idx >> 4, c = (idx & 15) * 8;
                *(uint4*)(&BsP[r * LDW + c]) = *(const uint4*)(memt + r * 1024 + k0 + kt * 128 + c);
            }
            __syncthreads();
#pragma unroll
            for (int kk = 0; kk < 128; kk += 32) {
                bf16x8 a1 = *(const bf16x8*)(&rwS[lrow * SLDW + kt * 128 + kk + 8 * lq]);
                bf16x8 a2 = *(const bf16x8*)(&rw2S[lrow * SLDW + kt * 128 + kk + 8 * lq]);
                bf16x8 b  = *(const bf16x8*)(&BsP[(16 * w + lrow) * LDW + kk + 8 * lq]);
                acc1 = MFMA_BF16(a1, b, acc1);
                acc2 = MFMA_BF16(a2, b, acc2);
            }
            __syncthreads();
        }

#pragma unroll
        for (int r = 0; r < 4; ++r) {
            int row_l = 4 * lq + r, col = 16 * w + lrow;
            int row_g = m0 + row_l;
            float p = acc1[r] - erase[row_g * 64 + col] * acc2[r];
            if (kh == 0) p += add[row_g * 64 + col] * s_sh[row_l];
            Ps[row_l * 72 + col] = f2bf(p);
        }
#pragma unroll
        for (int i = 0; i < 2; ++i) {
            int idx = i * 256 + tid, r = idx >> 3, c = (idx & 7) * 8;
            *(uint4*)(&BsP[r * LDW + c]) = *(const uint4*)(Wo_rn + r * 64 + c);
        }
        __syncthreads();

        f32x4 acc3 = {};
#pragma unroll
        for (int kk = 0; kk < 64; kk += 32) {
            bf16x8 a = *(const bf16x8*)(&Ps[lrow * 72 + kk + 8 * lq]);
            bf16x8 b = *(const bf16x8*)(&BsP[(16 * w + lrow) * LDW + kk + 8 * lq]);
            acc3 = MFMA_BF16(a, b, acc3);
        }
#pragma unroll
        for (int r = 0; r < 4; ++r) {
            int row_g = m0 + 4 * lq + r, col = 16 * w + lrow;
            atomicAdd(&out[row_g * 64 + col], acc3[r]);
        }
    }
}

extern "C" void kernel_launch(void* const* d_in, const int* in_sizes, int n_in,
                              void* d_out, int out_size, void* d_ws, size_t ws_size,
                              hipStream_t stream)
{
    const float* x        = (const float*)d_in[0];
    const float* h_prev   = (const float*)d_in[1];
    const float* c_prev   = (const float*)d_in[2];
    const float* rwp      = (const float*)d_in[3];
    const float* memory   = (const float*)d_in[4];
    const float* W_ih     = (const float*)d_in[5];
    const float* b_ih     = (const float*)d_in[6];
    const float* W_hh     = (const float*)d_in[7];
    const float* b_hh     = (const float*)d_in[8];
    const float* W_read   = (const float*)d_in[9];
    const float* b_read   = (const float*)d_in[10];
    const float* W_write  = (const float*)d_in[11];
    const float* b_write  = (const float*)d_in[12];
    const float* W_erase  = (const float*)d_in[13];
    const float* b_erase  = (const float*)d_in[14];
    const float* W_add    = (const float*)d_in[15];
    const float* b_add    = (const float*)d_in[16];
    const float* W_out    = (const float*)d_in[17];
    const float* b_out    = (const float*)d_in[18];
    float* out = (float*)d_out;
    char* wsp = (char*)d_ws;

    k_fused<<<dim3(512), dim3(256), 0, stream>>>(
        x, h_prev, c_prev, rwp, memory, W_ih, b_ih, W_hh, b_hh,
        W_read, b_read, W_write, b_write, W_erase, b_erase, W_add, b_add,
        W_out, b_out, out, wsp);
}

// Round 5
// 186.015 us; speedup vs baseline: 2.2474x; 1.1445x over previous
//
#include <hip/hip_runtime.h>
#include <hip/hip_bf16.h>

// NTM cell on MI355X. B=2048, IN=64, CTRL=512, M=1024, V=64, OUT=64.
// Single kernel, 560 blocks x 256 threads, 4 phases separated by a
// device-scope grid barrier with PER-XCD FLUSH:
//   stage A: relaxed arrival (16-line tree) -> root1 (all 560 arrived; every
//            block's stores are in its XCD L2 via syncthreads vmcnt drain +
//            write-through L1)
//   elect:   CAS on elect[xcc] (xcc = s_getreg(HW_REG_XCC_ID), m09) -> exactly
//            one flusher per producer XCD, any block->XCD mapping
//   stage B: winner adds with RELEASE (compiler emits buffer_wbl2 sc1 +
//            waitcnt -> one L2 writeback per XCD, was one per BLOCK in r4),
//            losers RELAXED; root2 full => all flushes complete
//   acquire: per-block ACQUIRE load (L1+L2 inv; L1 is per-CU so per-block)
// Monotonic counters -> no reset across graph replays.
//   phase0: blocks 0..127 split-K read_prev GEMM; blocks 128..559 grid-stride
//           fp32->bf16 converts to tile-major layouts
//   phase1: gates GEMM + fused LSTM (512 tiles; blocks 512..559 idle)
//   phase2: heads GEMM (560 tiles, exactly 1/block -- no straggler tail)
//   phase3: tail softmax + read_new + out-GEMM (blocks 0..255)
// Co-residency: 52KB LDS -> 3 blocks/CU (159744 <= 163840); VGPR 96 <= 128
// keeps 12 waves/CU; launch_bounds(256,3); 560 <= 3*256=768 slots.

typedef unsigned short u16;
typedef __attribute__((ext_vector_type(8))) short bf16x8;
typedef __attribute__((ext_vector_type(4))) float f32x4;

#define MFMA_BF16(a, b, c) __builtin_amdgcn_mfma_f32_16x16x32_bf16((a), (b), (c), 0, 0, 0)
#define LDW 136
#define SLDW 520
#define SMEM_BYTES 53248
#define GRID 560
#define NGRP 16
#define GRPSZ 35

// Barrier state (zero-initialized at module load), 256B-strided lines.
__device__ unsigned g_a[3 * NGRP * 64];
__device__ unsigned g_b2[3 * NGRP * 64];
__device__ unsigned g_r1[3 * 64];
__device__ unsigned g_r2[3 * 64];
__device__ unsigned g_el[3 * 8 * 64];

__device__ __forceinline__ void grid_barrier(int idx) {
    __syncthreads();                      // all block stores drained -> in local L2
    if (threadIdx.x == 0) {
        const int grp = blockIdx.x / GRPSZ;
        // ---- stage A: relaxed arrival ----
        unsigned t = __hip_atomic_fetch_add(&g_a[(idx * NGRP + grp) * 64], 1u,
                          __ATOMIC_RELAXED, __HIP_MEMORY_SCOPE_AGENT);
        unsigned r = t / GRPSZ;           // round number (monotonic)
        if (t - r * GRPSZ == GRPSZ - 1u)
            __hip_atomic_fetch_add(&g_r1[idx * 64], 1u,
                                   __ATOMIC_RELAXED, __HIP_MEMORY_SCOPE_AGENT);
        const unsigned tgt = r * NGRP + NGRP;
        while (__hip_atomic_load(&g_r1[idx * 64], __ATOMIC_RELAXED,
                                 __HIP_MEMORY_SCOPE_AGENT) < tgt)
            __builtin_amdgcn_s_sleep(4);
        // ---- elect one flusher per XCD ----
        unsigned xcc;
        asm volatile("s_getreg_b32 %0, hwreg(HW_REG_XCC_ID)" : "=s"(xcc));
        unsigned expv = r;
        bool win = __hip_atomic_compare_exchange_strong(
            &g_el[(idx * 8 + (xcc & 7u)) * 64], &expv, r + 1u,
            __ATOMIC_RELAXED, __ATOMIC_RELAXED, __HIP_MEMORY_SCOPE_AGENT);
        // ---- stage B: winner RELEASE (one wbl2 per XCD), losers RELAXED ----
        unsigned t2;
        if (win)
            t2 = __hip_atomic_fetch_add(&g_b2[(idx * NGRP + grp) * 64], 1u,
                     __ATOMIC_RELEASE, __HIP_MEMORY_SCOPE_AGENT);
        else
            t2 = __hip_atomic_fetch_add(&g_b2[(idx * NGRP + grp) * 64], 1u,
                     __ATOMIC_RELAXED, __HIP_MEMORY_SCOPE_AGENT);
        unsigned r2 = t2 / GRPSZ;
        if (t2 - r2 * GRPSZ == GRPSZ - 1u)
            __hip_atomic_fetch_add(&g_r2[idx * 64], 1u,
                                   __ATOMIC_RELAXED, __HIP_MEMORY_SCOPE_AGENT);
        while (__hip_atomic_load(&g_r2[idx * 64], __ATOMIC_RELAXED,
                                 __HIP_MEMORY_SCOPE_AGENT) < tgt)
            __builtin_amdgcn_s_sleep(4);
        // ---- acquire: invalidate this CU's L1 (+L2 clean lines) ----
        unsigned v = __hip_atomic_load(&g_r2[idx * 64], __ATOMIC_ACQUIRE,
                                       __HIP_MEMORY_SCOPE_AGENT);
        asm volatile("" :: "v"(v) : "memory");  // keep acquire live, fence codegen
    }
    __syncthreads();
}

__device__ __forceinline__ void dma16(const void* g, void* l) {
    __builtin_amdgcn_global_load_lds(
        (const __attribute__((address_space(1))) unsigned int*)g,
        (__attribute__((address_space(3))) unsigned int*)l, 16, 0, 0);
}

__device__ __forceinline__ u16 f2bf(float f) {
    union { float f; unsigned int u; } a; a.f = f;
    return (u16)((a.u + 0x7FFFu + ((a.u >> 16) & 1u)) >> 16);
}

__device__ __forceinline__ void pack_store4(float a0, float a1, float a2, float a3, u16* d) {
    union { __hip_bfloat162 h[2]; uint2 u; } cv;
    cv.h[0] = __float22bfloat162_rn(make_float2(a0, a1));
    cv.h[1] = __float22bfloat162_rn(make_float2(a2, a3));
    *(uint2*)d = cv.u;
}

__device__ __forceinline__ void cvt4(const float* __restrict__ s, u16* __restrict__ d) {
    float4 v = *(const float4*)s;
    pack_store4(v.x, v.y, v.z, v.w, d);
}

__device__ __forceinline__ uint4 cvt8u(const float* __restrict__ s) {
    float4 v0 = *(const float4*)(s);
    float4 v1 = *(const float4*)(s + 4);
    union { __hip_bfloat162 h[4]; uint4 u; } r;
    r.h[0] = __float22bfloat162_rn(make_float2(v0.x, v0.y));
    r.h[1] = __float22bfloat162_rn(make_float2(v0.z, v0.w));
    r.h[2] = __float22bfloat162_rn(make_float2(v1.x, v1.y));
    r.h[3] = __float22bfloat162_rn(make_float2(v1.z, v1.w));
    return r.u;
}

__device__ __forceinline__ uint4 cvt8u_sum4(const float* __restrict__ p, int off) {
    float4 a0 = *(const float4*)(p + off);
    float4 a1 = *(const float4*)(p + 131072 + off);
    float4 a2 = *(const float4*)(p + 262144 + off);
    float4 a3 = *(const float4*)(p + 393216 + off);
    float4 b0 = *(const float4*)(p + off + 4);
    float4 b1 = *(const float4*)(p + 131072 + off + 4);
    float4 b2 = *(const float4*)(p + 262144 + off + 4);
    float4 b3 = *(const float4*)(p + 393216 + off + 4);
    float4 s0{a0.x + a1.x + a2.x + a3.x, a0.y + a1.y + a2.y + a3.y,
              a0.z + a1.z + a2.z + a3.z, a0.w + a1.w + a2.w + a3.w};
    float4 s1{b0.x + b1.x + b2.x + b3.x, b0.y + b1.y + b2.y + b3.y,
              b0.z + b1.z + b2.z + b3.z, b0.w + b1.w + b2.w + b3.w};
    union { __hip_bfloat162 h[4]; uint4 u; } r;
    r.h[0] = __float22bfloat162_rn(make_float2(s0.x, s0.y));
    r.h[1] = __float22bfloat162_rn(make_float2(s0.z, s0.w));
    r.h[2] = __float22bfloat162_rn(make_float2(s1.x, s1.y));
    r.h[3] = __float22bfloat162_rn(make_float2(s1.z, s1.w));
    return r.u;
}

__device__ __forceinline__ void bfu4_to_f8(uint4 u, float* f) {
    f[0] = __uint_as_float(u.x << 16); f[1] = __uint_as_float(u.x & 0xffff0000u);
    f[2] = __uint_as_float(u.y << 16); f[3] = __uint_as_float(u.y & 0xffff0000u);
    f[4] = __uint_as_float(u.z << 16); f[5] = __uint_as_float(u.z & 0xffff0000u);
    f[6] = __uint_as_float(u.w << 16); f[7] = __uint_as_float(u.w & 0xffff0000u);
}

__device__ __forceinline__ uint4 pack8(const float* v) {
    union { __hip_bfloat162 h[4]; uint4 u; } r;
#pragma unroll
    for (int j = 0; j < 4; ++j) r.h[j] = __float22bfloat162_rn(make_float2(v[2 * j], v[2 * j + 1]));
    return r.u;
}

__device__ __forceinline__ float sigf(float x) { return 1.f / (1.f + __expf(-x)); }
__device__ __forceinline__ float fast_tanh(float x) { return 1.f - 2.f / (__expf(2.f * x) + 1.f); }

#define PIPE_BAR_PRE_CNT()  do {                                              \
    asm volatile("s_waitcnt vmcnt(6) lgkmcnt(0)" ::: "memory");               \
    __builtin_amdgcn_s_barrier();                                             \
    __builtin_amdgcn_sched_barrier(0);                                        \
} while (0)
#define PIPE_BAR_PRE_ZERO() do {                                              \
    asm volatile("s_waitcnt vmcnt(0) lgkmcnt(0)" ::: "memory");               \
    __builtin_amdgcn_s_barrier();                                             \
    __builtin_amdgcn_sched_barrier(0);                                        \
} while (0)
#define PIPE_BAR_POST() do {                                                  \
    __builtin_amdgcn_sched_barrier(0);                                        \
    asm volatile("s_waitcnt lgkmcnt(0)" ::: "memory");                        \
    __builtin_amdgcn_s_barrier();                                             \
    __builtin_amdgcn_sched_barrier(0);                                        \
} while (0)

// One fp32->bf16 tile-major convert unit, t in [0, 926720).
__device__ __forceinline__ void convert_unit(int t,
    const float* __restrict__ x, const float* __restrict__ h_prev,
    const float* __restrict__ W_ih, const float* __restrict__ W_hh,
    const float* __restrict__ W_read, const float* __restrict__ W_write,
    const float* __restrict__ W_erase, const float* __restrict__ W_add,
    const float* __restrict__ W_out, const float* __restrict__ memory,
    u16* x_t, u16* ht_t, u16* wcat_t, u16* Wcat2_t, u16* Wo_rn, u16* memt)
{
    if (t < 32768) {  // x -> x_t[mt][oct8][row128]
        int r = t >> 4, c = (t & 15) * 4;
        cvt4(x + r * 64 + c, x_t + ((r >> 7) * 8 + (c >> 3)) * 1024 + (r & 127) * 8 + (c & 7));
        return;
    }
    t -= 32768;
    if (t < 262144) {  // h_prev -> ht_t[mt][oct64][row128]
        int r = t >> 7, c = (t & 127) * 4;
        cvt4(h_prev + r * 512 + c, ht_t + ((r >> 7) * 64 + (c >> 3)) * 1024 + (r & 127) * 8 + (c & 7));
        return;
    }
    t -= 262144;
    if (t < 65536) {  // W_ih (gate-interleave rows, col swap rp|x) -> wcat_t[bn][kt0][oct][row64]
        int r = t >> 5, c = (t & 31) * 4;
        int g = r >> 9, j = r & 511;
        int bn = j >> 4, row64 = (g << 4) + (j & 15);
        int cd = (c < 64) ? c + 64 : c - 64;
        cvt4(W_ih + r * 128 + c, wcat_t + (bn * 5) * 8192 + (cd >> 3) * 512 + row64 * 8 + (cd & 7));
        return;
    }
    t -= 65536;
    if (t < 262144) {  // W_hh -> wcat_t[bn][kt1..4][oct][row64]
        int r = t >> 7, c = (t & 127) * 4;
        int g = r >> 9, j = r & 511;
        int bn = j >> 4, row64 = (g << 4) + (j & 15);
        int cd = 128 + c;
        cvt4(W_hh + r * 512 + c, wcat_t + (bn * 5 + (cd >> 7)) * 8192 + ((cd >> 3) & 15) * 512 + row64 * 8 + (cd & 7));
        return;
    }
    t -= 262144;
    if (t < 131072) {  // W_read -> Wcat2_t bn 0..15
        int r = t >> 7, c = (t & 127) * 4;
        cvt4(W_read + t * 4, Wcat2_t + ((r >> 6) * 4 + (c >> 7)) * 8192 + ((c >> 3) & 15) * 512 + (r & 63) * 8 + (c & 7));
        return;
    }
    t -= 131072;
    if (t < 131072) {  // W_write -> bn 16..31
        int r = t >> 7, c = (t & 127) * 4;
        cvt4(W_write + t * 4, Wcat2_t + ((16 + (r >> 6)) * 4 + (c >> 7)) * 8192 + ((c >> 3) & 15) * 512 + (r & 63) * 8 + (c & 7));
        return;
    }
    t -= 131072;
    if (t < 8192) {  // W_erase -> bn 32
        int r = t >> 7, c = (t & 127) * 4;
        cvt4(W_erase + t * 4, Wcat2_t + (32 * 4 + (c >> 7)) * 8192 + ((c >> 3) & 15) * 512 + r * 8 + (c & 7));
        return;
    }
    t -= 8192;
    if (t < 8192) {  // W_add -> bn 33
        int r = t >> 7, c = (t & 127) * 4;
        cvt4(W_add + t * 4, Wcat2_t + (33 * 4 + (c >> 7)) * 8192 + ((c >> 3) & 15) * 512 + r * 8 + (c & 7));
        return;
    }
    t -= 8192;
    if (t < 9216) {  // W_out: h-part -> bn 34; rn-part -> Wo_rn
        int r = t / 144, c = (t % 144) * 4;
        if (c < 512)
            cvt4(W_out + r * 576 + c, Wcat2_t + (34 * 4 + (c >> 7)) * 8192 + ((c >> 3) & 15) * 512 + r * 8 + (c & 7));
        else
            cvt4(W_out + r * 576 + c, Wo_rn + r * 64 + (c - 512));
        return;
    }
    t -= 9216;
    {  // memory^T -> memt (64 x 1024)
        int v = t >> 8, m = (t & 255) * 4;
        pack_store4(memory[m * 64 + v], memory[(m + 1) * 64 + v],
                    memory[(m + 2) * 64 + v], memory[(m + 3) * 64 + v], memt + v * 1024 + m);
    }
}

__global__ __launch_bounds__(256, 3) void k_fused(
    const float* __restrict__ x, const float* __restrict__ h_prev, const float* __restrict__ c_prev,
    const float* __restrict__ rwp, const float* __restrict__ memory,
    const float* __restrict__ W_ih, const float* __restrict__ b_ih,
    const float* __restrict__ W_hh, const float* __restrict__ b_hh,
    const float* __restrict__ W_read, const float* __restrict__ b_read,
    const float* __restrict__ W_write, const float* __restrict__ b_write,
    const float* __restrict__ W_erase, const float* __restrict__ b_erase,
    const float* __restrict__ W_add, const float* __restrict__ b_add,
    const float* __restrict__ W_out, const float* __restrict__ b_out,
    float* __restrict__ out, char* __restrict__ wsp)
{
    __shared__ __align__(16) char smem[SMEM_BYTES];

    u16*   x_t     = (u16*)(wsp + 0);           // 16 x 8oct x 128row x 8  (256 KB)
    u16*   ht_t    = (u16*)(wsp + 262144);      // 16 x 64oct x 128row x 8 (2 MB)
    u16*   wcat_t  = (u16*)(wsp + 2359296);     // 32bn x 5kt x 16oct x 64row x 8
    u16*   memt    = (u16*)(wsp + 4980736);     // 64 x 1024 bf16 memory^T
    u16*   Wcat2_t = (u16*)(wsp + 5111808);     // 35bn x 4kt x 16oct x 64row x 8
    u16*   Wo_rn   = (u16*)(wsp + 7405568);     // 64x64 bf16
    float* rp      = (float*)(wsp + 7413760);   // 4 x 2048x64 fp32 split-K partials
    u16*   hrn_t   = (u16*)(wsp + 9510912);     // 16 x 64oct x 128row x 8 (2 MB)
    u16*   pre_r   = (u16*)(wsp + 11608064);    // 2048x1024 bf16
    u16*   pre_w   = (u16*)(wsp + 15802368);    // 2048x1024 bf16
    float* erase   = (float*)(wsp + 19996672);  // 2048x64 fp32
    float* add     = (float*)(wsp + 20520960);  // 2048x64 fp32

    const int bid = blockIdx.x;
    const int tid = threadIdx.x, w = tid >> 6, lane = tid & 63;
    const int lrow = lane & 15, lq = lane >> 4;

    // ======================= phase 0: pre =======================
    if (bid < 128) {
        u16* As = (u16*)smem;                 // 64 x LDW
        u16* Bs = (u16*)(smem + 64 * LDW * 2);
        const int mb = bid & 31, ks = bid >> 5;
        const int m0 = mb * 64, k0 = ks * 256;
        const int m_loc = tid >> 1, v0 = (tid & 1) * 32;
        f32x4 acc[4] = {};
        for (int kt = 0; kt < 2; ++kt) {
#pragma unroll
            for (int i = 0; i < 4; ++i) {
                int idx = i * 256 + tid, r = idx >> 4, c = (idx & 15) * 8;
                *(uint4*)(&As[r * LDW + c]) = cvt8u(rwp + (m0 + r) * 1024 + k0 + kt * 128 + c);
            }
#pragma unroll
            for (int j = 0; j < 8; ++j) {
                float4 q = *(const float4*)(memory + (k0 + kt * 128 + m_loc) * 64 + v0 + 4 * j);
                Bs[(v0 + 4 * j + 0) * LDW + m_loc] = f2bf(q.x);
                Bs[(v0 + 4 * j + 1) * LDW + m_loc] = f2bf(q.y);
                Bs[(v0 + 4 * j + 2) * LDW + m_loc] = f2bf(q.z);
                Bs[(v0 + 4 * j + 3) * LDW + m_loc] = f2bf(q.w);
            }
            __syncthreads();
#pragma unroll
            for (int kk = 0; kk < 128; kk += 32) {
                bf16x8 a  = *(const bf16x8*)(&As[(16 * w + lrow) * LDW + kk + 8 * lq]);
                bf16x8 b0 = *(const bf16x8*)(&Bs[(lrow) * LDW + kk + 8 * lq]);
                bf16x8 b1 = *(const bf16x8*)(&Bs[(16 + lrow) * LDW + kk + 8 * lq]);
                bf16x8 b2 = *(const bf16x8*)(&Bs[(32 + lrow) * LDW + kk + 8 * lq]);
                bf16x8 b3 = *(const bf16x8*)(&Bs[(48 + lrow) * LDW + kk + 8 * lq]);
                acc[0] = MFMA_BF16(a, b0, acc[0]);
                acc[1] = MFMA_BF16(a, b1, acc[1]);
                acc[2] = MFMA_BF16(a, b2, acc[2]);
                acc[3] = MFMA_BF16(a, b3, acc[3]);
            }
            __syncthreads();
        }
        float* rps = rp + ks * 131072;
#pragma unroll
        for (int nj = 0; nj < 4; ++nj)
#pragma unroll
            for (int r = 0; r < 4; ++r) {
                int row = m0 + 16 * w + 4 * lq + r, col = 16 * nj + lrow;
                rps[row * 64 + col] = acc[nj][r];
            }
    } else {
        for (int t = (bid - 128) * 256 + tid; t < 926720; t += 432 * 256)
            convert_unit(t, x, h_prev, W_ih, W_hh, W_read, W_write, W_erase, W_add,
                         W_out, memory, x_t, ht_t, wcat_t, Wcat2_t, Wo_rn, memt);
    }
    grid_barrier(0);

    // ======================= phase 1: gates =======================
    if (bid < 512) {
        u16* AsG = (u16*)smem;                 // 2 x 8192 u16
        u16* BsG = (u16*)(smem + 32768);       // 2 x 4096 u16
        const int mt = bid & 15, bn = bid >> 4;
        const int m0 = mt * 128;
        f32x4 acc[2][4] = {};

        // prologue: tile 0 = rp strip (K 0..63). A via VGPR sum4-cvt, B via DMA.
#pragma unroll
        for (int i = 0; i < 4; ++i) {
            int cp = i * 256 + tid;
            *(uint4*)(&AsG[cp * 8]) = cvt8u_sum4(rp, (m0 + (cp & 127)) * 64 + (cp >> 7) * 8);
        }
#pragma unroll
        for (int i = 0; i < 2; ++i) {
            dma16(wcat_t + (bn * 5) * 8192 + (i * 256 + tid) * 8, &BsG[(i * 256 + w * 64) * 8]);
        }

#pragma unroll
        for (int t = 0; t < 10; ++t) {
            if (t < 9) {
                const int tn = t + 1, b = tn & 1;
                const u16* asrc = (tn == 1) ? (x_t + mt * 8192)
                                            : (ht_t + mt * 65536 + (tn - 2) * 8192);
#pragma unroll
                for (int i = 0; i < 4; ++i)
                    dma16(asrc + (i * 256 + tid) * 8, &AsG[b * 8192 + (i * 256 + w * 64) * 8]);
#pragma unroll
                for (int i = 0; i < 2; ++i)
                    dma16(wcat_t + (bn * 5 + (tn >> 1)) * 8192 + (tn & 1) * 4096 + (i * 256 + tid) * 8,
                          &BsG[b * 4096 + (i * 256 + w * 64) * 8]);
                PIPE_BAR_PRE_CNT();
            } else {
                PIPE_BAR_PRE_ZERO();
            }
            const int b = t & 1;
#pragma unroll
            for (int kk = 0; kk < 64; kk += 32) {
                const int ob = (kk >> 3) + lq;
                bf16x8 a0 = *(const bf16x8*)(&AsG[b * 8192 + ob * 1024 + (32 * w + lrow) * 8]);
                bf16x8 a1 = *(const bf16x8*)(&AsG[b * 8192 + ob * 1024 + (32 * w + 16 + lrow) * 8]);
                bf16x8 b0 = *(const bf16x8*)(&BsG[b * 4096 + ob * 512 + (lrow) * 8]);
                bf16x8 b1 = *(const bf16x8*)(&BsG[b * 4096 + ob * 512 + (16 + lrow) * 8]);
                bf16x8 b2 = *(const bf16x8*)(&BsG[b * 4096 + ob * 512 + (32 + lrow) * 8]);
                bf16x8 b3 = *(const bf16x8*)(&BsG[b * 4096 + ob * 512 + (48 + lrow) * 8]);
                acc[0][0] = MFMA_BF16(a0, b0, acc[0][0]);
                acc[0][1] = MFMA_BF16(a0, b1, acc[0][1]);
                acc[0][2] = MFMA_BF16(a0, b2, acc[0][2]);
                acc[0][3] = MFMA_BF16(a0, b3, acc[0][3]);
                acc[1][0] = MFMA_BF16(a1, b0, acc[1][0]);
                acc[1][1] = MFMA_BF16(a1, b1, acc[1][1]);
                acc[1][2] = MFMA_BF16(a1, b2, acc[1][2]);
                acc[1][3] = MFMA_BF16(a1, b3, acc[1][3]);
            }
            PIPE_BAR_POST();
        }

        const int j = bn * 16 + lrow;
        const float bI = b_ih[j] + b_hh[j];
        const float bF = b_ih[512 + j] + b_hh[512 + j];
        const float bG = b_ih[1024 + j] + b_hh[1024 + j];
        const float bO = b_ih[1536 + j] + b_hh[1536 + j];
#pragma unroll
        for (int mi = 0; mi < 2; ++mi)
#pragma unroll
            for (int r = 0; r < 4; ++r) {
                int row = m0 + 32 * w + 16 * mi + 4 * lq + r;
                float ig = sigf(acc[mi][0][r] + bI);
                float fg = sigf(acc[mi][1][r] + bF);
                float gg = fast_tanh(acc[mi][2][r] + bG);
                float og = sigf(acc[mi][3][r] + bO);
                float c = fg * c_prev[row * 512 + j] + ig * gg;
                hrn_t[(row >> 7) * 65536 + (j >> 3) * 1024 + (row & 127) * 8 + (j & 7)] =
                    f2bf(og * fast_tanh(c));
            }
    }
    grid_barrier(1);

    // ======================= phase 2: heads (1 tile/block) =======================
    {
        u16* AsG = (u16*)smem;
        u16* BsG = (u16*)(smem + 32768);
        const int mt = bid & 15, bn = bid >> 4;
        const int m0 = mt * 128;
        f32x4 acc[2][4] = {};

#pragma unroll
        for (int i = 0; i < 4; ++i)
            dma16(hrn_t + mt * 65536 + (i * 256 + tid) * 8, &AsG[(i * 256 + w * 64) * 8]);
#pragma unroll
        for (int i = 0; i < 2; ++i)
            dma16(Wcat2_t + (bn * 4) * 8192 + (i * 256 + tid) * 8, &BsG[(i * 256 + w * 64) * 8]);

#pragma unroll
        for (int t = 0; t < 8; ++t) {
            if (t < 7) {
                const int tn = t + 1, b = tn & 1;
#pragma unroll
                for (int i = 0; i < 4; ++i)
                    dma16(hrn_t + mt * 65536 + tn * 8192 + (i * 256 + tid) * 8,
                          &AsG[b * 8192 + (i * 256 + w * 64) * 8]);
#pragma unroll
                for (int i = 0; i < 2; ++i)
                    dma16(Wcat2_t + (bn * 4 + (tn >> 1)) * 8192 + (tn & 1) * 4096 + (i * 256 + tid) * 8,
                          &BsG[b * 4096 + (i * 256 + w * 64) * 8]);
                PIPE_BAR_PRE_CNT();
            } else {
                PIPE_BAR_PRE_ZERO();
            }
            const int b = t & 1;
#pragma unroll
            for (int kk = 0; kk < 64; kk += 32) {
                const int ob = (kk >> 3) + lq;
                bf16x8 a0 = *(const bf16x8*)(&AsG[b * 8192 + ob * 1024 + (32 * w + lrow) * 8]);
                bf16x8 a1 = *(const bf16x8*)(&AsG[b * 8192 + ob * 1024 + (32 * w + 16 + lrow) * 8]);
                bf16x8 b0 = *(const bf16x8*)(&BsG[b * 4096 + ob * 512 + (lrow) * 8]);
                bf16x8 b1 = *(const bf16x8*)(&BsG[b * 4096 + ob * 512 + (16 + lrow) * 8]);
                bf16x8 b2 = *(const bf16x8*)(&BsG[b * 4096 + ob * 512 + (32 + lrow) * 8]);
                bf16x8 b3 = *(const bf16x8*)(&BsG[b * 4096 + ob * 512 + (48 + lrow) * 8]);
                acc[0][0] = MFMA_BF16(a0, b0, acc[0][0]);
                acc[0][1] = MFMA_BF16(a0, b1, acc[0][1]);
                acc[0][2] = MFMA_BF16(a0, b2, acc[0][2]);
                acc[0][3] = MFMA_BF16(a0, b3, acc[0][3]);
                acc[1][0] = MFMA_BF16(a1, b0, acc[1][0]);
                acc[1][1] = MFMA_BF16(a1, b1, acc[1][1]);
                acc[1][2] = MFMA_BF16(a1, b2, acc[1][2]);
                acc[1][3] = MFMA_BF16(a1, b3, acc[1][3]);
            }
            PIPE_BAR_POST();
        }

#pragma unroll
        for (int mi = 0; mi < 2; ++mi)
#pragma unroll
            for (int nj = 0; nj < 4; ++nj)
#pragma unroll
                for (int r = 0; r < 4; ++r) {
                    int row = m0 + 32 * w + 16 * mi + 4 * lq + r;
                    int col = bn * 64 + 16 * nj + lrow;
                    float v = acc[mi][nj][r];
                    if (bn < 16)       pre_r[row * 1024 + col] = f2bf(v + b_read[col]);
                    else if (bn < 32)  pre_w[row * 1024 + (col - 1024)] = f2bf(v + b_write[col - 1024]);
                    else if (bn == 32) erase[row * 64 + (col - 2048)] = sigf(v + b_erase[col - 2048]);
                    else if (bn == 33) add[row * 64 + (col - 2112)] = fast_tanh(v + b_add[col - 2112]);
                    else               out[row * 64 + (col - 2176)] = v + b_out[col - 2176];
                }
    }
    grid_barrier(2);

    // ======================= phase 3: tail =======================
    if (bid < 256) {
        u16*   rwS  = (u16*)smem;                    // 16 x SLDW
        u16*   rw2S = (u16*)(smem + 16640);          // 16 x SLDW
        u16*   BsP  = (u16*)(smem + 33280);          // 64 x LDW
        u16*   Ps   = (u16*)(smem + 50688);          // 16 x 72
        float* s_sh = (float*)(smem + 52992);        // 16
        const int mb = bid >> 1, kh = bid & 1;
        const int m0 = mb * 16, k0 = kh * 512;

        {
            const int row = tid >> 4, c16 = tid & 15;
            const int row_g = m0 + row;
            const u16* prp = pre_r + row_g * 1024;
            const u16* pwp = pre_w + row_g * 1024;
            float vr[64], vw[64];
#pragma unroll
            for (int q = 0; q < 8; ++q) {
                bfu4_to_f8(*(const uint4*)(prp + q * 128 + c16 * 8), vr + 8 * q);
                bfu4_to_f8(*(const uint4*)(pwp + q * 128 + c16 * 8), vw + 8 * q);
            }
            float mr = vr[0], mw = vw[0];
#pragma unroll
            for (int i = 1; i < 64; ++i) { mr = fmaxf(mr, vr[i]); mw = fmaxf(mw, vw[i]); }
#pragma unroll
            for (int o = 1; o < 16; o <<= 1) {
                mr = fmaxf(mr, __shfl_xor(mr, o, 64));
                mw = fmaxf(mw, __shfl_xor(mw, o, 64));
            }
            float sr = 0.f, sw = 0.f;
#pragma unroll
            for (int i = 0; i < 64; ++i) {
                vr[i] = __expf(vr[i] - mr); sr += vr[i];
                vw[i] = __expf(vw[i] - mw); sw += vw[i];
            }
#pragma unroll
            for (int o = 1; o < 16; o <<= 1) {
                sr += __shfl_xor(sr, o, 64);
                sw += __shfl_xor(sw, o, 64);
            }
            const float isr = 1.f / sr, isw = 1.f / sw;
            float ss = 0.f;
#pragma unroll
            for (int q = 0; q < 8; ++q) {
                float a8[8], r8[8];
#pragma unroll
                for (int i = 0; i < 8; ++i) {
                    float a = vr[8 * q + i] * isr;
                    float r2 = a * (vw[8 * q + i] * isw);
                    a8[i] = a; r8[i] = r2;
                    ss += r2;
                }
                if ((q >> 2) == kh) {
                    int cb = (q - 4 * kh) * 128 + c16 * 8;
                    *(uint4*)(&rwS[row * SLDW + cb])  = pack8(a8);
                    *(uint4*)(&rw2S[row * SLDW + cb]) = pack8(r8);
                }
            }
#pragma unroll
            for (int o = 1; o < 16; o <<= 1) ss += __shfl_xor(ss, o, 64);
            if (c16 == 0) s_sh[row] = ss;
        }
        __syncthreads();

        f32x4 acc1 = {}, acc2 = {};
        for (int kt = 0; kt < 4; ++kt) {
#pragma unroll
            for (int i = 0; i < 4; ++i) {
                int idx = i * 256 + tid, r = idx >> 4, c = (idx & 15) * 8;
                *(uint4*)(&BsP[r * LDW + c]) = *(const uint4*)(memt + r * 1024 + k0 + kt * 128 + c);
            }
            __syncthreads();
#pragma unroll
            for (int kk = 0; kk < 128; kk += 32) {
                bf16x8 a1 = *(const bf16x8*)(&rwS[lrow * SLDW + kt * 128 + kk + 8 * lq]);
                bf16x8 a2 = *(const bf16x8*)(&rw2S[lrow * SLDW + kt * 128 + kk + 8 * lq]);
                bf16x8 b  = *(const bf16x8*)(&BsP[(16 * w + lrow) * LDW + kk + 8 * lq]);
                acc1 = MFMA_BF16(a1, b, acc1);
                acc2 = MFMA_BF16(a2, b, acc2);
            }
            __syncthreads();
        }

#pragma unroll
        for (int r = 0; r < 4; ++r) {
            int row_l = 4 * lq + r, col = 16 * w + lrow;
            int row_g = m0 + row_l;
            float p = acc1[r] - erase[row_g * 64 + col] * acc2[r];
            if (kh == 0) p += add[row_g * 64 + col] * s_sh[row_l];
            Ps[row_l * 72 + col] = f2bf(p);
        }
#pragma unroll
        for (int i = 0; i < 2; ++i) {
            int idx = i * 256 + tid, r = idx >> 3, c = (idx & 7) * 8;
            *(uint4*)(&BsP[r * LDW + c]) = *(const uint4*)(Wo_rn + r * 64 + c);
        }
        __syncthreads();

        f32x4 acc3 = {};
#pragma unroll
        for (int kk = 0; kk < 64; kk += 32) {
            bf16x8 a = *(const bf16x8*)(&Ps[lrow * 72 + kk + 8 * lq]);
            bf16x8 b = *(const bf16x8*)(&BsP[(16 * w + lrow) * LDW + kk + 8 * lq]);
            acc3 = MFMA_BF16(a, b, acc3);
        }
#pragma unroll
        for (int r = 0; r < 4; ++r) {
            int row_g = m0 + 4 * lq + r, col = 16 * w + lrow;
            atomicAdd(&out[row_g * 64 + col], acc3[r]);
        }
    }
}

extern "C" void kernel_launch(void* const* d_in, const int* in_sizes, int n_in,
                              void* d_out, int out_size, void* d_ws, size_t ws_size,
                              hipStream_t stream)
{
    const float* x        = (const float*)d_in[0];
    const float* h_prev   = (const float*)d_in[1];
    const float* c_prev   = (const float*)d_in[2];
    const float* rwp      = (const float*)d_in[3];
    const float* memory   = (const float*)d_in[4];
    const float* W_ih     = (const float*)d_in[5];
    const float* b_ih     = (const float*)d_in[6];
    const float* W_hh     = (const float*)d_in[7];
    const float* b_hh     = (const float*)d_in[8];
    const float* W_read   = (const float*)d_in[9];
    const float* b_read   = (const float*)d_in[10];
    const float* W_write  = (const float*)d_in[11];
    const float* b_write  = (const float*)d_in[12];
    const float* W_erase  = (const float*)d_in[13];
    const float* b_erase  = (const float*)d_in[14];
    const float* W_add    = (const float*)d_in[15];
    const float* b_add    = (const float*)d_in[16];
    const float* W_out    = (const float*)d_in[17];
    const float* b_out    = (const float*)d_in[18];
    float* out = (float*)d_out;
    char* wsp = (char*)d_ws;

    k_fused<<<dim3(GRID), dim3(256), 0, stream>>>(
        x, h_prev, c_prev, rwp, memory, W_ih, b_ih, W_hh, b_hh,
        W_read, b_read, W_write, b_write, W_erase, b_erase, W_add, b_add,
        W_out, b_out, out, wsp);
}

// Round 6
// 177.498 us; speedup vs baseline: 2.3553x; 1.0480x over previous
//
#include <hip/hip_runtime.h>
#include <hip/hip_bf16.h>

// NTM cell on MI355X. B=2048, IN=64, CTRL=512, M=1024, V=64, OUT=64.
// Single kernel, 560 blocks x 256 threads, 4 phases separated by a
// device-scope grid barrier v3 (elected L2 maintenance on BOTH sides):
//   stage A: relaxed arrival tree (16 lines) -> root1: all blocks' stores are
//            in their XCD's L2 (syncthreads vmcnt drain + write-through L1)
//   elect:   CAS on g_el[xcc] (xcc = s_getreg(HW_REG_XCC_ID)) -> one winner
//            per XCD per round, robust to any block->XCD mapping
//   stage B: winner adds RELEASE (buffer_wbl2 sc1: ONE L2 flush per XCD;
//            was per-block in r4), losers RELAXED; root2 full => all flushed
//   inv:     winner does ONE agent-ACQUIRE (buffer_inv sc1: own-XCD L2+L1
//            inv, AFTER all flushes) then sets g_done[xcc]=r+1 (r5 did this
//            per-block: 560 L2-inv walks/barrier -> the ~20us residual);
//            losers spin on their own XCD's g_done then L1-only
//            buffer_inv sc0 (per-CU cache, cheap)
// Monotonic counters -> no reset across graph replays.
//   phase0: blocks 0..127 split-K read_prev GEMM; blocks 128..559 grid-stride
//           fp32->bf16 converts to tile-major layouts
//   phase1: gates GEMM + fused LSTM (512 tiles; blocks 512..559 idle)
//   phase2: heads GEMM (560 tiles, exactly 1/block)
//   phase3: tail softmax + read_new + out-GEMM (blocks 0..255)
// Co-residency: 52KB LDS -> 3 blocks/CU; VGPR<=128 -> launch_bounds(256,3);
// 560 <= 768 slots so all blocks resident (no deadlock).

typedef unsigned short u16;
typedef __attribute__((ext_vector_type(8))) short bf16x8;
typedef __attribute__((ext_vector_type(4))) float f32x4;

#define MFMA_BF16(a, b, c) __builtin_amdgcn_mfma_f32_16x16x32_bf16((a), (b), (c), 0, 0, 0)
#define LDW 136
#define SLDW 520
#define SMEM_BYTES 53248
#define GRID 560
#define NGRP 16
#define GRPSZ 35

// Barrier state (zero-initialized at module load), 256B-strided lines.
__device__ unsigned g_a[3 * NGRP * 64];
__device__ unsigned g_b2[3 * NGRP * 64];
__device__ unsigned g_r1[3 * 64];
__device__ unsigned g_r2[3 * 64];
__device__ unsigned g_el[3 * 8 * 64];
__device__ unsigned g_done[3 * 8 * 64];

__device__ __forceinline__ void grid_barrier(int idx) {
    __syncthreads();                      // all block stores drained -> in local L2
    if (threadIdx.x == 0) {
        const int grp = blockIdx.x / GRPSZ;
        unsigned xcc;
        asm volatile("s_getreg_b32 %0, hwreg(HW_REG_XCC_ID)" : "=s"(xcc));
        xcc &= 7u;
        // ---- stage A: relaxed arrival ----
        unsigned t = __hip_atomic_fetch_add(&g_a[(idx * NGRP + grp) * 64], 1u,
                          __ATOMIC_RELAXED, __HIP_MEMORY_SCOPE_AGENT);
        unsigned r = t / GRPSZ;           // round number (monotonic)
        if (t - r * GRPSZ == GRPSZ - 1u)
            __hip_atomic_fetch_add(&g_r1[idx * 64], 1u,
                                   __ATOMIC_RELAXED, __HIP_MEMORY_SCOPE_AGENT);
        const unsigned tgt = r * NGRP + NGRP;
        while (__hip_atomic_load(&g_r1[idx * 64], __ATOMIC_RELAXED,
                                 __HIP_MEMORY_SCOPE_AGENT) < tgt)
            __builtin_amdgcn_s_sleep(2);
        // ---- elect one block per XCD ----
        unsigned expv = r;
        bool win = __hip_atomic_compare_exchange_strong(
            &g_el[(idx * 8 + xcc) * 64], &expv, r + 1u,
            __ATOMIC_RELAXED, __ATOMIC_RELAXED, __HIP_MEMORY_SCOPE_AGENT);
        // ---- stage B: winner RELEASE (one wbl2 per XCD), losers RELAXED ----
        unsigned t2;
        if (win)
            t2 = __hip_atomic_fetch_add(&g_b2[(idx * NGRP + grp) * 64], 1u,
                     __ATOMIC_RELEASE, __HIP_MEMORY_SCOPE_AGENT);
        else
            t2 = __hip_atomic_fetch_add(&g_b2[(idx * NGRP + grp) * 64], 1u,
                     __ATOMIC_RELAXED, __HIP_MEMORY_SCOPE_AGENT);
        unsigned r2 = t2 / GRPSZ;
        if (t2 - r2 * GRPSZ == GRPSZ - 1u)
            __hip_atomic_fetch_add(&g_r2[idx * 64], 1u,
                                   __ATOMIC_RELAXED, __HIP_MEMORY_SCOPE_AGENT);
        while (__hip_atomic_load(&g_r2[idx * 64], __ATOMIC_RELAXED,
                                 __HIP_MEMORY_SCOPE_AGENT) < tgt)
            __builtin_amdgcn_s_sleep(2);
        // ---- invalidate: ONE agent acquire per XCD, L1-only for the rest ----
        if (win) {
            unsigned v = __hip_atomic_load(&g_r2[idx * 64], __ATOMIC_ACQUIRE,
                                           __HIP_MEMORY_SCOPE_AGENT);
            asm volatile("" :: "v"(v) : "memory");  // keep inv-bearing load live
            __hip_atomic_store(&g_done[(idx * 8 + xcc) * 64], r + 1u,
                               __ATOMIC_RELAXED, __HIP_MEMORY_SCOPE_AGENT);
        } else {
            while (__hip_atomic_load(&g_done[(idx * 8 + xcc) * 64], __ATOMIC_RELAXED,
                                     __HIP_MEMORY_SCOPE_AGENT) < r + 1u)
                __builtin_amdgcn_s_sleep(2);
            asm volatile("buffer_inv sc0\n\ts_waitcnt vmcnt(0)" ::: "memory");
        }
    }
    __syncthreads();
}

__device__ __forceinline__ void dma16(const void* g, void* l) {
    __builtin_amdgcn_global_load_lds(
        (const __attribute__((address_space(1))) unsigned int*)g,
        (__attribute__((address_space(3))) unsigned int*)l, 16, 0, 0);
}

__device__ __forceinline__ u16 f2bf(float f) {
    union { float f; unsigned int u; } a; a.f = f;
    return (u16)((a.u + 0x7FFFu + ((a.u >> 16) & 1u)) >> 16);
}

__device__ __forceinline__ void pack_store4(float a0, float a1, float a2, float a3, u16* d) {
    union { __hip_bfloat162 h[2]; uint2 u; } cv;
    cv.h[0] = __float22bfloat162_rn(make_float2(a0, a1));
    cv.h[1] = __float22bfloat162_rn(make_float2(a2, a3));
    *(uint2*)d = cv.u;
}

__device__ __forceinline__ void cvt4(const float* __restrict__ s, u16* __restrict__ d) {
    float4 v = *(const float4*)s;
    pack_store4(v.x, v.y, v.z, v.w, d);
}

__device__ __forceinline__ uint4 cvt8u(const float* __restrict__ s) {
    float4 v0 = *(const float4*)(s);
    float4 v1 = *(const float4*)(s + 4);
    union { __hip_bfloat162 h[4]; uint4 u; } r;
    r.h[0] = __float22bfloat162_rn(make_float2(v0.x, v0.y));
    r.h[1] = __float22bfloat162_rn(make_float2(v0.z, v0.w));
    r.h[2] = __float22bfloat162_rn(make_float2(v1.x, v1.y));
    r.h[3] = __float22bfloat162_rn(make_float2(v1.z, v1.w));
    return r.u;
}

__device__ __forceinline__ uint4 cvt8u_sum4(const float* __restrict__ p, int off) {
    float4 a0 = *(const float4*)(p + off);
    float4 a1 = *(const float4*)(p + 131072 + off);
    float4 a2 = *(const float4*)(p + 262144 + off);
    float4 a3 = *(const float4*)(p + 393216 + off);
    float4 b0 = *(const float4*)(p + off + 4);
    float4 b1 = *(const float4*)(p + 131072 + off + 4);
    float4 b2 = *(const float4*)(p + 262144 + off + 4);
    float4 b3 = *(const float4*)(p + 393216 + off + 4);
    float4 s0{a0.x + a1.x + a2.x + a3.x, a0.y + a1.y + a2.y + a3.y,
              a0.z + a1.z + a2.z + a3.z, a0.w + a1.w + a2.w + a3.w};
    float4 s1{b0.x + b1.x + b2.x + b3.x, b0.y + b1.y + b2.y + b3.y,
              b0.z + b1.z + b2.z + b3.z, b0.w + b1.w + b2.w + b3.w};
    union { __hip_bfloat162 h[4]; uint4 u; } r;
    r.h[0] = __float22bfloat162_rn(make_float2(s0.x, s0.y));
    r.h[1] = __float22bfloat162_rn(make_float2(s0.z, s0.w));
    r.h[2] = __float22bfloat162_rn(make_float2(s1.x, s1.y));
    r.h[3] = __float22bfloat162_rn(make_float2(s1.z, s1.w));
    return r.u;
}

__device__ __forceinline__ void bfu4_to_f8(uint4 u, float* f) {
    f[0] = __uint_as_float(u.x << 16); f[1] = __uint_as_float(u.x & 0xffff0000u);
    f[2] = __uint_as_float(u.y << 16); f[3] = __uint_as_float(u.y & 0xffff0000u);
    f[4] = __uint_as_float(u.z << 16); f[5] = __uint_as_float(u.z & 0xffff0000u);
    f[6] = __uint_as_float(u.w << 16); f[7] = __uint_as_float(u.w & 0xffff0000u);
}

__device__ __forceinline__ uint4 pack8(const float* v) {
    union { __hip_bfloat162 h[4]; uint4 u; } r;
#pragma unroll
    for (int j = 0; j < 4; ++j) r.h[j] = __float22bfloat162_rn(make_float2(v[2 * j], v[2 * j + 1]));
    return r.u;
}

__device__ __forceinline__ float sigf(float x) { return 1.f / (1.f + __expf(-x)); }
__device__ __forceinline__ float fast_tanh(float x) { return 1.f - 2.f / (__expf(2.f * x) + 1.f); }

#define PIPE_BAR_PRE_CNT()  do {                                              \
    asm volatile("s_waitcnt vmcnt(6) lgkmcnt(0)" ::: "memory");               \
    __builtin_amdgcn_s_barrier();                                             \
    __builtin_amdgcn_sched_barrier(0);                                        \
} while (0)
#define PIPE_BAR_PRE_ZERO() do {                                              \
    asm volatile("s_waitcnt vmcnt(0) lgkmcnt(0)" ::: "memory");               \
    __builtin_amdgcn_s_barrier();                                             \
    __builtin_amdgcn_sched_barrier(0);                                        \
} while (0)
#define PIPE_BAR_POST() do {                                                  \
    __builtin_amdgcn_sched_barrier(0);                                        \
    asm volatile("s_waitcnt lgkmcnt(0)" ::: "memory");                        \
    __builtin_amdgcn_s_barrier();                                             \
    __builtin_amdgcn_sched_barrier(0);                                        \
} while (0)

// One fp32->bf16 tile-major convert unit, t in [0, 926720).
__device__ __forceinline__ void convert_unit(int t,
    const float* __restrict__ x, const float* __restrict__ h_prev,
    const float* __restrict__ W_ih, const float* __restrict__ W_hh,
    const float* __restrict__ W_read, const float* __restrict__ W_write,
    const float* __restrict__ W_erase, const float* __restrict__ W_add,
    const float* __restrict__ W_out, const float* __restrict__ memory,
    u16* x_t, u16* ht_t, u16* wcat_t, u16* Wcat2_t, u16* Wo_rn, u16* memt)
{
    if (t < 32768) {  // x -> x_t[mt][oct8][row128]
        int r = t >> 4, c = (t & 15) * 4;
        cvt4(x + r * 64 + c, x_t + ((r >> 7) * 8 + (c >> 3)) * 1024 + (r & 127) * 8 + (c & 7));
        return;
    }
    t -= 32768;
    if (t < 262144) {  // h_prev -> ht_t[mt][oct64][row128]
        int r = t >> 7, c = (t & 127) * 4;
        cvt4(h_prev + r * 512 + c, ht_t + ((r >> 7) * 64 + (c >> 3)) * 1024 + (r & 127) * 8 + (c & 7));
        return;
    }
    t -= 262144;
    if (t < 65536) {  // W_ih (gate-interleave rows, col swap rp|x) -> wcat_t[bn][kt0][oct][row64]
        int r = t >> 5, c = (t & 31) * 4;
        int g = r >> 9, j = r & 511;
        int bn = j >> 4, row64 = (g << 4) + (j & 15);
        int cd = (c < 64) ? c + 64 : c - 64;
        cvt4(W_ih + r * 128 + c, wcat_t + (bn * 5) * 8192 + (cd >> 3) * 512 + row64 * 8 + (cd & 7));
        return;
    }
    t -= 65536;
    if (t < 262144) {  // W_hh -> wcat_t[bn][kt1..4][oct][row64]
        int r = t >> 7, c = (t & 127) * 4;
        int g = r >> 9, j = r & 511;
        int bn = j >> 4, row64 = (g << 4) + (j & 15);
        int cd = 128 + c;
        cvt4(W_hh + r * 512 + c, wcat_t + (bn * 5 + (cd >> 7)) * 8192 + ((cd >> 3) & 15) * 512 + row64 * 8 + (cd & 7));
        return;
    }
    t -= 262144;
    if (t < 131072) {  // W_read -> Wcat2_t bn 0..15
        int r = t >> 7, c = (t & 127) * 4;
        cvt4(W_read + t * 4, Wcat2_t + ((r >> 6) * 4 + (c >> 7)) * 8192 + ((c >> 3) & 15) * 512 + (r & 63) * 8 + (c & 7));
        return;
    }
    t -= 131072;
    if (t < 131072) {  // W_write -> bn 16..31
        int r = t >> 7, c = (t & 127) * 4;
        cvt4(W_write + t * 4, Wcat2_t + ((16 + (r >> 6)) * 4 + (c >> 7)) * 8192 + ((c >> 3) & 15) * 512 + (r & 63) * 8 + (c & 7));
        return;
    }
    t -= 131072;
    if (t < 8192) {  // W_erase -> bn 32
        int r = t >> 7, c = (t & 127) * 4;
        cvt4(W_erase + t * 4, Wcat2_t + (32 * 4 + (c >> 7)) * 8192 + ((c >> 3) & 15) * 512 + r * 8 + (c & 7));
        return;
    }
    t -= 8192;
    if (t < 8192) {  // W_add -> bn 33
        int r = t >> 7, c = (t & 127) * 4;
        cvt4(W_add + t * 4, Wcat2_t + (33 * 4 + (c >> 7)) * 8192 + ((c >> 3) & 15) * 512 + r * 8 + (c & 7));
        return;
    }
    t -= 8192;
    if (t < 9216) {  // W_out: h-part -> bn 34; rn-part -> Wo_rn
        int r = t / 144, c = (t % 144) * 4;
        if (c < 512)
            cvt4(W_out + r * 576 + c, Wcat2_t + (34 * 4 + (c >> 7)) * 8192 + ((c >> 3) & 15) * 512 + r * 8 + (c & 7));
        else
            cvt4(W_out + r * 576 + c, Wo_rn + r * 64 + (c - 512));
        return;
    }
    t -= 9216;
    {  // memory^T -> memt (64 x 1024)
        int v = t >> 8, m = (t & 255) * 4;
        pack_store4(memory[m * 64 + v], memory[(m + 1) * 64 + v],
                    memory[(m + 2) * 64 + v], memory[(m + 3) * 64 + v], memt + v * 1024 + m);
    }
}

__global__ __launch_bounds__(256, 3) void k_fused(
    const float* __restrict__ x, const float* __restrict__ h_prev, const float* __restrict__ c_prev,
    const float* __restrict__ rwp, const float* __restrict__ memory,
    const float* __restrict__ W_ih, const float* __restrict__ b_ih,
    const float* __restrict__ W_hh, const float* __restrict__ b_hh,
    const float* __restrict__ W_read, const float* __restrict__ b_read,
    const float* __restrict__ W_write, const float* __restrict__ b_write,
    const float* __restrict__ W_erase, const float* __restrict__ b_erase,
    const float* __restrict__ W_add, const float* __restrict__ b_add,
    const float* __restrict__ W_out, const float* __restrict__ b_out,
    float* __restrict__ out, char* __restrict__ wsp)
{
    __shared__ __align__(16) char smem[SMEM_BYTES];

    u16*   x_t     = (u16*)(wsp + 0);           // 16 x 8oct x 128row x 8  (256 KB)
    u16*   ht_t    = (u16*)(wsp + 262144);      // 16 x 64oct x 128row x 8 (2 MB)
    u16*   wcat_t  = (u16*)(wsp + 2359296);     // 32bn x 5kt x 16oct x 64row x 8
    u16*   memt    = (u16*)(wsp + 4980736);     // 64 x 1024 bf16 memory^T
    u16*   Wcat2_t = (u16*)(wsp + 5111808);     // 35bn x 4kt x 16oct x 64row x 8
    u16*   Wo_rn   = (u16*)(wsp + 7405568);     // 64x64 bf16
    float* rp      = (float*)(wsp + 7413760);   // 4 x 2048x64 fp32 split-K partials
    u16*   hrn_t   = (u16*)(wsp + 9510912);     // 16 x 64oct x 128row x 8 (2 MB)
    u16*   pre_r   = (u16*)(wsp + 11608064);    // 2048x1024 bf16
    u16*   pre_w   = (u16*)(wsp + 15802368);    // 2048x1024 bf16
    float* erase   = (float*)(wsp + 19996672);  // 2048x64 fp32
    float* add     = (float*)(wsp + 20520960);  // 2048x64 fp32

    const int bid = blockIdx.x;
    const int tid = threadIdx.x, w = tid >> 6, lane = tid & 63;
    const int lrow = lane & 15, lq = lane >> 4;

    // ======================= phase 0: pre =======================
    if (bid < 128) {
        u16* As = (u16*)smem;                 // 64 x LDW
        u16* Bs = (u16*)(smem + 64 * LDW * 2);
        const int mb = bid & 31, ks = bid >> 5;
        const int m0 = mb * 64, k0 = ks * 256;
        const int m_loc = tid >> 1, v0 = (tid & 1) * 32;
        f32x4 acc[4] = {};
        for (int kt = 0; kt < 2; ++kt) {
#pragma unroll
            for (int i = 0; i < 4; ++i) {
                int idx = i * 256 + tid, r = idx >> 4, c = (idx & 15) * 8;
                *(uint4*)(&As[r * LDW + c]) = cvt8u(rwp + (m0 + r) * 1024 + k0 + kt * 128 + c);
            }
#pragma unroll
            for (int j = 0; j < 8; ++j) {
                float4 q = *(const float4*)(memory + (k0 + kt * 128 + m_loc) * 64 + v0 + 4 * j);
                Bs[(v0 + 4 * j + 0) * LDW + m_loc] = f2bf(q.x);
                Bs[(v0 + 4 * j + 1) * LDW + m_loc] = f2bf(q.y);
                Bs[(v0 + 4 * j + 2) * LDW + m_loc] = f2bf(q.z);
                Bs[(v0 + 4 * j + 3) * LDW + m_loc] = f2bf(q.w);
            }
            __syncthreads();
#pragma unroll
            for (int kk = 0; kk < 128; kk += 32) {
                bf16x8 a  = *(const bf16x8*)(&As[(16 * w + lrow) * LDW + kk + 8 * lq]);
                bf16x8 b0 = *(const bf16x8*)(&Bs[(lrow) * LDW + kk + 8 * lq]);
                bf16x8 b1 = *(const bf16x8*)(&Bs[(16 + lrow) * LDW + kk + 8 * lq]);
                bf16x8 b2 = *(const bf16x8*)(&Bs[(32 + lrow) * LDW + kk + 8 * lq]);
                bf16x8 b3 = *(const bf16x8*)(&Bs[(48 + lrow) * LDW + kk + 8 * lq]);
                acc[0] = MFMA_BF16(a, b0, acc[0]);
                acc[1] = MFMA_BF16(a, b1, acc[1]);
                acc[2] = MFMA_BF16(a, b2, acc[2]);
                acc[3] = MFMA_BF16(a, b3, acc[3]);
            }
            __syncthreads();
        }
        float* rps = rp + ks * 131072;
#pragma unroll
        for (int nj = 0; nj < 4; ++nj)
#pragma unroll
            for (int r = 0; r < 4; ++r) {
                int row = m0 + 16 * w + 4 * lq + r, col = 16 * nj + lrow;
                rps[row * 64 + col] = acc[nj][r];
            }
    } else {
        for (int t = (bid - 128) * 256 + tid; t < 926720; t += 432 * 256)
            convert_unit(t, x, h_prev, W_ih, W_hh, W_read, W_write, W_erase, W_add,
                         W_out, memory, x_t, ht_t, wcat_t, Wcat2_t, Wo_rn, memt);
    }
    grid_barrier(0);

    // ======================= phase 1: gates =======================
    if (bid < 512) {
        u16* AsG = (u16*)smem;                 // 2 x 8192 u16
        u16* BsG = (u16*)(smem + 32768);       // 2 x 4096 u16
        const int mt = bid & 15, bn = bid >> 4;
        const int m0 = mt * 128;
        f32x4 acc[2][4] = {};

        // prologue: tile 0 = rp strip (K 0..63). A via VGPR sum4-cvt, B via DMA.
#pragma unroll
        for (int i = 0; i < 4; ++i) {
            int cp = i * 256 + tid;
            *(uint4*)(&AsG[cp * 8]) = cvt8u_sum4(rp, (m0 + (cp & 127)) * 64 + (cp >> 7) * 8);
        }
#pragma unroll
        for (int i = 0; i < 2; ++i) {
            dma16(wcat_t + (bn * 5) * 8192 + (i * 256 + tid) * 8, &BsG[(i * 256 + w * 64) * 8]);
        }

#pragma unroll
        for (int t = 0; t < 10; ++t) {
            if (t < 9) {
                const int tn = t + 1, b = tn & 1;
                const u16* asrc = (tn == 1) ? (x_t + mt * 8192)
                                            : (ht_t + mt * 65536 + (tn - 2) * 8192);
#pragma unroll
                for (int i = 0; i < 4; ++i)
                    dma16(asrc + (i * 256 + tid) * 8, &AsG[b * 8192 + (i * 256 + w * 64) * 8]);
#pragma unroll
                for (int i = 0; i < 2; ++i)
                    dma16(wcat_t + (bn * 5 + (tn >> 1)) * 8192 + (tn & 1) * 4096 + (i * 256 + tid) * 8,
                          &BsG[b * 4096 + (i * 256 + w * 64) * 8]);
                PIPE_BAR_PRE_CNT();
            } else {
                PIPE_BAR_PRE_ZERO();
            }
            const int b = t & 1;
#pragma unroll
            for (int kk = 0; kk < 64; kk += 32) {
                const int ob = (kk >> 3) + lq;
                bf16x8 a0 = *(const bf16x8*)(&AsG[b * 8192 + ob * 1024 + (32 * w + lrow) * 8]);
                bf16x8 a1 = *(const bf16x8*)(&AsG[b * 8192 + ob * 1024 + (32 * w + 16 + lrow) * 8]);
                bf16x8 b0 = *(const bf16x8*)(&BsG[b * 4096 + ob * 512 + (lrow) * 8]);
                bf16x8 b1 = *(const bf16x8*)(&BsG[b * 4096 + ob * 512 + (16 + lrow) * 8]);
                bf16x8 b2 = *(const bf16x8*)(&BsG[b * 4096 + ob * 512 + (32 + lrow) * 8]);
                bf16x8 b3 = *(const bf16x8*)(&BsG[b * 4096 + ob * 512 + (48 + lrow) * 8]);
                acc[0][0] = MFMA_BF16(a0, b0, acc[0][0]);
                acc[0][1] = MFMA_BF16(a0, b1, acc[0][1]);
                acc[0][2] = MFMA_BF16(a0, b2, acc[0][2]);
                acc[0][3] = MFMA_BF16(a0, b3, acc[0][3]);
                acc[1][0] = MFMA_BF16(a1, b0, acc[1][0]);
                acc[1][1] = MFMA_BF16(a1, b1, acc[1][1]);
                acc[1][2] = MFMA_BF16(a1, b2, acc[1][2]);
                acc[1][3] = MFMA_BF16(a1, b3, acc[1][3]);
            }
            PIPE_BAR_POST();
        }

        const int j = bn * 16 + lrow;
        const float bI = b_ih[j] + b_hh[j];
        const float bF = b_ih[512 + j] + b_hh[512 + j];
        const float bG = b_ih[1024 + j] + b_hh[1024 + j];
        const float bO = b_ih[1536 + j] + b_hh[1536 + j];
#pragma unroll
        for (int mi = 0; mi < 2; ++mi)
#pragma unroll
            for (int r = 0; r < 4; ++r) {
                int row = m0 + 32 * w + 16 * mi + 4 * lq + r;
                float ig = sigf(acc[mi][0][r] + bI);
                float fg = sigf(acc[mi][1][r] + bF);
                float gg = fast_tanh(acc[mi][2][r] + bG);
                float og = sigf(acc[mi][3][r] + bO);
                float c = fg * c_prev[row * 512 + j] + ig * gg;
                hrn_t[(row >> 7) * 65536 + (j >> 3) * 1024 + (row & 127) * 8 + (j & 7)] =
                    f2bf(og * fast_tanh(c));
            }
    }
    grid_barrier(1);

    // ======================= phase 2: heads (1 tile/block) =======================
    {
        u16* AsG = (u16*)smem;
        u16* BsG = (u16*)(smem + 32768);
        const int mt = bid & 15, bn = bid >> 4;
        const int m0 = mt * 128;
        f32x4 acc[2][4] = {};

#pragma unroll
        for (int i = 0; i < 4; ++i)
            dma16(hrn_t + mt * 65536 + (i * 256 + tid) * 8, &AsG[(i * 256 + w * 64) * 8]);
#pragma unroll
        for (int i = 0; i < 2; ++i)
            dma16(Wcat2_t + (bn * 4) * 8192 + (i * 256 + tid) * 8, &BsG[(i * 256 + w * 64) * 8]);

#pragma unroll
        for (int t = 0; t < 8; ++t) {
            if (t < 7) {
                const int tn = t + 1, b = tn & 1;
#pragma unroll
                for (int i = 0; i < 4; ++i)
                    dma16(hrn_t + mt * 65536 + tn * 8192 + (i * 256 + tid) * 8,
                          &AsG[b * 8192 + (i * 256 + w * 64) * 8]);
#pragma unroll
                for (int i = 0; i < 2; ++i)
                    dma16(Wcat2_t + (bn * 4 + (tn >> 1)) * 8192 + (tn & 1) * 4096 + (i * 256 + tid) * 8,
                          &BsG[b * 4096 + (i * 256 + w * 64) * 8]);
                PIPE_BAR_PRE_CNT();
            } else {
                PIPE_BAR_PRE_ZERO();
            }
            const int b = t & 1;
#pragma unroll
            for (int kk = 0; kk < 64; kk += 32) {
                const int ob = (kk >> 3) + lq;
                bf16x8 a0 = *(const bf16x8*)(&AsG[b * 8192 + ob * 1024 + (32 * w + lrow) * 8]);
                bf16x8 a1 = *(const bf16x8*)(&AsG[b * 8192 + ob * 1024 + (32 * w + 16 + lrow) * 8]);
                bf16x8 b0 = *(const bf16x8*)(&BsG[b * 4096 + ob * 512 + (lrow) * 8]);
                bf16x8 b1 = *(const bf16x8*)(&BsG[b * 4096 + ob * 512 + (16 + lrow) * 8]);
                bf16x8 b2 = *(const bf16x8*)(&BsG[b * 4096 + ob * 512 + (32 + lrow) * 8]);
                bf16x8 b3 = *(const bf16x8*)(&BsG[b * 4096 + ob * 512 + (48 + lrow) * 8]);
                acc[0][0] = MFMA_BF16(a0, b0, acc[0][0]);
                acc[0][1] = MFMA_BF16(a0, b1, acc[0][1]);
                acc[0][2] = MFMA_BF16(a0, b2, acc[0][2]);
                acc[0][3] = MFMA_BF16(a0, b3, acc[0][3]);
                acc[1][0] = MFMA_BF16(a1, b0, acc[1][0]);
                acc[1][1] = MFMA_BF16(a1, b1, acc[1][1]);
                acc[1][2] = MFMA_BF16(a1, b2, acc[1][2]);
                acc[1][3] = MFMA_BF16(a1, b3, acc[1][3]);
            }
            PIPE_BAR_POST();
        }

#pragma unroll
        for (int mi = 0; mi < 2; ++mi)
#pragma unroll
            for (int nj = 0; nj < 4; ++nj)
#pragma unroll
                for (int r = 0; r < 4; ++r) {
                    int row = m0 + 32 * w + 16 * mi + 4 * lq + r;
                    int col = bn * 64 + 16 * nj + lrow;
                    float v = acc[mi][nj][r];
                    if (bn < 16)       pre_r[row * 1024 + col] = f2bf(v + b_read[col]);
                    else if (bn < 32)  pre_w[row * 1024 + (col - 1024)] = f2bf(v + b_write[col - 1024]);
                    else if (bn == 32) erase[row * 64 + (col - 2048)] = sigf(v + b_erase[col - 2048]);
                    else if (bn == 33) add[row * 64 + (col - 2112)] = fast_tanh(v + b_add[col - 2112]);
                    else               out[row * 64 + (col - 2176)] = v + b_out[col - 2176];
                }
    }
    grid_barrier(2);

    // ======================= phase 3: tail =======================
    if (bid < 256) {
        u16*   rwS  = (u16*)smem;                    // 16 x SLDW
        u16*   rw2S = (u16*)(smem + 16640);          // 16 x SLDW
        u16*   BsP  = (u16*)(smem + 33280);          // 64 x LDW
        u16*   Ps   = (u16*)(smem + 50688);          // 16 x 72
        float* s_sh = (float*)(smem + 52992);        // 16
        const int mb = bid >> 1, kh = bid & 1;
        const int m0 = mb * 16, k0 = kh * 512;

        {
            const int row = tid >> 4, c16 = tid & 15;
            const int row_g = m0 + row;
            const u16* prp = pre_r + row_g * 1024;
            const u16* pwp = pre_w + row_g * 1024;
            float vr[64], vw[64];
#pragma unroll
            for (int q = 0; q < 8; ++q) {
                bfu4_to_f8(*(const uint4*)(prp + q * 128 + c16 * 8), vr + 8 * q);
                bfu4_to_f8(*(const uint4*)(pwp + q * 128 + c16 * 8), vw + 8 * q);
            }
            float mr = vr[0], mw = vw[0];
#pragma unroll
            for (int i = 1; i < 64; ++i) { mr = fmaxf(mr, vr[i]); mw = fmaxf(mw, vw[i]); }
#pragma unroll
            for (int o = 1; o < 16; o <<= 1) {
                mr = fmaxf(mr, __shfl_xor(mr, o, 64));
                mw = fmaxf(mw, __shfl_xor(mw, o, 64));
            }
            float sr = 0.f, sw = 0.f;
#pragma unroll
            for (int i = 0; i < 64; ++i) {
                vr[i] = __expf(vr[i] - mr); sr += vr[i];
                vw[i] = __expf(vw[i] - mw); sw += vw[i];
            }
#pragma unroll
            for (int o = 1; o < 16; o <<= 1) {
                sr += __shfl_xor(sr, o, 64);
                sw += __shfl_xor(sw, o, 64);
            }
            const float isr = 1.f / sr, isw = 1.f / sw;
            float ss = 0.f;
#pragma unroll
            for (int q = 0; q < 8; ++q) {
                float a8[8], r8[8];
#pragma unroll
                for (int i = 0; i < 8; ++i) {
                    float a = vr[8 * q + i] * isr;
                    float r2 = a * (vw[8 * q + i] * isw);
                    a8[i] = a; r8[i] = r2;
                    ss += r2;
                }
                if ((q >> 2) == kh) {
                    int cb = (q - 4 * kh) * 128 + c16 * 8;
                    *(uint4*)(&rwS[row * SLDW + cb])  = pack8(a8);
                    *(uint4*)(&rw2S[row * SLDW + cb]) = pack8(r8);
                }
            }
#pragma unroll
            for (int o = 1; o < 16; o <<= 1) ss += __shfl_xor(ss, o, 64);
            if (c16 == 0) s_sh[row] = ss;
        }
        __syncthreads();

        f32x4 acc1 = {}, acc2 = {};
        for (int kt = 0; kt < 4; ++kt) {
#pragma unroll
            for (int i = 0; i < 4; ++i) {
                int idx = i * 256 + tid, r = idx >> 4, c = (idx & 15) * 8;
                *(uint4*)(&BsP[r * LDW + c]) = *(const uint4*)(memt + r * 1024 + k0 + kt * 128 + c);
            }
            __syncthreads();
#pragma unroll
            for (int kk = 0; kk < 128; kk += 32) {
                bf16x8 a1 = *(const bf16x8*)(&rwS[lrow * SLDW + kt * 128 + kk + 8 * lq]);
                bf16x8 a2 = *(const bf16x8*)(&rw2S[lrow * SLDW + kt * 128 + kk + 8 * lq]);
                bf16x8 b  = *(const bf16x8*)(&BsP[(16 * w + lrow) * LDW + kk + 8 * lq]);
                acc1 = MFMA_BF16(a1, b, acc1);
                acc2 = MFMA_BF16(a2, b, acc2);
            }
            __syncthreads();
        }

#pragma unroll
        for (int r = 0; r < 4; ++r) {
            int row_l = 4 * lq + r, col = 16 * w + lrow;
            int row_g = m0 + row_l;
            float p = acc1[r] - erase[row_g * 64 + col] * acc2[r];
            if (kh == 0) p += add[row_g * 64 + col] * s_sh[row_l];
            Ps[row_l * 72 + col] = f2bf(p);
        }
#pragma unroll
        for (int i = 0; i < 2; ++i) {
            int idx = i * 256 + tid, r = idx >> 3, c = (idx & 7) * 8;
            *(uint4*)(&BsP[r * LDW + c]) = *(const uint4*)(Wo_rn + r * 64 + c);
        }
        __syncthreads();

        f32x4 acc3 = {};
#pragma unroll
        for (int kk = 0; kk < 64; kk += 32) {
            bf16x8 a = *(const bf16x8*)(&Ps[lrow * 72 + kk + 8 * lq]);
            bf16x8 b = *(const bf16x8*)(&BsP[(16 * w + lrow) * LDW + kk + 8 * lq]);
            acc3 = MFMA_BF16(a, b, acc3);
        }
#pragma unroll
        for (int r = 0; r < 4; ++r) {
            int row_g = m0 + 4 * lq + r, col = 16 * w + lrow;
            atomicAdd(&out[row_g * 64 + col], acc3[r]);
        }
    }
}

extern "C" void kernel_launch(void* const* d_in, const int* in_sizes, int n_in,
                              void* d_out, int out_size, void* d_ws, size_t ws_size,
                              hipStream_t stream)
{
    const float* x        = (const float*)d_in[0];
    const float* h_prev   = (const float*)d_in[1];
    const float* c_prev   = (const float*)d_in[2];
    const float* rwp      = (const float*)d_in[3];
    const float* memory   = (const float*)d_in[4];
    const float* W_ih     = (const float*)d_in[5];
    const float* b_ih     = (const float*)d_in[6];
    const float* W_hh     = (const float*)d_in[7];
    const float* b_hh     = (const float*)d_in[8];
    const float* W_read   = (const float*)d_in[9];
    const float* b_read   = (const float*)d_in[10];
    const float* W_write  = (const float*)d_in[11];
    const float* b_write  = (const float*)d_in[12];
    const float* W_erase  = (const float*)d_in[13];
    const float* b_erase  = (const float*)d_in[14];
    const float* W_add    = (const float*)d_in[15];
    const float* b_add    = (const float*)d_in[16];
    const float* W_out    = (const float*)d_in[17];
    const float* b_out    = (const float*)d_in[18];
    float* out = (float*)d_out;
    char* wsp = (char*)d_ws;

    k_fused<<<dim3(GRID), dim3(256), 0, stream>>>(
        x, h_prev, c_prev, rwp, memory, W_ih, b_ih, W_hh, b_hh,
        W_read, b_read, W_write, b_write, W_erase, b_erase, W_add, b_add,
        W_out, b_out, out, wsp);
}

// Round 7
// 156.785 us; speedup vs baseline: 2.6664x; 1.1321x over previous
//
#include <hip/hip_runtime.h>
#include <hip/hip_bf16.h>

// NTM cell on MI355X. B=2048, IN=64, CTRL=512, M=1024, V=64, OUT=64.
// 4 dispatches (reverted from the fused+grid-barrier experiments of r2-r6:
// measured barrier floor ~16us x3 makes fused ~= 4-kernel; 4-kernel is the
// known-good base). This round: k_pre grid 3748 -> 640 blocks (128 GEMM +
// 512 grid-stride convert blocks, ~7 units/thread) to cut dispatch ramp and
// add per-thread ILP. k_gates/k_heads keep the 2-phase dbuf pipeline (r1).

typedef unsigned short u16;
typedef __attribute__((ext_vector_type(8))) short bf16x8;
typedef __attribute__((ext_vector_type(4))) float f32x4;

#define MFMA_BF16(a, b, c) __builtin_amdgcn_mfma_f32_16x16x32_bf16((a), (b), (c), 0, 0, 0)
#define LDW 136
#define SLDW 520

__device__ __forceinline__ void dma16(const void* g, void* l) {
    __builtin_amdgcn_global_load_lds(
        (const __attribute__((address_space(1))) unsigned int*)g,
        (__attribute__((address_space(3))) unsigned int*)l, 16, 0, 0);
}

__device__ __forceinline__ u16 f2bf(float f) {
    union { float f; unsigned int u; } a; a.f = f;
    return (u16)((a.u + 0x7FFFu + ((a.u >> 16) & 1u)) >> 16);
}

__device__ __forceinline__ void pack_store4(float a0, float a1, float a2, float a3, u16* d) {
    union { __hip_bfloat162 h[2]; uint2 u; } cv;
    cv.h[0] = __float22bfloat162_rn(make_float2(a0, a1));
    cv.h[1] = __float22bfloat162_rn(make_float2(a2, a3));
    *(uint2*)d = cv.u;
}

__device__ __forceinline__ void cvt4(const float* __restrict__ s, u16* __restrict__ d) {
    float4 v = *(const float4*)s;
    pack_store4(v.x, v.y, v.z, v.w, d);
}

__device__ __forceinline__ uint4 cvt8u(const float* __restrict__ s) {
    float4 v0 = *(const float4*)(s);
    float4 v1 = *(const float4*)(s + 4);
    union { __hip_bfloat162 h[4]; uint4 u; } r;
    r.h[0] = __float22bfloat162_rn(make_float2(v0.x, v0.y));
    r.h[1] = __float22bfloat162_rn(make_float2(v0.z, v0.w));
    r.h[2] = __float22bfloat162_rn(make_float2(v1.x, v1.y));
    r.h[3] = __float22bfloat162_rn(make_float2(v1.z, v1.w));
    return r.u;
}

__device__ __forceinline__ uint4 cvt8u_sum4(const float* __restrict__ p, int off) {
    float4 a0 = *(const float4*)(p + off);
    float4 a1 = *(const float4*)(p + 131072 + off);
    float4 a2 = *(const float4*)(p + 262144 + off);
    float4 a3 = *(const float4*)(p + 393216 + off);
    float4 b0 = *(const float4*)(p + off + 4);
    float4 b1 = *(const float4*)(p + 131072 + off + 4);
    float4 b2 = *(const float4*)(p + 262144 + off + 4);
    float4 b3 = *(const float4*)(p + 393216 + off + 4);
    float4 s0{a0.x + a1.x + a2.x + a3.x, a0.y + a1.y + a2.y + a3.y,
              a0.z + a1.z + a2.z + a3.z, a0.w + a1.w + a2.w + a3.w};
    float4 s1{b0.x + b1.x + b2.x + b3.x, b0.y + b1.y + b2.y + b3.y,
              b0.z + b1.z + b2.z + b3.z, b0.w + b1.w + b2.w + b3.w};
    union { __hip_bfloat162 h[4]; uint4 u; } r;
    r.h[0] = __float22bfloat162_rn(make_float2(s0.x, s0.y));
    r.h[1] = __float22bfloat162_rn(make_float2(s0.z, s0.w));
    r.h[2] = __float22bfloat162_rn(make_float2(s1.x, s1.y));
    r.h[3] = __float22bfloat162_rn(make_float2(s1.z, s1.w));
    return r.u;
}

__device__ __forceinline__ void bfu4_to_f8(uint4 u, float* f) {
    f[0] = __uint_as_float(u.x << 16); f[1] = __uint_as_float(u.x & 0xffff0000u);
    f[2] = __uint_as_float(u.y << 16); f[3] = __uint_as_float(u.y & 0xffff0000u);
    f[4] = __uint_as_float(u.z << 16); f[5] = __uint_as_float(u.z & 0xffff0000u);
    f[6] = __uint_as_float(u.w << 16); f[7] = __uint_as_float(u.w & 0xffff0000u);
}

__device__ __forceinline__ uint4 pack8(const float* v) {
    union { __hip_bfloat162 h[4]; uint4 u; } r;
#pragma unroll
    for (int j = 0; j < 4; ++j) r.h[j] = __float22bfloat162_rn(make_float2(v[2 * j], v[2 * j + 1]));
    return r.u;
}

__device__ __forceinline__ float sigf(float x) { return 1.f / (1.f + __expf(-x)); }
__device__ __forceinline__ float fast_tanh(float x) { return 1.f - 2.f / (__expf(2.f * x) + 1.f); }

#define PIPE_BAR_PRE_CNT()  do {                                              \
    asm volatile("s_waitcnt vmcnt(6) lgkmcnt(0)" ::: "memory");               \
    __builtin_amdgcn_s_barrier();                                             \
    __builtin_amdgcn_sched_barrier(0);                                        \
} while (0)
#define PIPE_BAR_PRE_ZERO() do {                                              \
    asm volatile("s_waitcnt vmcnt(0) lgkmcnt(0)" ::: "memory");               \
    __builtin_amdgcn_s_barrier();                                             \
    __builtin_amdgcn_sched_barrier(0);                                        \
} while (0)
#define PIPE_BAR_POST() do {                                                  \
    __builtin_amdgcn_sched_barrier(0);                                        \
    asm volatile("s_waitcnt lgkmcnt(0)" ::: "memory");                        \
    __builtin_amdgcn_s_barrier();                                             \
    __builtin_amdgcn_sched_barrier(0);                                        \
} while (0)

// One fp32->bf16 tile-major convert unit, t in [0, 926720).
__device__ __forceinline__ void convert_unit(int t,
    const float* __restrict__ x, const float* __restrict__ h_prev,
    const float* __restrict__ W_ih, const float* __restrict__ W_hh,
    const float* __restrict__ W_read, const float* __restrict__ W_write,
    const float* __restrict__ W_erase, const float* __restrict__ W_add,
    const float* __restrict__ W_out, const float* __restrict__ memory,
    u16* x_t, u16* ht_t, u16* wcat_t, u16* Wcat2_t, u16* Wo_rn, u16* memt)
{
    if (t < 32768) {  // x -> x_t[mt][oct8][row128]
        int r = t >> 4, c = (t & 15) * 4;
        cvt4(x + r * 64 + c, x_t + ((r >> 7) * 8 + (c >> 3)) * 1024 + (r & 127) * 8 + (c & 7));
        return;
    }
    t -= 32768;
    if (t < 262144) {  // h_prev -> ht_t[mt][oct64][row128]
        int r = t >> 7, c = (t & 127) * 4;
        cvt4(h_prev + r * 512 + c, ht_t + ((r >> 7) * 64 + (c >> 3)) * 1024 + (r & 127) * 8 + (c & 7));
        return;
    }
    t -= 262144;
    if (t < 65536) {  // W_ih (gate-interleave rows, col swap rp|x) -> wcat_t[bn][kt0][oct][row64]
        int r = t >> 5, c = (t & 31) * 4;
        int g = r >> 9, j = r & 511;
        int bn = j >> 4, row64 = (g << 4) + (j & 15);
        int cd = (c < 64) ? c + 64 : c - 64;
        cvt4(W_ih + r * 128 + c, wcat_t + (bn * 5) * 8192 + (cd >> 3) * 512 + row64 * 8 + (cd & 7));
        return;
    }
    t -= 65536;
    if (t < 262144) {  // W_hh -> wcat_t[bn][kt1..4][oct][row64]
        int r = t >> 7, c = (t & 127) * 4;
        int g = r >> 9, j = r & 511;
        int bn = j >> 4, row64 = (g << 4) + (j & 15);
        int cd = 128 + c;
        cvt4(W_hh + r * 512 + c, wcat_t + (bn * 5 + (cd >> 7)) * 8192 + ((cd >> 3) & 15) * 512 + row64 * 8 + (cd & 7));
        return;
    }
    t -= 262144;
    if (t < 131072) {  // W_read -> Wcat2_t bn 0..15
        int r = t >> 7, c = (t & 127) * 4;
        cvt4(W_read + t * 4, Wcat2_t + ((r >> 6) * 4 + (c >> 7)) * 8192 + ((c >> 3) & 15) * 512 + (r & 63) * 8 + (c & 7));
        return;
    }
    t -= 131072;
    if (t < 131072) {  // W_write -> bn 16..31
        int r = t >> 7, c = (t & 127) * 4;
        cvt4(W_write + t * 4, Wcat2_t + ((16 + (r >> 6)) * 4 + (c >> 7)) * 8192 + ((c >> 3) & 15) * 512 + (r & 63) * 8 + (c & 7));
        return;
    }
    t -= 131072;
    if (t < 8192) {  // W_erase -> bn 32
        int r = t >> 7, c = (t & 127) * 4;
        cvt4(W_erase + t * 4, Wcat2_t + (32 * 4 + (c >> 7)) * 8192 + ((c >> 3) & 15) * 512 + r * 8 + (c & 7));
        return;
    }
    t -= 8192;
    if (t < 8192) {  // W_add -> bn 33
        int r = t >> 7, c = (t & 127) * 4;
        cvt4(W_add + t * 4, Wcat2_t + (33 * 4 + (c >> 7)) * 8192 + ((c >> 3) & 15) * 512 + r * 8 + (c & 7));
        return;
    }
    t -= 8192;
    if (t < 9216) {  // W_out: h-part -> bn 34; rn-part -> Wo_rn
        int r = t / 144, c = (t % 144) * 4;
        if (c < 512)
            cvt4(W_out + r * 576 + c, Wcat2_t + (34 * 4 + (c >> 7)) * 8192 + ((c >> 3) & 15) * 512 + r * 8 + (c & 7));
        else
            cvt4(W_out + r * 576 + c, Wo_rn + r * 64 + (c - 512));
        return;
    }
    t -= 9216;
    {  // memory^T -> memt (64 x 1024)
        int v = t >> 8, m = (t & 255) * 4;
        pack_store4(memory[m * 64 + v], memory[(m + 1) * 64 + v],
                    memory[(m + 2) * 64 + v], memory[(m + 3) * 64 + v], memt + v * 1024 + m);
    }
}

// ---------------------------------------------------------------------------
// k_pre: blocks 0..127 = split-K read_prev GEMM. Blocks 128..639 = grid-stride
// fp32->bf16 converts writing TILE-MAJOR layouts (~7 units/thread for ILP).
// ---------------------------------------------------------------------------
__global__ __launch_bounds__(256) void k_pre(
    const float* __restrict__ x, const float* __restrict__ h_prev, const float* __restrict__ rwp,
    const float* __restrict__ memory, const float* __restrict__ W_ih, const float* __restrict__ W_hh,
    const float* __restrict__ W_read, const float* __restrict__ W_write, const float* __restrict__ W_erase,
    const float* __restrict__ W_add, const float* __restrict__ W_out,
    u16* x_t, u16* ht_t, u16* wcat_t, u16* Wcat2_t, u16* Wo_rn, u16* memt, float* rp)
{
    __shared__ u16 As[64 * LDW];
    __shared__ u16 Bs[64 * LDW];
    const int tid = threadIdx.x;

    if (blockIdx.x < 128) {
        const int mb = blockIdx.x & 31, ks = blockIdx.x >> 5;
        const int w = tid >> 6, lane = tid & 63;
        const int lrow = lane & 15, lq = lane >> 4;
        const int m0 = mb * 64, k0 = ks * 256;
        const int m_loc = tid >> 1, v0 = (tid & 1) * 32;
        f32x4 acc[4] = {};
        for (int kt = 0; kt < 2; ++kt) {
#pragma unroll
            for (int i = 0; i < 4; ++i) {
                int idx = i * 256 + tid, r = idx >> 4, c = (idx & 15) * 8;
                *(uint4*)(&As[r * LDW + c]) = cvt8u(rwp + (m0 + r) * 1024 + k0 + kt * 128 + c);
            }
#pragma unroll
            for (int j = 0; j < 8; ++j) {
                float4 q = *(const float4*)(memory + (k0 + kt * 128 + m_loc) * 64 + v0 + 4 * j);
                Bs[(v0 + 4 * j + 0) * LDW + m_loc] = f2bf(q.x);
                Bs[(v0 + 4 * j + 1) * LDW + m_loc] = f2bf(q.y);
                Bs[(v0 + 4 * j + 2) * LDW + m_loc] = f2bf(q.z);
                Bs[(v0 + 4 * j + 3) * LDW + m_loc] = f2bf(q.w);
            }
            __syncthreads();
#pragma unroll
            for (int kk = 0; kk < 128; kk += 32) {
                bf16x8 a  = *(const bf16x8*)(&As[(16 * w + lrow) * LDW + kk + 8 * lq]);
                bf16x8 b0 = *(const bf16x8*)(&Bs[(lrow) * LDW + kk + 8 * lq]);
                bf16x8 b1 = *(const bf16x8*)(&Bs[(16 + lrow) * LDW + kk + 8 * lq]);
                bf16x8 b2 = *(const bf16x8*)(&Bs[(32 + lrow) * LDW + kk + 8 * lq]);
                bf16x8 b3 = *(const bf16x8*)(&Bs[(48 + lrow) * LDW + kk + 8 * lq]);
                acc[0] = MFMA_BF16(a, b0, acc[0]);
                acc[1] = MFMA_BF16(a, b1, acc[1]);
                acc[2] = MFMA_BF16(a, b2, acc[2]);
                acc[3] = MFMA_BF16(a, b3, acc[3]);
            }
            __syncthreads();
        }
        float* rps = rp + ks * 131072;
#pragma unroll
        for (int nj = 0; nj < 4; ++nj)
#pragma unroll
            for (int r = 0; r < 4; ++r) {
                int row = m0 + 16 * w + 4 * lq + r, col = 16 * nj + lrow;
                rps[row * 64 + col] = acc[nj][r];
            }
        return;
    }

    for (int t = (blockIdx.x - 128) * 256 + tid; t < 926720; t += 512 * 256)
        convert_unit(t, x, h_prev, W_ih, W_hh, W_read, W_write, W_erase, W_add,
                     W_out, memory, x_t, ht_t, wcat_t, Wcat2_t, Wo_rn, memt);
}

// ---------------------------------------------------------------------------
// gates GEMM + fused LSTM. A-K = [rp(64) | x(64) | h(512)] = 10 BK=64 tiles.
// Double-buffered 2-phase pipeline with counted vmcnt(6).
// ---------------------------------------------------------------------------
__global__ __launch_bounds__(256) void k_gates(const u16* __restrict__ x_t, const u16* __restrict__ ht_t,
                                               const float* __restrict__ rp, const u16* __restrict__ wcat_t,
                                               const float* __restrict__ b_ih, const float* __restrict__ b_hh,
                                               const float* __restrict__ c_prev, u16* __restrict__ hrn_t)
{
    __shared__ u16 As[2][8192];   // 2 x (8 oct x 128 row x 8)  = 32 KB
    __shared__ u16 Bs[2][4096];   // 2 x (8 oct x  64 row x 8)  = 16 KB
    const int tid = threadIdx.x, w = tid >> 6, lane = tid & 63;
    const int lrow = lane & 15, lq = lane >> 4;
    const int mt = blockIdx.x, bn = blockIdx.y;
    const int m0 = mt * 128;
    f32x4 acc[2][4] = {};

    // prologue: tile 0 = rp strip (K 0..63). A via VGPR sum4-cvt, B via DMA.
#pragma unroll
    for (int i = 0; i < 4; ++i) {
        int cp = i * 256 + tid;                     // chunk = oct*128 + row
        *(uint4*)(&As[0][cp * 8]) = cvt8u_sum4(rp, (m0 + (cp & 127)) * 64 + (cp >> 7) * 8);
    }
#pragma unroll
    for (int i = 0; i < 2; ++i) {
        int cp = i * 256 + tid;
        dma16(wcat_t + (bn * 5) * 8192 + cp * 8, &Bs[0][(i * 256 + w * 64) * 8]);
    }

#pragma unroll
    for (int t = 0; t < 10; ++t) {
        if (t < 9) {
            const int tn = t + 1, b = tn & 1;
            const u16* asrc = (tn == 1) ? (x_t + mt * 8192)
                                        : (ht_t + mt * 65536 + (tn - 2) * 8192);
#pragma unroll
            for (int i = 0; i < 4; ++i) {
                int cp = i * 256 + tid;
                dma16(asrc + cp * 8, &As[b][(i * 256 + w * 64) * 8]);
            }
#pragma unroll
            for (int i = 0; i < 2; ++i) {
                int cp = i * 256 + tid;
                dma16(wcat_t + (bn * 5 + (tn >> 1)) * 8192 + (tn & 1) * 4096 + cp * 8,
                      &Bs[b][(i * 256 + w * 64) * 8]);
            }
            PIPE_BAR_PRE_CNT();
        } else {
            PIPE_BAR_PRE_ZERO();
        }
        const int b = t & 1;
#pragma unroll
        for (int kk = 0; kk < 64; kk += 32) {
            const int ob = (kk >> 3) + lq;
            bf16x8 a0 = *(const bf16x8*)(&As[b][ob * 1024 + (32 * w + lrow) * 8]);
            bf16x8 a1 = *(const bf16x8*)(&As[b][ob * 1024 + (32 * w + 16 + lrow) * 8]);
            bf16x8 b0 = *(const bf16x8*)(&Bs[b][ob * 512 + (lrow) * 8]);
            bf16x8 b1 = *(const bf16x8*)(&Bs[b][ob * 512 + (16 + lrow) * 8]);
            bf16x8 b2 = *(const bf16x8*)(&Bs[b][ob * 512 + (32 + lrow) * 8]);
            bf16x8 b3 = *(const bf16x8*)(&Bs[b][ob * 512 + (48 + lrow) * 8]);
            acc[0][0] = MFMA_BF16(a0, b0, acc[0][0]);
            acc[0][1] = MFMA_BF16(a0, b1, acc[0][1]);
            acc[0][2] = MFMA_BF16(a0, b2, acc[0][2]);
            acc[0][3] = MFMA_BF16(a0, b3, acc[0][3]);
            acc[1][0] = MFMA_BF16(a1, b0, acc[1][0]);
            acc[1][1] = MFMA_BF16(a1, b1, acc[1][1]);
            acc[1][2] = MFMA_BF16(a1, b2, acc[1][2]);
            acc[1][3] = MFMA_BF16(a1, b3, acc[1][3]);
        }
        PIPE_BAR_POST();
    }

    const int j = bn * 16 + lrow;
    const float bI = b_ih[j] + b_hh[j];
    const float bF = b_ih[512 + j] + b_hh[512 + j];
    const float bG = b_ih[1024 + j] + b_hh[1024 + j];
    const float bO = b_ih[1536 + j] + b_hh[1536 + j];
#pragma unroll
    for (int mi = 0; mi < 2; ++mi)
#pragma unroll
        for (int r = 0; r < 4; ++r) {
            int row = m0 + 32 * w + 16 * mi + 4 * lq + r;
            float ig = sigf(acc[mi][0][r] + bI);
            float fg = sigf(acc[mi][1][r] + bF);
            float gg = fast_tanh(acc[mi][2][r] + bG);
            float og = sigf(acc[mi][3][r] + bO);
            float c = fg * c_prev[row * 512 + j] + ig * gg;
            // h -> tile-major hrn_t[mt][oct][row]
            hrn_t[(row >> 7) * 65536 + (j >> 3) * 1024 + (row & 127) * 8 + (j & 7)] =
                f2bf(og * fast_tanh(c));
        }
}

// ---------------------------------------------------------------------------
// heads: [pre_read | pre_write | erase | add | out_h] = h @ Wcat2^T + biases.
// grid (16, 35). Same 2-phase double-buffered pipeline, 8 BK=64 tiles.
// ---------------------------------------------------------------------------
__global__ __launch_bounds__(256) void k_heads(const u16* __restrict__ hrn_t, const u16* __restrict__ Wcat2_t,
                                               const float* __restrict__ b_read, const float* __restrict__ b_write,
                                               const float* __restrict__ b_erase, const float* __restrict__ b_add,
                                               const float* __restrict__ b_out,
                                               u16* __restrict__ pre_r, u16* __restrict__ pre_w,
                                               float* __restrict__ erase, float* __restrict__ add,
                                               float* __restrict__ out)
{
    __shared__ u16 As[2][8192];
    __shared__ u16 Bs[2][4096];
    const int tid = threadIdx.x, w = tid >> 6, lane = tid & 63;
    const int lrow = lane & 15, lq = lane >> 4;
    const int mt = blockIdx.x, bn = blockIdx.y;
    const int m0 = mt * 128;
    f32x4 acc[2][4] = {};

    // prologue: stage tile 0
#pragma unroll
    for (int i = 0; i < 4; ++i) {
        int cp = i * 256 + tid;
        dma16(hrn_t + mt * 65536 + cp * 8, &As[0][(i * 256 + w * 64) * 8]);
    }
#pragma unroll
    for (int i = 0; i < 2; ++i) {
        int cp = i * 256 + tid;
        dma16(Wcat2_t + (bn * 4) * 8192 + cp * 8, &Bs[0][(i * 256 + w * 64) * 8]);
    }

#pragma unroll
    for (int t = 0; t < 8; ++t) {
        if (t < 7) {
            const int tn = t + 1, b = tn & 1;
#pragma unroll
            for (int i = 0; i < 4; ++i) {
                int cp = i * 256 + tid;
                dma16(hrn_t + mt * 65536 + tn * 8192 + cp * 8, &As[b][(i * 256 + w * 64) * 8]);
            }
#pragma unroll
            for (int i = 0; i < 2; ++i) {
                int cp = i * 256 + tid;
                dma16(Wcat2_t + (bn * 4 + (tn >> 1)) * 8192 + (tn & 1) * 4096 + cp * 8,
                      &Bs[b][(i * 256 + w * 64) * 8]);
            }
            PIPE_BAR_PRE_CNT();
        } else {
            PIPE_BAR_PRE_ZERO();
        }
        const int b = t & 1;
#pragma unroll
        for (int kk = 0; kk < 64; kk += 32) {
            const int ob = (kk >> 3) + lq;
            bf16x8 a0 = *(const bf16x8*)(&As[b][ob * 1024 + (32 * w + lrow) * 8]);
            bf16x8 a1 = *(const bf16x8*)(&As[b][ob * 1024 + (32 * w + 16 + lrow) * 8]);
            bf16x8 b0 = *(const bf16x8*)(&Bs[b][ob * 512 + (lrow) * 8]);
            bf16x8 b1 = *(const bf16x8*)(&Bs[b][ob * 512 + (16 + lrow) * 8]);
            bf16x8 b2 = *(const bf16x8*)(&Bs[b][ob * 512 + (32 + lrow) * 8]);
            bf16x8 b3 = *(const bf16x8*)(&Bs[b][ob * 512 + (48 + lrow) * 8]);
            acc[0][0] = MFMA_BF16(a0, b0, acc[0][0]);
            acc[0][1] = MFMA_BF16(a0, b1, acc[0][1]);
            acc[0][2] = MFMA_BF16(a0, b2, acc[0][2]);
            acc[0][3] = MFMA_BF16(a0, b3, acc[0][3]);
            acc[1][0] = MFMA_BF16(a1, b0, acc[1][0]);
            acc[1][1] = MFMA_BF16(a1, b1, acc[1][1]);
            acc[1][2] = MFMA_BF16(a1, b2, acc[1][2]);
            acc[1][3] = MFMA_BF16(a1, b3, acc[1][3]);
        }
        PIPE_BAR_POST();
    }

#pragma unroll
    for (int mi = 0; mi < 2; ++mi)
#pragma unroll
        for (int nj = 0; nj < 4; ++nj)
#pragma unroll
            for (int r = 0; r < 4; ++r) {
                int row = m0 + 32 * w + 16 * mi + 4 * lq + r;
                int col = bn * 64 + 16 * nj + lrow;
                float v = acc[mi][nj][r];
                if (bn < 16)       pre_r[row * 1024 + col] = f2bf(v + b_read[col]);
                else if (bn < 32)  pre_w[row * 1024 + (col - 1024)] = f2bf(v + b_write[col - 1024]);
                else if (bn == 32) erase[row * 64 + (col - 2048)] = sigf(v + b_erase[col - 2048]);
                else if (bn == 33) add[row * 64 + (col - 2112)] = fast_tanh(v + b_add[col - 2112]);
                else               out[row * 64 + (col - 2176)] = v + b_out[col - 2176];
            }
}

// ---------------------------------------------------------------------------
// k_tail: 256 blocks = 128 m-blocks (16 rows) x 2 K-halves.
// dual softmax (redundant across halves) -> LDS; read_new GEMM (K=512);
// partial rn through Wo_rn^T; atomicAdd into out (seeded with out_h + b_out).
// ---------------------------------------------------------------------------
__global__ __launch_bounds__(256) void k_tail(const u16* __restrict__ pre_r, const u16* __restrict__ pre_w,
                                              const u16* __restrict__ memt, const u16* __restrict__ Wo_rn,
                                              const float* __restrict__ erase, const float* __restrict__ add,
                                              float* __restrict__ out)
{
    __shared__ u16 rwS[16 * SLDW];
    __shared__ u16 rw2S[16 * SLDW];
    __shared__ u16 BsP[64 * LDW];
    __shared__ u16 Ps[16 * 72];
    __shared__ float s_sh[16];
    const int tid = threadIdx.x, w = tid >> 6, lane = tid & 63;
    const int lrow = lane & 15, lq = lane >> 4;
    const int mb = blockIdx.x >> 1, kh = blockIdx.x & 1;
    const int m0 = mb * 16, k0 = kh * 512;

    {
        const int row = tid >> 4, c16 = tid & 15;
        const int row_g = m0 + row;
        const u16* prp = pre_r + row_g * 1024;
        const u16* pwp = pre_w + row_g * 1024;
        float vr[64], vw[64];
#pragma unroll
        for (int q = 0; q < 8; ++q) {
            bfu4_to_f8(*(const uint4*)(prp + q * 128 + c16 * 8), vr + 8 * q);
            bfu4_to_f8(*(const uint4*)(pwp + q * 128 + c16 * 8), vw + 8 * q);
        }
        float mr = vr[0], mw = vw[0];
#pragma unroll
        for (int i = 1; i < 64; ++i) { mr = fmaxf(mr, vr[i]); mw = fmaxf(mw, vw[i]); }
#pragma unroll
        for (int o = 1; o < 16; o <<= 1) {
            mr = fmaxf(mr, __shfl_xor(mr, o, 64));
            mw = fmaxf(mw, __shfl_xor(mw, o, 64));
        }
        float sr = 0.f, sw = 0.f;
#pragma unroll
        for (int i = 0; i < 64; ++i) {
            vr[i] = __expf(vr[i] - mr); sr += vr[i];
            vw[i] = __expf(vw[i] - mw); sw += vw[i];
        }
#pragma unroll
        for (int o = 1; o < 16; o <<= 1) {
            sr += __shfl_xor(sr, o, 64);
            sw += __shfl_xor(sw, o, 64);
        }
        const float isr = 1.f / sr, isw = 1.f / sw;
        float ss = 0.f;
#pragma unroll
        for (int q = 0; q < 8; ++q) {
            float a8[8], r8[8];
#pragma unroll
            for (int i = 0; i < 8; ++i) {
                float a = vr[8 * q + i] * isr;
                float r2 = a * (vw[8 * q + i] * isw);
                a8[i] = a; r8[i] = r2;
                ss += r2;
            }
            if ((q >> 2) == kh) {
                int cb = (q - 4 * kh) * 128 + c16 * 8;
                *(uint4*)(&rwS[row * SLDW + cb])  = pack8(a8);
                *(uint4*)(&rw2S[row * SLDW + cb]) = pack8(r8);
            }
        }
#pragma unroll
        for (int o = 1; o < 16; o <<= 1) ss += __shfl_xor(ss, o, 64);
        if (c16 == 0) s_sh[row] = ss;
    }
    __syncthreads();

    f32x4 acc1 = {}, acc2 = {};
    for (int kt = 0; kt < 4; ++kt) {
#pragma unroll
        for (int i = 0; i < 4; ++i) {
            int idx = i * 256 + tid, r = idx >> 4, c = (idx & 15) * 8;
            *(uint4*)(&BsP[r * LDW + c]) = *(const uint4*)(memt + r * 1024 + k0 + kt * 128 + c);
        }
        __syncthreads();
#pragma unroll
        for (int kk = 0; kk < 128; kk += 32) {
            bf16x8 a1 = *(const bf16x8*)(&rwS[lrow * SLDW + kt * 128 + kk + 8 * lq]);
            bf16x8 a2 = *(const bf16x8*)(&rw2S[lrow * SLDW + kt * 128 + kk + 8 * lq]);
            bf16x8 b  = *(const bf16x8*)(&BsP[(16 * w + lrow) * LDW + kk + 8 * lq]);
            acc1 = MFMA_BF16(a1, b, acc1);
            acc2 = MFMA_BF16(a2, b, acc2);
        }
        __syncthreads();
    }

#pragma unroll
    for (int r = 0; r < 4; ++r) {
        int row_l = 4 * lq + r, col = 16 * w + lrow;
        int row_g = m0 + row_l;
        float p = acc1[r] - erase[row_g * 64 + col] * acc2[r];
        if (kh == 0) p += add[row_g * 64 + col] * s_sh[row_l];
        Ps[row_l * 72 + col] = f2bf(p);
    }
#pragma unroll
    for (int i = 0; i < 2; ++i) {
        int idx = i * 256 + tid, r = idx >> 3, c = (idx & 7) * 8;
        *(uint4*)(&BsP[r * LDW + c]) = *(const uint4*)(Wo_rn + r * 64 + c);
    }
    __syncthreads();

    f32x4 acc3 = {};
#pragma unroll
    for (int kk = 0; kk < 64; kk += 32) {
        bf16x8 a = *(const bf16x8*)(&Ps[lrow * 72 + kk + 8 * lq]);
        bf16x8 b = *(const bf16x8*)(&BsP[(16 * w + lrow) * LDW + kk + 8 * lq]);
        acc3 = MFMA_BF16(a, b, acc3);
    }
#pragma unroll
    for (int r = 0; r < 4; ++r) {
        int row_g = m0 + 4 * lq + r, col = 16 * w + lrow;
        atomicAdd(&out[row_g * 64 + col], acc3[r]);
    }
}

extern "C" void kernel_launch(void* const* d_in, const int* in_sizes, int n_in,
                              void* d_out, int out_size, void* d_ws, size_t ws_size,
                              hipStream_t stream)
{
    const float* x        = (const float*)d_in[0];
    const float* h_prev   = (const float*)d_in[1];
    const float* c_prev   = (const float*)d_in[2];
    const float* rwp      = (const float*)d_in[3];
    const float* memory   = (const float*)d_in[4];
    const float* W_ih     = (const float*)d_in[5];
    const float* b_ih     = (const float*)d_in[6];
    const float* W_hh     = (const float*)d_in[7];
    const float* b_hh     = (const float*)d_in[8];
    const float* W_read   = (const float*)d_in[9];
    const float* b_read   = (const float*)d_in[10];
    const float* W_write  = (const float*)d_in[11];
    const float* b_write  = (const float*)d_in[12];
    const float* W_erase  = (const float*)d_in[13];
    const float* b_erase  = (const float*)d_in[14];
    const float* W_add    = (const float*)d_in[15];
    const float* b_add    = (const float*)d_in[16];
    const float* W_out    = (const float*)d_in[17];
    const float* b_out    = (const float*)d_in[18];
    float* out = (float*)d_out;

    char* wsp = (char*)d_ws;
    u16*   x_t     = (u16*)(wsp + 0);           // 16 x 8oct x 128row x 8  (256 KB)
    u16*   ht_t    = (u16*)(wsp + 262144);      // 16 x 64oct x 128row x 8 (2 MB)
    u16*   wcat_t  = (u16*)(wsp + 2359296);     // 32bn x 5kt x 16oct x 64row x 8
    u16*   memt    = (u16*)(wsp + 4980736);     // 64 x 1024 bf16 memory^T
    u16*   Wcat2_t = (u16*)(wsp + 5111808);     // 35bn x 4kt x 16oct x 64row x 8
    u16*   Wo_rn   = (u16*)(wsp + 7405568);     // 64x64 bf16
    float* rp      = (float*)(wsp + 7413760);   // 4 x 2048x64 fp32 split-K partials
    u16*   hrn_t   = (u16*)(wsp + 9510912);     // 16 x 64oct x 128row x 8 (2 MB)
    u16*   pre_r   = (u16*)(wsp + 11608064);    // 2048x1024 bf16
    u16*   pre_w   = (u16*)(wsp + 15802368);    // 2048x1024 bf16
    float* erase   = (float*)(wsp + 19996672);  // 2048x64 fp32
    float* add     = (float*)(wsp + 20520960);  // 2048x64 fp32

    k_pre<<<640, 256, 0, stream>>>(x, h_prev, rwp, memory, W_ih, W_hh, W_read, W_write,
                                   W_erase, W_add, W_out,
                                   x_t, ht_t, wcat_t, Wcat2_t, Wo_rn, memt, rp);
    k_gates<<<dim3(16, 32), 256, 0, stream>>>(x_t, ht_t, rp, wcat_t, b_ih, b_hh, c_prev, hrn_t);
    k_heads<<<dim3(16, 35), 256, 0, stream>>>(hrn_t, Wcat2_t, b_read, b_write, b_erase, b_add, b_out,
                                              pre_r, pre_w, erase, add, out);
    k_tail<<<256, 256, 0, stream>>>(pre_r, pre_w, memt, Wo_rn, erase, add, out);
}

// Round 8
// 154.098 us; speedup vs baseline: 2.7129x; 1.0174x over previous
//
#include <hip/hip_runtime.h>
#include <hip/hip_bf16.h>

// NTM cell on MI355X. B=2048, IN=64, CTRL=512, M=1024, V=64, OUT=64.
// 4 dispatches. This round: kill the rp fp32 split-K round-trip.
// k_pre's read_prev GEMM is now FULL-K (128 blocks x 16 rows x K=1024,
// 8 staging rounds) and writes bf16 directly in the gates A-tile fragment
// layout (rpt, 256 KB). k_gates tile 0 becomes a plain 6-DMA prefetch like
// tiles 1..9 (was: 32 float4 loads + sum4 + cvt per thread = 64 MB L2 reads
// + serialized VALU prologue across 512 blocks).

typedef unsigned short u16;
typedef __attribute__((ext_vector_type(8))) short bf16x8;
typedef __attribute__((ext_vector_type(4))) float f32x4;

#define MFMA_BF16(a, b, c) __builtin_amdgcn_mfma_f32_16x16x32_bf16((a), (b), (c), 0, 0, 0)
#define LDW 136
#define SLDW 520

__device__ __forceinline__ void dma16(const void* g, void* l) {
    __builtin_amdgcn_global_load_lds(
        (const __attribute__((address_space(1))) unsigned int*)g,
        (__attribute__((address_space(3))) unsigned int*)l, 16, 0, 0);
}

__device__ __forceinline__ u16 f2bf(float f) {
    union { float f; unsigned int u; } a; a.f = f;
    return (u16)((a.u + 0x7FFFu + ((a.u >> 16) & 1u)) >> 16);
}

__device__ __forceinline__ void pack_store4(float a0, float a1, float a2, float a3, u16* d) {
    union { __hip_bfloat162 h[2]; uint2 u; } cv;
    cv.h[0] = __float22bfloat162_rn(make_float2(a0, a1));
    cv.h[1] = __float22bfloat162_rn(make_float2(a2, a3));
    *(uint2*)d = cv.u;
}

__device__ __forceinline__ void cvt4(const float* __restrict__ s, u16* __restrict__ d) {
    float4 v = *(const float4*)s;
    pack_store4(v.x, v.y, v.z, v.w, d);
}

__device__ __forceinline__ uint4 cvt8u(const float* __restrict__ s) {
    float4 v0 = *(const float4*)(s);
    float4 v1 = *(const float4*)(s + 4);
    union { __hip_bfloat162 h[4]; uint4 u; } r;
    r.h[0] = __float22bfloat162_rn(make_float2(v0.x, v0.y));
    r.h[1] = __float22bfloat162_rn(make_float2(v0.z, v0.w));
    r.h[2] = __float22bfloat162_rn(make_float2(v1.x, v1.y));
    r.h[3] = __float22bfloat162_rn(make_float2(v1.z, v1.w));
    return r.u;
}

__device__ __forceinline__ void bfu4_to_f8(uint4 u, float* f) {
    f[0] = __uint_as_float(u.x << 16); f[1] = __uint_as_float(u.x & 0xffff0000u);
    f[2] = __uint_as_float(u.y << 16); f[3] = __uint_as_float(u.y & 0xffff0000u);
    f[4] = __uint_as_float(u.z << 16); f[5] = __uint_as_float(u.z & 0xffff0000u);
    f[6] = __uint_as_float(u.w << 16); f[7] = __uint_as_float(u.w & 0xffff0000u);
}

__device__ __forceinline__ uint4 pack8(const float* v) {
    union { __hip_bfloat162 h[4]; uint4 u; } r;
#pragma unroll
    for (int j = 0; j < 4; ++j) r.h[j] = __float22bfloat162_rn(make_float2(v[2 * j], v[2 * j + 1]));
    return r.u;
}

__device__ __forceinline__ float sigf(float x) { return 1.f / (1.f + __expf(-x)); }
__device__ __forceinline__ float fast_tanh(float x) { return 1.f - 2.f / (__expf(2.f * x) + 1.f); }

#define PIPE_BAR_PRE_CNT()  do {                                              \
    asm volatile("s_waitcnt vmcnt(6) lgkmcnt(0)" ::: "memory");               \
    __builtin_amdgcn_s_barrier();                                             \
    __builtin_amdgcn_sched_barrier(0);                                        \
} while (0)
#define PIPE_BAR_PRE_ZERO() do {                                              \
    asm volatile("s_waitcnt vmcnt(0) lgkmcnt(0)" ::: "memory");               \
    __builtin_amdgcn_s_barrier();                                             \
    __builtin_amdgcn_sched_barrier(0);                                        \
} while (0)
#define PIPE_BAR_POST() do {                                                  \
    __builtin_amdgcn_sched_barrier(0);                                        \
    asm volatile("s_waitcnt lgkmcnt(0)" ::: "memory");                        \
    __builtin_amdgcn_s_barrier();                                             \
    __builtin_amdgcn_sched_barrier(0);                                        \
} while (0)

// One fp32->bf16 tile-major convert unit, t in [0, 926720).
__device__ __forceinline__ void convert_unit(int t,
    const float* __restrict__ x, const float* __restrict__ h_prev,
    const float* __restrict__ W_ih, const float* __restrict__ W_hh,
    const float* __restrict__ W_read, const float* __restrict__ W_write,
    const float* __restrict__ W_erase, const float* __restrict__ W_add,
    const float* __restrict__ W_out, const float* __restrict__ memory,
    u16* x_t, u16* ht_t, u16* wcat_t, u16* Wcat2_t, u16* Wo_rn, u16* memt)
{
    if (t < 32768) {  // x -> x_t[mt][oct8][row128]
        int r = t >> 4, c = (t & 15) * 4;
        cvt4(x + r * 64 + c, x_t + ((r >> 7) * 8 + (c >> 3)) * 1024 + (r & 127) * 8 + (c & 7));
        return;
    }
    t -= 32768;
    if (t < 262144) {  // h_prev -> ht_t[mt][oct64][row128]
        int r = t >> 7, c = (t & 127) * 4;
        cvt4(h_prev + r * 512 + c, ht_t + ((r >> 7) * 64 + (c >> 3)) * 1024 + (r & 127) * 8 + (c & 7));
        return;
    }
    t -= 262144;
    if (t < 65536) {  // W_ih (gate-interleave rows, col swap rp|x) -> wcat_t[bn][kt0][oct][row64]
        int r = t >> 5, c = (t & 31) * 4;
        int g = r >> 9, j = r & 511;
        int bn = j >> 4, row64 = (g << 4) + (j & 15);
        int cd = (c < 64) ? c + 64 : c - 64;
        cvt4(W_ih + r * 128 + c, wcat_t + (bn * 5) * 8192 + (cd >> 3) * 512 + row64 * 8 + (cd & 7));
        return;
    }
    t -= 65536;
    if (t < 262144) {  // W_hh -> wcat_t[bn][kt1..4][oct][row64]
        int r = t >> 7, c = (t & 127) * 4;
        int g = r >> 9, j = r & 511;
        int bn = j >> 4, row64 = (g << 4) + (j & 15);
        int cd = 128 + c;
        cvt4(W_hh + r * 512 + c, wcat_t + (bn * 5 + (cd >> 7)) * 8192 + ((cd >> 3) & 15) * 512 + row64 * 8 + (cd & 7));
        return;
    }
    t -= 262144;
    if (t < 131072) {  // W_read -> Wcat2_t bn 0..15
        int r = t >> 7, c = (t & 127) * 4;
        cvt4(W_read + t * 4, Wcat2_t + ((r >> 6) * 4 + (c >> 7)) * 8192 + ((c >> 3) & 15) * 512 + (r & 63) * 8 + (c & 7));
        return;
    }
    t -= 131072;
    if (t < 131072) {  // W_write -> bn 16..31
        int r = t >> 7, c = (t & 127) * 4;
        cvt4(W_write + t * 4, Wcat2_t + ((16 + (r >> 6)) * 4 + (c >> 7)) * 8192 + ((c >> 3) & 15) * 512 + (r & 63) * 8 + (c & 7));
        return;
    }
    t -= 131072;
    if (t < 8192) {  // W_erase -> bn 32
        int r = t >> 7, c = (t & 127) * 4;
        cvt4(W_erase + t * 4, Wcat2_t + (32 * 4 + (c >> 7)) * 8192 + ((c >> 3) & 15) * 512 + r * 8 + (c & 7));
        return;
    }
    t -= 8192;
    if (t < 8192) {  // W_add -> bn 33
        int r = t >> 7, c = (t & 127) * 4;
        cvt4(W_add + t * 4, Wcat2_t + (33 * 4 + (c >> 7)) * 8192 + ((c >> 3) & 15) * 512 + r * 8 + (c & 7));
        return;
    }
    t -= 8192;
    if (t < 9216) {  // W_out: h-part -> bn 34; rn-part -> Wo_rn
        int r = t / 144, c = (t % 144) * 4;
        if (c < 512)
            cvt4(W_out + r * 576 + c, Wcat2_t + (34 * 4 + (c >> 7)) * 8192 + ((c >> 3) & 15) * 512 + r * 8 + (c & 7));
        else
            cvt4(W_out + r * 576 + c, Wo_rn + r * 64 + (c - 512));
        return;
    }
    t -= 9216;
    {  // memory^T -> memt (64 x 1024)
        int v = t >> 8, m = (t & 255) * 4;
        pack_store4(memory[m * 64 + v], memory[(m + 1) * 64 + v],
                    memory[(m + 2) * 64 + v], memory[(m + 3) * 64 + v], memt + v * 1024 + m);
    }
}

// ---------------------------------------------------------------------------
// k_pre: blocks 0..127 = read_prev GEMM, FULL-K (16 rows x 64 cols x K=1024
// per block, 8 staging rounds), writing bf16 directly in the gates A-tile
// fragment layout rpt[mt][oct8][row128][8]. Blocks 128..639 = grid-stride
// fp32->bf16 converts writing TILE-MAJOR layouts.
// ---------------------------------------------------------------------------
__global__ __launch_bounds__(256) void k_pre(
    const float* __restrict__ x, const float* __restrict__ h_prev, const float* __restrict__ rwp,
    const float* __restrict__ memory, const float* __restrict__ W_ih, const float* __restrict__ W_hh,
    const float* __restrict__ W_read, const float* __restrict__ W_write, const float* __restrict__ W_erase,
    const float* __restrict__ W_add, const float* __restrict__ W_out,
    u16* x_t, u16* ht_t, u16* wcat_t, u16* Wcat2_t, u16* Wo_rn, u16* memt, u16* rpt)
{
    __shared__ u16 As[64 * LDW];
    __shared__ u16 Bs[64 * LDW];
    const int tid = threadIdx.x;

    if (blockIdx.x < 128) {
        const int mb = blockIdx.x;
        const int w = tid >> 6, lane = tid & 63;
        const int lrow = lane & 15, lq = lane >> 4;
        const int m0 = mb * 16;
        const int m_loc = tid >> 1, v0 = (tid & 1) * 32;
        f32x4 acc = {};
        for (int kt = 0; kt < 8; ++kt) {
            {   // As: 16 rows x 128 K (one cvt8u per thread)
                int r = tid >> 4, c = (tid & 15) * 8;
                *(uint4*)(&As[r * LDW + c]) = cvt8u(rwp + (m0 + r) * 1024 + kt * 128 + c);
            }
#pragma unroll
            for (int j = 0; j < 8; ++j) {  // Bs: v-major 64 x 128
                float4 q = *(const float4*)(memory + (kt * 128 + m_loc) * 64 + v0 + 4 * j);
                Bs[(v0 + 4 * j + 0) * LDW + m_loc] = f2bf(q.x);
                Bs[(v0 + 4 * j + 1) * LDW + m_loc] = f2bf(q.y);
                Bs[(v0 + 4 * j + 2) * LDW + m_loc] = f2bf(q.z);
                Bs[(v0 + 4 * j + 3) * LDW + m_loc] = f2bf(q.w);
            }
            __syncthreads();
#pragma unroll
            for (int kk = 0; kk < 128; kk += 32) {
                bf16x8 a = *(const bf16x8*)(&As[lrow * LDW + kk + 8 * lq]);
                bf16x8 b = *(const bf16x8*)(&Bs[(16 * w + lrow) * LDW + kk + 8 * lq]);
                acc = MFMA_BF16(a, b, acc);
            }
            __syncthreads();
        }
        // write bf16 in gates-A fragment layout: elem [row][v] ->
        // rpt[(row>>7)*8192 + (v>>3)*1024 + (row&127)*8 + (v&7)]
#pragma unroll
        for (int r = 0; r < 4; ++r) {
            int row = m0 + 4 * lq + r, v = 16 * w + lrow;
            rpt[(row >> 7) * 8192 + (v >> 3) * 1024 + (row & 127) * 8 + (v & 7)] = f2bf(acc[r]);
        }
        return;
    }

    for (int t = (blockIdx.x - 128) * 256 + tid; t < 926720; t += 512 * 256)
        convert_unit(t, x, h_prev, W_ih, W_hh, W_read, W_write, W_erase, W_add,
                     W_out, memory, x_t, ht_t, wcat_t, Wcat2_t, Wo_rn, memt);
}

// ---------------------------------------------------------------------------
// gates GEMM + fused LSTM. A-K = [rp(64) | x(64) | h(512)] = 10 BK=64 tiles,
// ALL staged via dma16 now (tile 0 from rpt). 2-phase dbuf, vmcnt(6).
// ---------------------------------------------------------------------------
__global__ __launch_bounds__(256) void k_gates(const u16* __restrict__ rpt, const u16* __restrict__ x_t,
                                               const u16* __restrict__ ht_t, const u16* __restrict__ wcat_t,
                                               const float* __restrict__ b_ih, const float* __restrict__ b_hh,
                                               const float* __restrict__ c_prev, u16* __restrict__ hrn_t)
{
    __shared__ u16 As[2][8192];   // 2 x (8 oct x 128 row x 8)  = 32 KB
    __shared__ u16 Bs[2][4096];   // 2 x (8 oct x  64 row x 8)  = 16 KB
    const int tid = threadIdx.x, w = tid >> 6, lane = tid & 63;
    const int lrow = lane & 15, lq = lane >> 4;
    const int mt = blockIdx.x, bn = blockIdx.y;
    const int m0 = mt * 128;
    f32x4 acc[2][4] = {};

    // prologue: stage tile 0 (rp strip) via DMA, same as every other tile.
#pragma unroll
    for (int i = 0; i < 4; ++i)
        dma16(rpt + mt * 8192 + (i * 256 + tid) * 8, &As[0][(i * 256 + w * 64) * 8]);
#pragma unroll
    for (int i = 0; i < 2; ++i)
        dma16(wcat_t + (bn * 5) * 8192 + (i * 256 + tid) * 8, &Bs[0][(i * 256 + w * 64) * 8]);

#pragma unroll
    for (int t = 0; t < 10; ++t) {
        if (t < 9) {
            const int tn = t + 1, b = tn & 1;
            const u16* asrc = (tn == 1) ? (x_t + mt * 8192)
                                        : (ht_t + mt * 65536 + (tn - 2) * 8192);
#pragma unroll
            for (int i = 0; i < 4; ++i)
                dma16(asrc + (i * 256 + tid) * 8, &As[b][(i * 256 + w * 64) * 8]);
#pragma unroll
            for (int i = 0; i < 2; ++i)
                dma16(wcat_t + (bn * 5 + (tn >> 1)) * 8192 + (tn & 1) * 4096 + (i * 256 + tid) * 8,
                      &Bs[b][(i * 256 + w * 64) * 8]);
            PIPE_BAR_PRE_CNT();
        } else {
            PIPE_BAR_PRE_ZERO();
        }
        const int b = t & 1;
#pragma unroll
        for (int kk = 0; kk < 64; kk += 32) {
            const int ob = (kk >> 3) + lq;
            bf16x8 a0 = *(const bf16x8*)(&As[b][ob * 1024 + (32 * w + lrow) * 8]);
            bf16x8 a1 = *(const bf16x8*)(&As[b][ob * 1024 + (32 * w + 16 + lrow) * 8]);
            bf16x8 b0 = *(const bf16x8*)(&Bs[b][ob * 512 + (lrow) * 8]);
            bf16x8 b1 = *(const bf16x8*)(&Bs[b][ob * 512 + (16 + lrow) * 8]);
            bf16x8 b2 = *(const bf16x8*)(&Bs[b][ob * 512 + (32 + lrow) * 8]);
            bf16x8 b3 = *(const bf16x8*)(&Bs[b][ob * 512 + (48 + lrow) * 8]);
            acc[0][0] = MFMA_BF16(a0, b0, acc[0][0]);
            acc[0][1] = MFMA_BF16(a0, b1, acc[0][1]);
            acc[0][2] = MFMA_BF16(a0, b2, acc[0][2]);
            acc[0][3] = MFMA_BF16(a0, b3, acc[0][3]);
            acc[1][0] = MFMA_BF16(a1, b0, acc[1][0]);
            acc[1][1] = MFMA_BF16(a1, b1, acc[1][1]);
            acc[1][2] = MFMA_BF16(a1, b2, acc[1][2]);
            acc[1][3] = MFMA_BF16(a1, b3, acc[1][3]);
        }
        PIPE_BAR_POST();
    }

    const int j = bn * 16 + lrow;
    const float bI = b_ih[j] + b_hh[j];
    const float bF = b_ih[512 + j] + b_hh[512 + j];
    const float bG = b_ih[1024 + j] + b_hh[1024 + j];
    const float bO = b_ih[1536 + j] + b_hh[1536 + j];
#pragma unroll
    for (int mi = 0; mi < 2; ++mi)
#pragma unroll
        for (int r = 0; r < 4; ++r) {
            int row = m0 + 32 * w + 16 * mi + 4 * lq + r;
            float ig = sigf(acc[mi][0][r] + bI);
            float fg = sigf(acc[mi][1][r] + bF);
            float gg = fast_tanh(acc[mi][2][r] + bG);
            float og = sigf(acc[mi][3][r] + bO);
            float c = fg * c_prev[row * 512 + j] + ig * gg;
            // h -> tile-major hrn_t[mt][oct][row]
            hrn_t[(row >> 7) * 65536 + (j >> 3) * 1024 + (row & 127) * 8 + (j & 7)] =
                f2bf(og * fast_tanh(c));
        }
}

// ---------------------------------------------------------------------------
// heads: [pre_read | pre_write | erase | add | out_h] = h @ Wcat2^T + biases.
// grid (16, 35). Same 2-phase double-buffered pipeline, 8 BK=64 tiles.
// ---------------------------------------------------------------------------
__global__ __launch_bounds__(256) void k_heads(const u16* __restrict__ hrn_t, const u16* __restrict__ Wcat2_t,
                                               const float* __restrict__ b_read, const float* __restrict__ b_write,
                                               const float* __restrict__ b_erase, const float* __restrict__ b_add,
                                               const float* __restrict__ b_out,
                                               u16* __restrict__ pre_r, u16* __restrict__ pre_w,
                                               float* __restrict__ erase, float* __restrict__ add,
                                               float* __restrict__ out)
{
    __shared__ u16 As[2][8192];
    __shared__ u16 Bs[2][4096];
    const int tid = threadIdx.x, w = tid >> 6, lane = tid & 63;
    const int lrow = lane & 15, lq = lane >> 4;
    const int mt = blockIdx.x, bn = blockIdx.y;
    const int m0 = mt * 128;
    f32x4 acc[2][4] = {};

    // prologue: stage tile 0
#pragma unroll
    for (int i = 0; i < 4; ++i)
        dma16(hrn_t + mt * 65536 + (i * 256 + tid) * 8, &As[0][(i * 256 + w * 64) * 8]);
#pragma unroll
    for (int i = 0; i < 2; ++i)
        dma16(Wcat2_t + (bn * 4) * 8192 + (i * 256 + tid) * 8, &Bs[0][(i * 256 + w * 64) * 8]);

#pragma unroll
    for (int t = 0; t < 8; ++t) {
        if (t < 7) {
            const int tn = t + 1, b = tn & 1;
#pragma unroll
            for (int i = 0; i < 4; ++i)
                dma16(hrn_t + mt * 65536 + tn * 8192 + (i * 256 + tid) * 8,
                      &As[b][(i * 256 + w * 64) * 8]);
#pragma unroll
            for (int i = 0; i < 2; ++i)
                dma16(Wcat2_t + (bn * 4 + (tn >> 1)) * 8192 + (tn & 1) * 4096 + (i * 256 + tid) * 8,
                      &Bs[b][(i * 256 + w * 64) * 8]);
            PIPE_BAR_PRE_CNT();
        } else {
            PIPE_BAR_PRE_ZERO();
        }
        const int b = t & 1;
#pragma unroll
        for (int kk = 0; kk < 64; kk += 32) {
            const int ob = (kk >> 3) + lq;
            bf16x8 a0 = *(const bf16x8*)(&As[b][ob * 1024 + (32 * w + lrow) * 8]);
            bf16x8 a1 = *(const bf16x8*)(&As[b][ob * 1024 + (32 * w + 16 + lrow) * 8]);
            bf16x8 b0 = *(const bf16x8*)(&Bs[b][ob * 512 + (lrow) * 8]);
            bf16x8 b1 = *(const bf16x8*)(&Bs[b][ob * 512 + (16 + lrow) * 8]);
            bf16x8 b2 = *(const bf16x8*)(&Bs[b][ob * 512 + (32 + lrow) * 8]);
            bf16x8 b3 = *(const bf16x8*)(&Bs[b][ob * 512 + (48 + lrow) * 8]);
            acc[0][0] = MFMA_BF16(a0, b0, acc[0][0]);
            acc[0][1] = MFMA_BF16(a0, b1, acc[0][1]);
            acc[0][2] = MFMA_BF16(a0, b2, acc[0][2]);
            acc[0][3] = MFMA_BF16(a0, b3, acc[0][3]);
            acc[1][0] = MFMA_BF16(a1, b0, acc[1][0]);
            acc[1][1] = MFMA_BF16(a1, b1, acc[1][1]);
            acc[1][2] = MFMA_BF16(a1, b2, acc[1][2]);
            acc[1][3] = MFMA_BF16(a1, b3, acc[1][3]);
        }
        PIPE_BAR_POST();
    }

#pragma unroll
    for (int mi = 0; mi < 2; ++mi)
#pragma unroll
        for (int nj = 0; nj < 4; ++nj)
#pragma unroll
            for (int r = 0; r < 4; ++r) {
                int row = m0 + 32 * w + 16 * mi + 4 * lq + r;
                int col = bn * 64 + 16 * nj + lrow;
                float v = acc[mi][nj][r];
                if (bn < 16)       pre_r[row * 1024 + col] = f2bf(v + b_read[col]);
                else if (bn < 32)  pre_w[row * 1024 + (col - 1024)] = f2bf(v + b_write[col - 1024]);
                else if (bn == 32) erase[row * 64 + (col - 2048)] = sigf(v + b_erase[col - 2048]);
                else if (bn == 33) add[row * 64 + (col - 2112)] = fast_tanh(v + b_add[col - 2112]);
                else               out[row * 64 + (col - 2176)] = v + b_out[col - 2176];
            }
}

// ---------------------------------------------------------------------------
// k_tail: 256 blocks = 128 m-blocks (16 rows) x 2 K-halves.
// dual softmax (redundant across halves) -> LDS; read_new GEMM (K=512);
// partial rn through Wo_rn^T; atomicAdd into out (seeded with out_h + b_out).
// ---------------------------------------------------------------------------
__global__ __launch_bounds__(256) void k_tail(const u16* __restrict__ pre_r, const u16* __restrict__ pre_w,
                                              const u16* __restrict__ memt, const u16* __restrict__ Wo_rn,
                                              const float* __restrict__ erase, const float* __restrict__ add,
                                              float* __restrict__ out)
{
    __shared__ u16 rwS[16 * SLDW];
    __shared__ u16 rw2S[16 * SLDW];
    __shared__ u16 BsP[64 * LDW];
    __shared__ u16 Ps[16 * 72];
    __shared__ float s_sh[16];
    const int tid = threadIdx.x, w = tid >> 6, lane = tid & 63;
    const int lrow = lane & 15, lq = lane >> 4;
    const int mb = blockIdx.x >> 1, kh = blockIdx.x & 1;
    const int m0 = mb * 16, k0 = kh * 512;

    {
        const int row = tid >> 4, c16 = tid & 15;
        const int row_g = m0 + row;
        const u16* prp = pre_r + row_g * 1024;
        const u16* pwp = pre_w + row_g * 1024;
        float vr[64], vw[64];
#pragma unroll
        for (int q = 0; q < 8; ++q) {
            bfu4_to_f8(*(const uint4*)(prp + q * 128 + c16 * 8), vr + 8 * q);
            bfu4_to_f8(*(const uint4*)(pwp + q * 128 + c16 * 8), vw + 8 * q);
        }
        float mr = vr[0], mw = vw[0];
#pragma unroll
        for (int i = 1; i < 64; ++i) { mr = fmaxf(mr, vr[i]); mw = fmaxf(mw, vw[i]); }
#pragma unroll
        for (int o = 1; o < 16; o <<= 1) {
            mr = fmaxf(mr, __shfl_xor(mr, o, 64));
            mw = fmaxf(mw, __shfl_xor(mw, o, 64));
        }
        float sr = 0.f, sw = 0.f;
#pragma unroll
        for (int i = 0; i < 64; ++i) {
            vr[i] = __expf(vr[i] - mr); sr += vr[i];
            vw[i] = __expf(vw[i] - mw); sw += vw[i];
        }
#pragma unroll
        for (int o = 1; o < 16; o <<= 1) {
            sr += __shfl_xor(sr, o, 64);
            sw += __shfl_xor(sw, o, 64);
        }
        const float isr = 1.f / sr, isw = 1.f / sw;
        float ss = 0.f;
#pragma unroll
        for (int q = 0; q < 8; ++q) {
            float a8[8], r8[8];
#pragma unroll
            for (int i = 0; i < 8; ++i) {
                float a = vr[8 * q + i] * isr;
                float r2 = a * (vw[8 * q + i] * isw);
                a8[i] = a; r8[i] = r2;
                ss += r2;
            }
            if ((q >> 2) == kh) {
                int cb = (q - 4 * kh) * 128 + c16 * 8;
                *(uint4*)(&rwS[row * SLDW + cb])  = pack8(a8);
                *(uint4*)(&rw2S[row * SLDW + cb]) = pack8(r8);
            }
        }
#pragma unroll
        for (int o = 1; o < 16; o <<= 1) ss += __shfl_xor(ss, o, 64);
        if (c16 == 0) s_sh[row] = ss;
    }
    __syncthreads();

    f32x4 acc1 = {}, acc2 = {};
    for (int kt = 0; kt < 4; ++kt) {
#pragma unroll
        for (int i = 0; i < 4; ++i) {
            int idx = i * 256 + tid, r = idx >> 4, c = (idx & 15) * 8;
            *(uint4*)(&BsP[r * LDW + c]) = *(const uint4*)(memt + r * 1024 + k0 + kt * 128 + c);
        }
        __syncthreads();
#pragma unroll
        for (int kk = 0; kk < 128; kk += 32) {
            bf16x8 a1 = *(const bf16x8*)(&rwS[lrow * SLDW + kt * 128 + kk + 8 * lq]);
            bf16x8 a2 = *(const bf16x8*)(&rw2S[lrow * SLDW + kt * 128 + kk + 8 * lq]);
            bf16x8 b  = *(const bf16x8*)(&BsP[(16 * w + lrow) * LDW + kk + 8 * lq]);
            acc1 = MFMA_BF16(a1, b, acc1);
            acc2 = MFMA_BF16(a2, b, acc2);
        }
        __syncthreads();
    }

#pragma unroll
    for (int r = 0; r < 4; ++r) {
        int row_l = 4 * lq + r, col = 16 * w + lrow;
        int row_g = m0 + row_l;
        float p = acc1[r] - erase[row_g * 64 + col] * acc2[r];
        if (kh == 0) p += add[row_g * 64 + col] * s_sh[row_l];
        Ps[row_l * 72 + col] = f2bf(p);
    }
#pragma unroll
    for (int i = 0; i < 2; ++i) {
        int idx = i * 256 + tid, r = idx >> 3, c = (idx & 7) * 8;
        *(uint4*)(&BsP[r * LDW + c]) = *(const uint4*)(Wo_rn + r * 64 + c);
    }
    __syncthreads();

    f32x4 acc3 = {};
#pragma unroll
    for (int kk = 0; kk < 64; kk += 32) {
        bf16x8 a = *(const bf16x8*)(&Ps[lrow * 72 + kk + 8 * lq]);
        bf16x8 b = *(const bf16x8*)(&BsP[(16 * w + lrow) * LDW + kk + 8 * lq]);
        acc3 = MFMA_BF16(a, b, acc3);
    }
#pragma unroll
    for (int r = 0; r < 4; ++r) {
        int row_g = m0 + 4 * lq + r, col = 16 * w + lrow;
        atomicAdd(&out[row_g * 64 + col], acc3[r]);
    }
}

extern "C" void kernel_launch(void* const* d_in, const int* in_sizes, int n_in,
                              void* d_out, int out_size, void* d_ws, size_t ws_size,
                              hipStream_t stream)
{
    const float* x        = (const float*)d_in[0];
    const float* h_prev   = (const float*)d_in[1];
    const float* c_prev   = (const float*)d_in[2];
    const float* rwp      = (const float*)d_in[3];
    const float* memory   = (const float*)d_in[4];
    const float* W_ih     = (const float*)d_in[5];
    const float* b_ih     = (const float*)d_in[6];
    const float* W_hh     = (const float*)d_in[7];
    const float* b_hh     = (const float*)d_in[8];
    const float* W_read   = (const float*)d_in[9];
    const float* b_read   = (const float*)d_in[10];
    const float* W_write  = (const float*)d_in[11];
    const float* b_write  = (const float*)d_in[12];
    const float* W_erase  = (const float*)d_in[13];
    const float* b_erase  = (const float*)d_in[14];
    const float* W_add    = (const float*)d_in[15];
    const float* b_add    = (const float*)d_in[16];
    const float* W_out    = (const float*)d_in[17];
    const float* b_out    = (const float*)d_in[18];
    float* out = (float*)d_out;

    char* wsp = (char*)d_ws;
    u16*   x_t     = (u16*)(wsp + 0);           // 16 x 8oct x 128row x 8  (256 KB)
    u16*   ht_t    = (u16*)(wsp + 262144);      // 16 x 64oct x 128row x 8 (2 MB)
    u16*   wcat_t  = (u16*)(wsp + 2359296);     // 32bn x 5kt x 16oct x 64row x 8
    u16*   memt    = (u16*)(wsp + 4980736);     // 64 x 1024 bf16 memory^T
    u16*   Wcat2_t = (u16*)(wsp + 5111808);     // 35bn x 4kt x 16oct x 64row x 8
    u16*   Wo_rn   = (u16*)(wsp + 7405568);     // 64x64 bf16
    u16*   rpt     = (u16*)(wsp + 7413760);     // 16mt x 8oct x 128row x 8 bf16 (256 KB)
    u16*   hrn_t   = (u16*)(wsp + 9510912);     // 16 x 64oct x 128row x 8 (2 MB)
    u16*   pre_r   = (u16*)(wsp + 11608064);    // 2048x1024 bf16
    u16*   pre_w   = (u16*)(wsp + 15802368);    // 2048x1024 bf16
    float* erase   = (float*)(wsp + 19996672);  // 2048x64 fp32
    float* add     = (float*)(wsp + 20520960);  // 2048x64 fp32

    k_pre<<<640, 256, 0, stream>>>(x, h_prev, rwp, memory, W_ih, W_hh, W_read, W_write,
                                   W_erase, W_add, W_out,
                                   x_t, ht_t, wcat_t, Wcat2_t, Wo_rn, memt, rpt);
    k_gates<<<dim3(16, 32), 256, 0, stream>>>(rpt, x_t, ht_t, wcat_t, b_ih, b_hh, c_prev, hrn_t);
    k_heads<<<dim3(16, 35), 256, 0, stream>>>(hrn_t, Wcat2_t, b_read, b_write, b_erase, b_add, b_out,
                                              pre_r, pre_w, erase, add, out);
    k_tail<<<256, 256, 0, stream>>>(pre_r, pre_w, memt, Wo_rn, erase, add, out);
}

// Round 9
// 151.426 us; speedup vs baseline: 2.7608x; 1.0176x over previous
//
#include <hip/hip_runtime.h>
#include <hip/hip_bf16.h>

// NTM cell on MI355X. B=2048, IN=64, CTRL=512, M=1024, V=64, OUT=64.
// 4 dispatches. This round: k_gates pipeline deepened to 3 LDS buffers /
// prefetch-distance-2 with counted s_waitcnt vmcnt(12) (T4 formula: 6 DMAs
// per tile x 2 tiles in flight). Phases were latency-bound (one-tile-ahead
// prefetch can't cover ~600-900cyc DMA latency at 2 blocks/CU lockstep).
// LDS 48->72KB: grid 512 = exactly 2/CU, 2x72=144<=160KB -> occupancy same.
// k_heads stays 2-deep (72KB would break its 560-block co-residency).

typedef unsigned short u16;
typedef __attribute__((ext_vector_type(8))) short bf16x8;
typedef __attribute__((ext_vector_type(4))) float f32x4;

#define MFMA_BF16(a, b, c) __builtin_amdgcn_mfma_f32_16x16x32_bf16((a), (b), (c), 0, 0, 0)
#define LDW 136
#define SLDW 520

__device__ __forceinline__ void dma16(const void* g, void* l) {
    __builtin_amdgcn_global_load_lds(
        (const __attribute__((address_space(1))) unsigned int*)g,
        (__attribute__((address_space(3))) unsigned int*)l, 16, 0, 0);
}

__device__ __forceinline__ u16 f2bf(float f) {
    union { float f; unsigned int u; } a; a.f = f;
    return (u16)((a.u + 0x7FFFu + ((a.u >> 16) & 1u)) >> 16);
}

__device__ __forceinline__ void pack_store4(float a0, float a1, float a2, float a3, u16* d) {
    union { __hip_bfloat162 h[2]; uint2 u; } cv;
    cv.h[0] = __float22bfloat162_rn(make_float2(a0, a1));
    cv.h[1] = __float22bfloat162_rn(make_float2(a2, a3));
    *(uint2*)d = cv.u;
}

__device__ __forceinline__ void cvt4(const float* __restrict__ s, u16* __restrict__ d) {
    float4 v = *(const float4*)s;
    pack_store4(v.x, v.y, v.z, v.w, d);
}

__device__ __forceinline__ uint4 cvt8u(const float* __restrict__ s) {
    float4 v0 = *(const float4*)(s);
    float4 v1 = *(const float4*)(s + 4);
    union { __hip_bfloat162 h[4]; uint4 u; } r;
    r.h[0] = __float22bfloat162_rn(make_float2(v0.x, v0.y));
    r.h[1] = __float22bfloat162_rn(make_float2(v0.z, v0.w));
    r.h[2] = __float22bfloat162_rn(make_float2(v1.x, v1.y));
    r.h[3] = __float22bfloat162_rn(make_float2(v1.z, v1.w));
    return r.u;
}

__device__ __forceinline__ void bfu4_to_f8(uint4 u, float* f) {
    f[0] = __uint_as_float(u.x << 16); f[1] = __uint_as_float(u.x & 0xffff0000u);
    f[2] = __uint_as_float(u.y << 16); f[3] = __uint_as_float(u.y & 0xffff0000u);
    f[4] = __uint_as_float(u.z << 16); f[5] = __uint_as_float(u.z & 0xffff0000u);
    f[6] = __uint_as_float(u.w << 16); f[7] = __uint_as_float(u.w & 0xffff0000u);
}

__device__ __forceinline__ uint4 pack8(const float* v) {
    union { __hip_bfloat162 h[4]; uint4 u; } r;
#pragma unroll
    for (int j = 0; j < 4; ++j) r.h[j] = __float22bfloat162_rn(make_float2(v[2 * j], v[2 * j + 1]));
    return r.u;
}

__device__ __forceinline__ float sigf(float x) { return 1.f / (1.f + __expf(-x)); }
__device__ __forceinline__ float fast_tanh(float x) { return 1.f - 2.f / (__expf(2.f * x) + 1.f); }

#define PIPE_BAR_PRE_12() do {                                                \
    asm volatile("s_waitcnt vmcnt(12) lgkmcnt(0)" ::: "memory");              \
    __builtin_amdgcn_s_barrier();                                             \
    __builtin_amdgcn_sched_barrier(0);                                        \
} while (0)
#define PIPE_BAR_PRE_CNT()  do {                                              \
    asm volatile("s_waitcnt vmcnt(6) lgkmcnt(0)" ::: "memory");               \
    __builtin_amdgcn_s_barrier();                                             \
    __builtin_amdgcn_sched_barrier(0);                                        \
} while (0)
#define PIPE_BAR_PRE_ZERO() do {                                              \
    asm volatile("s_waitcnt vmcnt(0) lgkmcnt(0)" ::: "memory");               \
    __builtin_amdgcn_s_barrier();                                             \
    __builtin_amdgcn_sched_barrier(0);                                        \
} while (0)
#define PIPE_BAR_POST() do {                                                  \
    __builtin_amdgcn_sched_barrier(0);                                        \
    asm volatile("s_waitcnt lgkmcnt(0)" ::: "memory");                        \
    __builtin_amdgcn_s_barrier();                                             \
    __builtin_amdgcn_sched_barrier(0);                                        \
} while (0)

// One fp32->bf16 tile-major convert unit, t in [0, 926720).
__device__ __forceinline__ void convert_unit(int t,
    const float* __restrict__ x, const float* __restrict__ h_prev,
    const float* __restrict__ W_ih, const float* __restrict__ W_hh,
    const float* __restrict__ W_read, const float* __restrict__ W_write,
    const float* __restrict__ W_erase, const float* __restrict__ W_add,
    const float* __restrict__ W_out, const float* __restrict__ memory,
    u16* x_t, u16* ht_t, u16* wcat_t, u16* Wcat2_t, u16* Wo_rn, u16* memt)
{
    if (t < 32768) {  // x -> x_t[mt][oct8][row128]
        int r = t >> 4, c = (t & 15) * 4;
        cvt4(x + r * 64 + c, x_t + ((r >> 7) * 8 + (c >> 3)) * 1024 + (r & 127) * 8 + (c & 7));
        return;
    }
    t -= 32768;
    if (t < 262144) {  // h_prev -> ht_t[mt][oct64][row128]
        int r = t >> 7, c = (t & 127) * 4;
        cvt4(h_prev + r * 512 + c, ht_t + ((r >> 7) * 64 + (c >> 3)) * 1024 + (r & 127) * 8 + (c & 7));
        return;
    }
    t -= 262144;
    if (t < 65536) {  // W_ih (gate-interleave rows, col swap rp|x) -> wcat_t[bn][kt0][oct][row64]
        int r = t >> 5, c = (t & 31) * 4;
        int g = r >> 9, j = r & 511;
        int bn = j >> 4, row64 = (g << 4) + (j & 15);
        int cd = (c < 64) ? c + 64 : c - 64;
        cvt4(W_ih + r * 128 + c, wcat_t + (bn * 5) * 8192 + (cd >> 3) * 512 + row64 * 8 + (cd & 7));
        return;
    }
    t -= 65536;
    if (t < 262144) {  // W_hh -> wcat_t[bn][kt1..4][oct][row64]
        int r = t >> 7, c = (t & 127) * 4;
        int g = r >> 9, j = r & 511;
        int bn = j >> 4, row64 = (g << 4) + (j & 15);
        int cd = 128 + c;
        cvt4(W_hh + r * 512 + c, wcat_t + (bn * 5 + (cd >> 7)) * 8192 + ((cd >> 3) & 15) * 512 + row64 * 8 + (cd & 7));
        return;
    }
    t -= 262144;
    if (t < 131072) {  // W_read -> Wcat2_t bn 0..15
        int r = t >> 7, c = (t & 127) * 4;
        cvt4(W_read + t * 4, Wcat2_t + ((r >> 6) * 4 + (c >> 7)) * 8192 + ((c >> 3) & 15) * 512 + (r & 63) * 8 + (c & 7));
        return;
    }
    t -= 131072;
    if (t < 131072) {  // W_write -> bn 16..31
        int r = t >> 7, c = (t & 127) * 4;
        cvt4(W_write + t * 4, Wcat2_t + ((16 + (r >> 6)) * 4 + (c >> 7)) * 8192 + ((c >> 3) & 15) * 512 + (r & 63) * 8 + (c & 7));
        return;
    }
    t -= 131072;
    if (t < 8192) {  // W_erase -> bn 32
        int r = t >> 7, c = (t & 127) * 4;
        cvt4(W_erase + t * 4, Wcat2_t + (32 * 4 + (c >> 7)) * 8192 + ((c >> 3) & 15) * 512 + r * 8 + (c & 7));
        return;
    }
    t -= 8192;
    if (t < 8192) {  // W_add -> bn 33
        int r = t >> 7, c = (t & 127) * 4;
        cvt4(W_add + t * 4, Wcat2_t + (33 * 4 + (c >> 7)) * 8192 + ((c >> 3) & 15) * 512 + r * 8 + (c & 7));
        return;
    }
    t -= 8192;
    if (t < 9216) {  // W_out: h-part -> bn 34; rn-part -> Wo_rn
        int r = t / 144, c = (t % 144) * 4;
        if (c < 512)
            cvt4(W_out + r * 576 + c, Wcat2_t + (34 * 4 + (c >> 7)) * 8192 + ((c >> 3) & 15) * 512 + r * 8 + (c & 7));
        else
            cvt4(W_out + r * 576 + c, Wo_rn + r * 64 + (c - 512));
        return;
    }
    t -= 9216;
    {  // memory^T -> memt (64 x 1024)
        int v = t >> 8, m = (t & 255) * 4;
        pack_store4(memory[m * 64 + v], memory[(m + 1) * 64 + v],
                    memory[(m + 2) * 64 + v], memory[(m + 3) * 64 + v], memt + v * 1024 + m);
    }
}

// ---------------------------------------------------------------------------
// k_pre: blocks 0..127 = read_prev GEMM, FULL-K (16 rows x 64 cols x K=1024
// per block, 8 staging rounds), writing bf16 directly in the gates A-tile
// fragment layout rpt[mt][oct8][row128][8]. Blocks 128..639 = grid-stride
// fp32->bf16 converts writing TILE-MAJOR layouts.
// ---------------------------------------------------------------------------
__global__ __launch_bounds__(256) void k_pre(
    const float* __restrict__ x, const float* __restrict__ h_prev, const float* __restrict__ rwp,
    const float* __restrict__ memory, const float* __restrict__ W_ih, const float* __restrict__ W_hh,
    const float* __restrict__ W_read, const float* __restrict__ W_write, const float* __restrict__ W_erase,
    const float* __restrict__ W_add, const float* __restrict__ W_out,
    u16* x_t, u16* ht_t, u16* wcat_t, u16* Wcat2_t, u16* Wo_rn, u16* memt, u16* rpt)
{
    __shared__ u16 As[64 * LDW];
    __shared__ u16 Bs[64 * LDW];
    const int tid = threadIdx.x;

    if (blockIdx.x < 128) {
        const int mb = blockIdx.x;
        const int w = tid >> 6, lane = tid & 63;
        const int lrow = lane & 15, lq = lane >> 4;
        const int m0 = mb * 16;
        const int m_loc = tid >> 1, v0 = (tid & 1) * 32;
        f32x4 acc = {};
        for (int kt = 0; kt < 8; ++kt) {
            {   // As: 16 rows x 128 K (one cvt8u per thread)
                int r = tid >> 4, c = (tid & 15) * 8;
                *(uint4*)(&As[r * LDW + c]) = cvt8u(rwp + (m0 + r) * 1024 + kt * 128 + c);
            }
#pragma unroll
            for (int j = 0; j < 8; ++j) {  // Bs: v-major 64 x 128
                float4 q = *(const float4*)(memory + (kt * 128 + m_loc) * 64 + v0 + 4 * j);
                Bs[(v0 + 4 * j + 0) * LDW + m_loc] = f2bf(q.x);
                Bs[(v0 + 4 * j + 1) * LDW + m_loc] = f2bf(q.y);
                Bs[(v0 + 4 * j + 2) * LDW + m_loc] = f2bf(q.z);
                Bs[(v0 + 4 * j + 3) * LDW + m_loc] = f2bf(q.w);
            }
            __syncthreads();
#pragma unroll
            for (int kk = 0; kk < 128; kk += 32) {
                bf16x8 a = *(const bf16x8*)(&As[lrow * LDW + kk + 8 * lq]);
                bf16x8 b = *(const bf16x8*)(&Bs[(16 * w + lrow) * LDW + kk + 8 * lq]);
                acc = MFMA_BF16(a, b, acc);
            }
            __syncthreads();
        }
        // write bf16 in gates-A fragment layout: elem [row][v] ->
        // rpt[(row>>7)*8192 + (v>>3)*1024 + (row&127)*8 + (v&7)]
#pragma unroll
        for (int r = 0; r < 4; ++r) {
            int row = m0 + 4 * lq + r, v = 16 * w + lrow;
            rpt[(row >> 7) * 8192 + (v >> 3) * 1024 + (row & 127) * 8 + (v & 7)] = f2bf(acc[r]);
        }
        return;
    }

    for (int t = (blockIdx.x - 128) * 256 + tid; t < 926720; t += 512 * 256)
        convert_unit(t, x, h_prev, W_ih, W_hh, W_read, W_write, W_erase, W_add,
                     W_out, memory, x_t, ht_t, wcat_t, Wcat2_t, Wo_rn, memt);
}

// ---------------------------------------------------------------------------
// gates GEMM + fused LSTM. A-K = [rp(64) | x(64) | h(512)] = 10 BK=64 tiles.
// 3-deep LDS pipeline, prefetch distance 2, counted vmcnt(12).
// ---------------------------------------------------------------------------
__global__ __launch_bounds__(256) void k_gates(const u16* __restrict__ rpt, const u16* __restrict__ x_t,
                                               const u16* __restrict__ ht_t, const u16* __restrict__ wcat_t,
                                               const float* __restrict__ b_ih, const float* __restrict__ b_hh,
                                               const float* __restrict__ c_prev, u16* __restrict__ hrn_t)
{
    __shared__ u16 As[3][8192];   // 3 x (8 oct x 128 row x 8)  = 48 KB
    __shared__ u16 Bs[3][4096];   // 3 x (8 oct x  64 row x 8)  = 24 KB
    const int tid = threadIdx.x, w = tid >> 6, lane = tid & 63;
    const int lrow = lane & 15, lq = lane >> 4;
    const int mt = blockIdx.x, bn = blockIdx.y;
    const int m0 = mt * 128;
    f32x4 acc[2][4] = {};

#define STAGE_A(tn, bb) do {                                                   \
    const u16* asrc_ = ((tn) == 0) ? (rpt + mt * 8192)                         \
                     : ((tn) == 1) ? (x_t + mt * 8192)                         \
                     : (ht_t + mt * 65536 + ((tn) - 2) * 8192);                \
    _Pragma("unroll")                                                          \
    for (int i_ = 0; i_ < 4; ++i_)                                             \
        dma16(asrc_ + (i_ * 256 + tid) * 8, &As[(bb)][(i_ * 256 + w * 64) * 8]);\
} while (0)
#define STAGE_B(tn, bb) do {                                                   \
    _Pragma("unroll")                                                          \
    for (int i_ = 0; i_ < 2; ++i_)                                             \
        dma16(wcat_t + (bn * 5 + ((tn) >> 1)) * 8192 + ((tn) & 1) * 4096       \
                  + (i_ * 256 + tid) * 8, &Bs[(bb)][(i_ * 256 + w * 64) * 8]); \
} while (0)

    // prologue: stage tiles 0 and 1 (12 DMAs in flight)
    STAGE_A(0, 0); STAGE_B(0, 0);
    STAGE_A(1, 1); STAGE_B(1, 1);

#pragma unroll
    for (int t = 0; t < 10; ++t) {
        if (t < 8) {
            const int tn = t + 2, bb = tn % 3;
            STAGE_A(tn, bb); STAGE_B(tn, bb);   // 18 in flight
            PIPE_BAR_PRE_12();                  // retire tile t (2 newest stay)
        } else if (t == 8) {
            PIPE_BAR_PRE_CNT();                 // vmcnt(6): retire tile 8
        } else {
            PIPE_BAR_PRE_ZERO();                // tile 9
        }
        const int b = t % 3;
#pragma unroll
        for (int kk = 0; kk < 64; kk += 32) {
            const int ob = (kk >> 3) + lq;
            bf16x8 a0 = *(const bf16x8*)(&As[b][ob * 1024 + (32 * w + lrow) * 8]);
            bf16x8 a1 = *(const bf16x8*)(&As[b][ob * 1024 + (32 * w + 16 + lrow) * 8]);
            bf16x8 b0 = *(const bf16x8*)(&Bs[b][ob * 512 + (lrow) * 8]);
            bf16x8 b1 = *(const bf16x8*)(&Bs[b][ob * 512 + (16 + lrow) * 8]);
            bf16x8 b2 = *(const bf16x8*)(&Bs[b][ob * 512 + (32 + lrow) * 8]);
            bf16x8 b3 = *(const bf16x8*)(&Bs[b][ob * 512 + (48 + lrow) * 8]);
            acc[0][0] = MFMA_BF16(a0, b0, acc[0][0]);
            acc[0][1] = MFMA_BF16(a0, b1, acc[0][1]);
            acc[0][2] = MFMA_BF16(a0, b2, acc[0][2]);
            acc[0][3] = MFMA_BF16(a0, b3, acc[0][3]);
            acc[1][0] = MFMA_BF16(a1, b0, acc[1][0]);
            acc[1][1] = MFMA_BF16(a1, b1, acc[1][1]);
            acc[1][2] = MFMA_BF16(a1, b2, acc[1][2]);
            acc[1][3] = MFMA_BF16(a1, b3, acc[1][3]);
        }
        PIPE_BAR_POST();
    }
#undef STAGE_A
#undef STAGE_B

    const int j = bn * 16 + lrow;
    const float bI = b_ih[j] + b_hh[j];
    const float bF = b_ih[512 + j] + b_hh[512 + j];
    const float bG = b_ih[1024 + j] + b_hh[1024 + j];
    const float bO = b_ih[1536 + j] + b_hh[1536 + j];
#pragma unroll
    for (int mi = 0; mi < 2; ++mi)
#pragma unroll
        for (int r = 0; r < 4; ++r) {
            int row = m0 + 32 * w + 16 * mi + 4 * lq + r;
            float ig = sigf(acc[mi][0][r] + bI);
            float fg = sigf(acc[mi][1][r] + bF);
            float gg = fast_tanh(acc[mi][2][r] + bG);
            float og = sigf(acc[mi][3][r] + bO);
            float c = fg * c_prev[row * 512 + j] + ig * gg;
            // h -> tile-major hrn_t[mt][oct][row]
            hrn_t[(row >> 7) * 65536 + (j >> 3) * 1024 + (row & 127) * 8 + (j & 7)] =
                f2bf(og * fast_tanh(c));
        }
}

// ---------------------------------------------------------------------------
// heads: [pre_read | pre_write | erase | add | out_h] = h @ Wcat2^T + biases.
// grid (16, 35). 2-phase double-buffered pipeline, 8 BK=64 tiles (48 KB LDS
// keeps all 560 blocks co-resident at 3/CU -- do NOT deepen this one).
// ---------------------------------------------------------------------------
__global__ __launch_bounds__(256) void k_heads(const u16* __restrict__ hrn_t, const u16* __restrict__ Wcat2_t,
                                               const float* __restrict__ b_read, const float* __restrict__ b_write,
                                               const float* __restrict__ b_erase, const float* __restrict__ b_add,
                                               const float* __restrict__ b_out,
                                               u16* __restrict__ pre_r, u16* __restrict__ pre_w,
                                               float* __restrict__ erase, float* __restrict__ add,
                                               float* __restrict__ out)
{
    __shared__ u16 As[2][8192];
    __shared__ u16 Bs[2][4096];
    const int tid = threadIdx.x, w = tid >> 6, lane = tid & 63;
    const int lrow = lane & 15, lq = lane >> 4;
    const int mt = blockIdx.x, bn = blockIdx.y;
    const int m0 = mt * 128;
    f32x4 acc[2][4] = {};

    // prologue: stage tile 0
#pragma unroll
    for (int i = 0; i < 4; ++i)
        dma16(hrn_t + mt * 65536 + (i * 256 + tid) * 8, &As[0][(i * 256 + w * 64) * 8]);
#pragma unroll
    for (int i = 0; i < 2; ++i)
        dma16(Wcat2_t + (bn * 4) * 8192 + (i * 256 + tid) * 8, &Bs[0][(i * 256 + w * 64) * 8]);

#pragma unroll
    for (int t = 0; t < 8; ++t) {
        if (t < 7) {
            const int tn = t + 1, b = tn & 1;
#pragma unroll
            for (int i = 0; i < 4; ++i)
                dma16(hrn_t + mt * 65536 + tn * 8192 + (i * 256 + tid) * 8,
                      &As[b][(i * 256 + w * 64) * 8]);
#pragma unroll
            for (int i = 0; i < 2; ++i)
                dma16(Wcat2_t + (bn * 4 + (tn >> 1)) * 8192 + (tn & 1) * 4096 + (i * 256 + tid) * 8,
                      &Bs[b][(i * 256 + w * 64) * 8]);
            PIPE_BAR_PRE_CNT();
        } else {
            PIPE_BAR_PRE_ZERO();
        }
        const int b = t & 1;
#pragma unroll
        for (int kk = 0; kk < 64; kk += 32) {
            const int ob = (kk >> 3) + lq;
            bf16x8 a0 = *(const bf16x8*)(&As[b][ob * 1024 + (32 * w + lrow) * 8]);
            bf16x8 a1 = *(const bf16x8*)(&As[b][ob * 1024 + (32 * w + 16 + lrow) * 8]);
            bf16x8 b0 = *(const bf16x8*)(&Bs[b][ob * 512 + (lrow) * 8]);
            bf16x8 b1 = *(const bf16x8*)(&Bs[b][ob * 512 + (16 + lrow) * 8]);
            bf16x8 b2 = *(const bf16x8*)(&Bs[b][ob * 512 + (32 + lrow) * 8]);
            bf16x8 b3 = *(const bf16x8*)(&Bs[b][ob * 512 + (48 + lrow) * 8]);
            acc[0][0] = MFMA_BF16(a0, b0, acc[0][0]);
            acc[0][1] = MFMA_BF16(a0, b1, acc[0][1]);
            acc[0][2] = MFMA_BF16(a0, b2, acc[0][2]);
            acc[0][3] = MFMA_BF16(a0, b3, acc[0][3]);
            acc[1][0] = MFMA_BF16(a1, b0, acc[1][0]);
            acc[1][1] = MFMA_BF16(a1, b1, acc[1][1]);
            acc[1][2] = MFMA_BF16(a1, b2, acc[1][2]);
            acc[1][3] = MFMA_BF16(a1, b3, acc[1][3]);
        }
        PIPE_BAR_POST();
    }

#pragma unroll
    for (int mi = 0; mi < 2; ++mi)
#pragma unroll
        for (int nj = 0; nj < 4; ++nj)
#pragma unroll
            for (int r = 0; r < 4; ++r) {
                int row = m0 + 32 * w + 16 * mi + 4 * lq + r;
                int col = bn * 64 + 16 * nj + lrow;
                float v = acc[mi][nj][r];
                if (bn < 16)       pre_r[row * 1024 + col] = f2bf(v + b_read[col]);
                else if (bn < 32)  pre_w[row * 1024 + (col - 1024)] = f2bf(v + b_write[col - 1024]);
                else if (bn == 32) erase[row * 64 + (col - 2048)] = sigf(v + b_erase[col - 2048]);
                else if (bn == 33) add[row * 64 + (col - 2112)] = fast_tanh(v + b_add[col - 2112]);
                else               out[row * 64 + (col - 2176)] = v + b_out[col - 2176];
            }
}

// ---------------------------------------------------------------------------
// k_tail: 256 blocks = 128 m-blocks (16 rows) x 2 K-halves.
// dual softmax (redundant across halves) -> LDS; read_new GEMM (K=512);
// partial rn through Wo_rn^T; atomicAdd into out (seeded with out_h + b_out).
// ---------------------------------------------------------------------------
__global__ __launch_bounds__(256) void k_tail(const u16* __restrict__ pre_r, const u16* __restrict__ pre_w,
                                              const u16* __restrict__ memt, const u16* __restrict__ Wo_rn,
                                              const float* __restrict__ erase, const float* __restrict__ add,
                                              float* __restrict__ out)
{
    __shared__ u16 rwS[16 * SLDW];
    __shared__ u16 rw2S[16 * SLDW];
    __shared__ u16 BsP[64 * LDW];
    __shared__ u16 Ps[16 * 72];
    __shared__ float s_sh[16];
    const int tid = threadIdx.x, w = tid >> 6, lane = tid & 63;
    const int lrow = lane & 15, lq = lane >> 4;
    const int mb = blockIdx.x >> 1, kh = blockIdx.x & 1;
    const int m0 = mb * 16, k0 = kh * 512;

    {
        const int row = tid >> 4, c16 = tid & 15;
        const int row_g = m0 + row;
        const u16* prp = pre_r + row_g * 1024;
        const u16* pwp = pre_w + row_g * 1024;
        float vr[64], vw[64];
#pragma unroll
        for (int q = 0; q < 8; ++q) {
            bfu4_to_f8(*(const uint4*)(prp + q * 128 + c16 * 8), vr + 8 * q);
            bfu4_to_f8(*(const uint4*)(pwp + q * 128 + c16 * 8), vw + 8 * q);
        }
        float mr = vr[0], mw = vw[0];
#pragma unroll
        for (int i = 1; i < 64; ++i) { mr = fmaxf(mr, vr[i]); mw = fmaxf(mw, vw[i]); }
#pragma unroll
        for (int o = 1; o < 16; o <<= 1) {
            mr = fmaxf(mr, __shfl_xor(mr, o, 64));
            mw = fmaxf(mw, __shfl_xor(mw, o, 64));
        }
        float sr = 0.f, sw = 0.f;
#pragma unroll
        for (int i = 0; i < 64; ++i) {
            vr[i] = __expf(vr[i] - mr); sr += vr[i];
            vw[i] = __expf(vw[i] - mw); sw += vw[i];
        }
#pragma unroll
        for (int o = 1; o < 16; o <<= 1) {
            sr += __shfl_xor(sr, o, 64);
            sw += __shfl_xor(sw, o, 64);
        }
        const float isr = 1.f / sr, isw = 1.f / sw;
        float ss = 0.f;
#pragma unroll
        for (int q = 0; q < 8; ++q) {
            float a8[8], r8[8];
#pragma unroll
            for (int i = 0; i < 8; ++i) {
                float a = vr[8 * q + i] * isr;
                float r2 = a * (vw[8 * q + i] * isw);
                a8[i] = a; r8[i] = r2;
                ss += r2;
            }
            if ((q >> 2) == kh) {
                int cb = (q - 4 * kh) * 128 + c16 * 8;
                *(uint4*)(&rwS[row * SLDW + cb])  = pack8(a8);
                *(uint4*)(&rw2S[row * SLDW + cb]) = pack8(r8);
            }
        }
#pragma unroll
        for (int o = 1; o < 16; o <<= 1) ss += __shfl_xor(ss, o, 64);
        if (c16 == 0) s_sh[row] = ss;
    }
    __syncthreads();

    f32x4 acc1 = {}, acc2 = {};
    for (int kt = 0; kt < 4; ++kt) {
#pragma unroll
        for (int i = 0; i < 4; ++i) {
            int idx = i * 256 + tid, r = idx >> 4, c = (idx & 15) * 8;
            *(uint4*)(&BsP[r * LDW + c]) = *(const uint4*)(memt + r * 1024 + k0 + kt * 128 + c);
        }
        __syncthreads();
#pragma unroll
        for (int kk = 0; kk < 128; kk += 32) {
            bf16x8 a1 = *(const bf16x8*)(&rwS[lrow * SLDW + kt * 128 + kk + 8 * lq]);
            bf16x8 a2 = *(const bf16x8*)(&rw2S[lrow * SLDW + kt * 128 + kk + 8 * lq]);
            bf16x8 b  = *(const bf16x8*)(&BsP[(16 * w + lrow) * LDW + kk + 8 * lq]);
            acc1 = MFMA_BF16(a1, b, acc1);
            acc2 = MFMA_BF16(a2, b, acc2);
        }
        __syncthreads();
    }

#pragma unroll
    for (int r = 0; r < 4; ++r) {
        int row_l = 4 * lq + r, col = 16 * w + lrow;
        int row_g = m0 + row_l;
        float p = acc1[r] - erase[row_g * 64 + col] * acc2[r];
        if (kh == 0) p += add[row_g * 64 + col] * s_sh[row_l];
        Ps[row_l * 72 + col] = f2bf(p);
    }
#pragma unroll
    for (int i = 0; i < 2; ++i) {
        int idx = i * 256 + tid, r = idx >> 3, c = (idx & 7) * 8;
        *(uint4*)(&BsP[r * LDW + c]) = *(const uint4*)(Wo_rn + r * 64 + c);
    }
    __syncthreads();

    f32x4 acc3 = {};
#pragma unroll
    for (int kk = 0; kk < 64; kk += 32) {
        bf16x8 a = *(const bf16x8*)(&Ps[lrow * 72 + kk + 8 * lq]);
        bf16x8 b = *(const bf16x8*)(&BsP[(16 * w + lrow) * LDW + kk + 8 * lq]);
        acc3 = MFMA_BF16(a, b, acc3);
    }
#pragma unroll
    for (int r = 0; r < 4; ++r) {
        int row_g = m0 + 4 * lq + r, col = 16 * w + lrow;
        atomicAdd(&out[row_g * 64 + col], acc3[r]);
    }
}

extern "C" void kernel_launch(void* const* d_in, const int* in_sizes, int n_in,
                              void* d_out, int out_size, void* d_ws, size_t ws_size,
                              hipStream_t stream)
{
    const float* x        = (const float*)d_in[0];
    const float* h_prev   = (const float*)d_in[1];
    const float* c_prev   = (const float*)d_in[2];
    const float* rwp      = (const float*)d_in[3];
    const float* memory   = (const float*)d_in[4];
    const float* W_ih     = (const float*)d_in[5];
    const float* b_ih     = (const float*)d_in[6];
    const float* W_hh     = (const float*)d_in[7];
    const float* b_hh     = (const float*)d_in[8];
    const float* W_read   = (const float*)d_in[9];
    const float* b_read   = (const float*)d_in[10];
    const float* W_write  = (const float*)d_in[11];
    const float* b_write  = (const float*)d_in[12];
    const float* W_erase  = (const float*)d_in[13];
    const float* b_erase  = (const float*)d_in[14];
    const float* W_add    = (const float*)d_in[15];
    const float* b_add    = (const float*)d_in[16];
    const float* W_out    = (const float*)d_in[17];
    const float* b_out    = (const float*)d_in[18];
    float* out = (float*)d_out;

    char* wsp = (char*)d_ws;
    u16*   x_t     = (u16*)(wsp + 0);           // 16 x 8oct x 128row x 8  (256 KB)
    u16*   ht_t    = (u16*)(wsp + 262144);      // 16 x 64oct x 128row x 8 (2 MB)
    u16*   wcat_t  = (u16*)(wsp + 2359296);     // 32bn x 5kt x 16oct x 64row x 8
    u16*   memt    = (u16*)(wsp + 4980736);     // 64 x 1024 bf16 memory^T
    u16*   Wcat2_t = (u16*)(wsp + 5111808);     // 35bn x 4kt x 16oct x 64row x 8
    u16*   Wo_rn   = (u16*)(wsp + 7405568);     // 64x64 bf16
    u16*   rpt     = (u16*)(wsp + 7413760);     // 16mt x 8oct x 128row x 8 bf16 (256 KB)
    u16*   hrn_t   = (u16*)(wsp + 9510912);     // 16 x 64oct x 128row x 8 (2 MB)
    u16*   pre_r   = (u16*)(wsp + 11608064);    // 2048x1024 bf16
    u16*   pre_w   = (u16*)(wsp + 15802368);    // 2048x1024 bf16
    float* erase   = (float*)(wsp + 19996672);  // 2048x64 fp32
    float* add     = (float*)(wsp + 20520960);  // 2048x64 fp32

    k_pre<<<640, 256, 0, stream>>>(x, h_prev, rwp, memory, W_ih, W_hh, W_read, W_write,
                                   W_erase, W_add, W_out,
                                   x_t, ht_t, wcat_t, Wcat2_t, Wo_rn, memt, rpt);
    k_gates<<<dim3(16, 32), 256, 0, stream>>>(rpt, x_t, ht_t, wcat_t, b_ih, b_hh, c_prev, hrn_t);
    k_heads<<<dim3(16, 35), 256, 0, stream>>>(hrn_t, Wcat2_t, b_read, b_write, b_erase, b_add, b_out,
                                              pre_r, pre_w, erase, add, out);
    k_tail<<<256, 256, 0, stream>>>(pre_r, pre_w, memt, Wo_rn, erase, add, out);
}